// Round 2
// baseline (1439.695 us; speedup 1.0000x reference)
//
#include <hip/hip_runtime.h>

#define DI __device__ __forceinline__

constexpr int SH_=2, SW_=3;
constexpr int ROWS_=57600;            // B*NW*T*N == B*T*H*W
constexpr float SCALE_=0.17677669529663687f;   // 32^-0.5

DI float bf2f(unsigned short u){ return __uint_as_float(((unsigned int)u)<<16); }
DI unsigned short f2bf(float f){
  unsigned int u = __float_as_uint(f);
  u += 0x7fffu + ((u>>16)&1u);          // round to nearest even
  return (unsigned short)(u>>16);
}
// flag f: 1 = external buffers are fp32, 0 = bf16
DI float ldf(const void* p, size_t i, int f){
  return f ? ((const float*)p)[i] : bf2f(((const unsigned short*)p)[i]);
}
DI float4 ldf4(const void* p, size_t i, int f){
  if (f) return *((const float4*)((const float*)p + i));
  ushort4 u = *((const ushort4*)((const unsigned short*)p + i));
  return make_float4(bf2f(u.x),bf2f(u.y),bf2f(u.z),bf2f(u.w));
}
DI void stf4(void* p, size_t i, float a, float b, float c, float d, int f){
  if (f){ *((float4*)((float*)p + i)) = make_float4(a,b,c,d); }
  else {
    ushort4 o; o.x=f2bf(a); o.y=f2bf(b); o.z=f2bf(c); o.w=f2bf(d);
    *((ushort4*)((unsigned short*)p + i)) = o;
  }
}

// ---------------- dtype detection: fp32-as-bf16 is detectable ----------------
// even u16 of an fp32 stream = random mantissa bits -> bf16 exponent uniform;
// sane bf16 data never has exponent > 0xC0 (|v| >= 2^65).
__global__ void k_detect(const unsigned short* __restrict__ xu, int* __restrict__ flag){
  unsigned short u = xu[threadIdx.x*2];
  int insane = ((u>>7)&0xFF) > 0xC0;
  unsigned long long m = __ballot(insane);
  if (threadIdx.x==0) *flag = m ? 1 : 0;
}

// ---------------- per-(b,t) positional bias folded through Wq/Wk -------------
__global__ __launch_bounds__(256) void k_posqk(const void* __restrict__ ce,
    const void* __restrict__ Wq, const void* __restrict__ bq,
    const void* __restrict__ Wk, const void* __restrict__ bk,
    float* __restrict__ posq, float* __restrict__ posk, const int* __restrict__ flagp)
{
  const int f = *flagp;
  const int bt = blockIdx.x, co = threadIdx.x;
  float aq = ldf(bq,co,f), ak = ldf(bk,co,f);
  for (int ci=0; ci<256; ++ci){
    float cv = ldf(ce,bt*256+ci,f);
    aq += cv*ldf(Wq,ci*256+co,f);
    ak += cv*ldf(Wk,ci*256+co,f);
  }
  posq[bt*256+co]=aq; posk[bt*256+co]=ak;
}

// ---------------- LN1 + cyclic shift + window partition ----------------------
__global__ __launch_bounds__(256) void k_ln1(const void* __restrict__ x,
    const void* __restrict__ g, const void* __restrict__ be,
    unsigned short* __restrict__ xw, const int* __restrict__ flagp)
{
  const int f = *flagp;
  const int lane = threadIdx.x & 63;
  const int wv   = threadIdx.x >> 6;
  const int rs   = blockIdx.x*4 + wv;           // spatial row (b,t,r,c)
  float4 u = ldf4(x, (size_t)rs*256 + lane*4, f);
  float s = u.x+u.y+u.z+u.w;
  #pragma unroll
  for (int o=32;o;o>>=1) s += __shfl_xor(s,o,64);
  const float mean = s*(1.f/256.f);
  float d0=u.x-mean, d1=u.y-mean, d2=u.z-mean, d3=u.w-mean;
  float qv = d0*d0+d1*d1+d2*d2+d3*d3;
  #pragma unroll
  for (int o=32;o;o>>=1) qv += __shfl_xor(qv,o,64);
  const float rstd = rsqrtf(qv*(1.f/256.f)+1e-5f);
  float4 gu = ldf4(g, lane*4, f);
  float4 bu = ldf4(be, lane*4, f);
  ushort4 o;
  o.x = f2bf(d0*rstd*gu.x+bu.x);
  o.y = f2bf(d1*rstd*gu.y+bu.y);
  o.z = f2bf(d2*rstd*gu.z+bu.z);
  o.w = f2bf(d3*rstd*gu.w+bu.w);
  const int c = rs % 60, r = (rs/60)%60, t = (rs/3600)&7, b = rs/28800;
  int r2 = r - SH_; if (r2<0) r2+=60;
  int c2 = c - SW_; if (c2<0) c2+=60;
  const int a=r2/5, ii=r2%5, bb=c2/6, jj=c2%6;
  const int rw = ((b*120 + a*10+bb)*8 + t)*30 + ii*6+jj;
  *reinterpret_cast<ushort4*>(xw + (size_t)rw*256 + lane*4) = o;
}

// ---------------- LN2 (spatial layout, x1 in out-dtype, bf16 out) ------------
__global__ __launch_bounds__(256) void k_ln2(const void* __restrict__ x1,
    const void* __restrict__ g, const void* __restrict__ be,
    unsigned short* __restrict__ xn2, const int* __restrict__ flagp)
{
  const int f = *flagp;
  const int lane = threadIdx.x & 63;
  const int wv   = threadIdx.x >> 6;
  const int rs   = blockIdx.x*4 + wv;
  float4 v = ldf4(x1, (size_t)rs*256 + lane*4, f);
  float s = v.x+v.y+v.z+v.w;
  #pragma unroll
  for (int o=32;o;o>>=1) s += __shfl_xor(s,o,64);
  const float mean = s*(1.f/256.f);
  float d0=v.x-mean, d1=v.y-mean, d2=v.z-mean, d3=v.w-mean;
  float qv = d0*d0+d1*d1+d2*d2+d3*d3;
  #pragma unroll
  for (int o=32;o;o>>=1) qv += __shfl_xor(qv,o,64);
  const float rstd = rsqrtf(qv*(1.f/256.f)+1e-5f);
  float4 gu = ldf4(g, lane*4, f);
  float4 bu = ldf4(be, lane*4, f);
  ushort4 o;
  o.x = f2bf(d0*rstd*gu.x+bu.x);
  o.y = f2bf(d1*rstd*gu.y+bu.y);
  o.z = f2bf(d2*rstd*gu.z+bu.z);
  o.w = f2bf(d3*rstd*gu.w+bu.w);
  *reinterpret_cast<ushort4*>(xn2 + (size_t)rs*256 + lane*4) = o;
}

// ---------------- shared 64x64 fp32 GEMM core --------------------------------
// A: [M][K] bf16 row-major (internal). Wt: [K][ldW] external (flag dtype).
template<int K>
DI void gemm_core(const unsigned short* __restrict__ A, const void* __restrict__ Wt,
                  const int ldW, const int m0, const int n0,
                  float acc[4][4], float* __restrict__ As, float* __restrict__ Bs, const int f)
{
  const int tid = threadIdx.x;
  const int tx = tid & 15, ty = tid >> 4;
  #pragma unroll
  for (int i=0;i<4;++i)
    #pragma unroll
    for (int j=0;j<4;++j) acc[i][j]=0.f;
  const int am = tid >> 2, akq = tid & 3;    // A tile: 64 rows x 16 k
  const int wk = tid >> 4, wnq = tid & 15;   // W tile: 16 k x 64 n
  for (int k0=0; k0<K; k0+=16){
    ushort4 ua = *reinterpret_cast<const ushort4*>(A + (size_t)(m0+am)*K + k0 + akq*4);
    float4 fw = ldf4(Wt, (size_t)(k0+wk)*ldW + n0 + wnq*4, f);
    As[(akq*4+0)*68+am]=bf2f(ua.x);
    As[(akq*4+1)*68+am]=bf2f(ua.y);
    As[(akq*4+2)*68+am]=bf2f(ua.z);
    As[(akq*4+3)*68+am]=bf2f(ua.w);
    *reinterpret_cast<float4*>(Bs + wk*64 + wnq*4) = fw;
    __syncthreads();
    #pragma unroll
    for (int kk=0;kk<16;++kk){
      float4 av  = *reinterpret_cast<const float4*>(As + kk*68 + ty*4);
      float4 bv4 = *reinterpret_cast<const float4*>(Bs + kk*64 + tx*4);
      float aa[4]={av.x,av.y,av.z,av.w};
      float bb4[4]={bv4.x,bv4.y,bv4.z,bv4.w};
      #pragma unroll
      for (int i=0;i<4;++i)
        #pragma unroll
        for (int j=0;j<4;++j) acc[i][j] += aa[i]*bb4[j];
    }
    __syncthreads();
  }
}

// ---------------- QKV projections -------------------------------------------
// BIASMODE 0: per-(b,t) fp32 vector (posq/posk).  1: plain external bias (bv).
template<int BIASMODE>
__global__ __launch_bounds__(256) void k_gemm_qkv(const unsigned short* __restrict__ Ain,
    const void* __restrict__ Wt, const float* __restrict__ posb,
    const void* __restrict__ bias, unsigned short* __restrict__ outb,
    const int* __restrict__ flagp)
{
  const int f = *flagp;
  __shared__ float As[16*68];
  __shared__ float Bs[16*64];
  float acc[4][4];
  const int m0 = blockIdx.x*64, n0 = blockIdx.y*64;
  gemm_core<256>(Ain, Wt, 256, m0, n0, acc, As, Bs, f);
  const int tx = threadIdx.x&15, ty = threadIdx.x>>4;
  #pragma unroll
  for (int i=0;i<4;++i){
    const int rw = m0 + ty*4 + i;
    const int bt2 = (rw/28800)*8 + (rw/30)%8;
    float vj[4];
    #pragma unroll
    for (int j=0;j<4;++j){
      const int col = n0 + tx*4 + j;
      const float bvv = (BIASMODE==0) ? posb[bt2*256+col] : ldf(bias,col,f);
      vj[j] = acc[i][j] + bvv;
    }
    ushort4 o; o.x=f2bf(vj[0]); o.y=f2bf(vj[1]); o.z=f2bf(vj[2]); o.w=f2bf(vj[3]);
    *reinterpret_cast<ushort4*>(outb + (size_t)rw*256 + n0 + tx*4) = o;
  }
}

// ---------------- attention: one block per (window*T, head) ------------------
__global__ __launch_bounds__(256) void k_attn(const unsigned short* __restrict__ q,
    const unsigned short* __restrict__ k, const unsigned short* __restrict__ v,
    const void* __restrict__ relb, unsigned short* __restrict__ ao,
    const int* __restrict__ flagp)
{
  const int f = *flagp;
  __shared__ float qs[30*33], ks[30*33], vs[30*33], sc[900], mx[30], inv[30];
  const int tid = threadIdx.x;
  const int blk = blockIdx.x;
  const int h  = blk & 7;
  const int bt = blk >> 3;            // (bw*T + t)
  const int wi = (bt>>3) % 120;
  const size_t base = (size_t)bt*30*256 + h*32;
  if (tid < 240){
    const int n = tid>>3, dq = tid&7;
    const size_t src = base + n*256 + dq*4;
    ushort4 uq = *reinterpret_cast<const ushort4*>(q + src);
    ushort4 uk = *reinterpret_cast<const ushort4*>(k + src);
    ushort4 uv = *reinterpret_cast<const ushort4*>(v + src);
    const int d0 = n*33 + dq*4;
    qs[d0]=bf2f(uq.x); qs[d0+1]=bf2f(uq.y); qs[d0+2]=bf2f(uq.z); qs[d0+3]=bf2f(uq.w);
    ks[d0]=bf2f(uk.x); ks[d0+1]=bf2f(uk.y); ks[d0+2]=bf2f(uk.z); ks[d0+3]=bf2f(uk.w);
    vs[d0]=bf2f(uv.x); vs[d0+1]=bf2f(uv.y); vs[d0+2]=bf2f(uv.z); vs[d0+3]=bf2f(uv.w);
  }
  __syncthreads();
  const int a = wi/10, bb = wi%10;
  for (int e=tid; e<900; e+=256){
    const int n = e/30, m = e - n*30;
    float s2 = 0.f;
    #pragma unroll
    for (int d=0; d<32; ++d) s2 += qs[n*33+d]*ks[m*33+d];
    const int in_=n/6, jn=n-in_*6, im=m/6, jm=m-im*6;
    const int ridx = (in_-im+4)*11 + (jn-jm+5);
    const float bi = ldf(relb, ridx*8+h, f);
    const int rn=a*5+in_, cn=bb*6+jn, rm=a*5+im, cm=bb*6+jm;
    const int ln_=(rn<55?0:(rn<58?1:2))*3 + (cn<54?0:(cn<57?1:2));
    const int lm_=(rm<55?0:(rm<58?1:2))*3 + (cm<54?0:(cm<57?1:2));
    sc[e] = s2*SCALE_ + bi + (ln_==lm_ ? 0.f : -100.f);
  }
  __syncthreads();
  if (tid<30){
    float m2=-1e30f;
    for (int j2=0;j2<30;++j2) m2 = fmaxf(m2, sc[tid*30+j2]);
    float su=0.f;
    for (int j2=0;j2<30;++j2) su += __expf(sc[tid*30+j2]-m2);
    mx[tid]=m2; inv[tid]=1.f/su;
  }
  __syncthreads();
  for (int e=tid; e<900; e+=256){
    const int n=e/30;
    sc[e] = __expf(sc[e]-mx[n])*inv[n];
  }
  __syncthreads();
  for (int e=tid; e<960; e+=256){
    const int n=e>>5, d=e&31;
    float s2=0.f;
    #pragma unroll
    for (int m=0;m<30;++m) s2 += sc[n*30+m]*vs[m*33+d];
    ao[base + n*256 + d] = f2bf(s2);
  }
}

// ---------------- Wo projection + window reverse + un-shift + residual -------
// x1 lives in d_out (out dtype per flag).
__global__ __launch_bounds__(256) void k_gemm_wo(const unsigned short* __restrict__ Ain,
    const void* __restrict__ Wt, const void* __restrict__ bias,
    const void* __restrict__ xin, void* __restrict__ x1, const int* __restrict__ flagp)
{
  const int f = *flagp;
  __shared__ float As[16*68];
  __shared__ float Bs[16*64];
  float acc[4][4];
  const int m0 = blockIdx.x*64, n0 = blockIdx.y*64;
  gemm_core<256>(Ain, Wt, 256, m0, n0, acc, As, Bs, f);
  const int tx=threadIdx.x&15, ty=threadIdx.x>>4;
  #pragma unroll
  for (int i=0;i<4;++i){
    const int rw = m0+ty*4+i;
    const int n = rw%30, t = (rw/30)%8, bw = rw/240;
    const int b = bw/120, wi = bw%120;
    const int a = wi/10, bb2 = wi%10, ii = n/6, jj = n%6;
    int r = a*5+ii+SH_; if (r>=60) r-=60;
    int c = bb2*6+jj+SW_; if (c>=60) c-=60;
    const size_t srow = ((size_t)((b*8+t)*60 + r)*60 + c);
    const int colb = n0 + tx*4;
    float4 ux = ldf4(xin, srow*256 + colb, f);
    stf4(x1, srow*256 + colb,
         ux.x + acc[i][0] + ldf(bias,colb+0,f),
         ux.y + acc[i][1] + ldf(bias,colb+1,f),
         ux.z + acc[i][2] + ldf(bias,colb+2,f),
         ux.w + acc[i][3] + ldf(bias,colb+3,f), f);
  }
}

// ---------------- MLP1: xn2 @ W1 + b1 -> exact GELU -> h ---------------------
__global__ __launch_bounds__(256) void k_mlp1(const unsigned short* __restrict__ Ain,
    const void* __restrict__ Wt, const void* __restrict__ bias,
    unsigned short* __restrict__ hb, const int row0, const int* __restrict__ flagp)
{
  const int f = *flagp;
  __shared__ float As[16*68];
  __shared__ float Bs[16*64];
  float acc[4][4];
  const int m0 = row0 + blockIdx.x*64, n0 = blockIdx.y*64;
  gemm_core<256>(Ain, Wt, 1024, m0, n0, acc, As, Bs, f);
  const int tx=threadIdx.x&15, ty=threadIdx.x>>4;
  #pragma unroll
  for (int i=0;i<4;++i){
    const int rl = m0 - row0 + ty*4 + i;
    float vj[4];
    #pragma unroll
    for (int j=0;j<4;++j){
      const int col = n0 + tx*4 + j;
      float vv = acc[i][j] + ldf(bias,col,f);
      vj[j] = 0.5f*vv*(1.f+erff(vv*0.70710678118654752f));
    }
    ushort4 o; o.x=f2bf(vj[0]); o.y=f2bf(vj[1]); o.z=f2bf(vj[2]); o.w=f2bf(vj[3]);
    *reinterpret_cast<ushort4*>(hb + (size_t)rl*1024 + n0 + tx*4) = o;
  }
}

// ---------------- MLP2: h @ W2 + b2 + x1 -> out ------------------------------
// x1 and outb alias (both d_out): each thread reads x1[row,col] then writes
// out[row,col] at the same address -> safe; do NOT mark them __restrict__.
__global__ __launch_bounds__(256) void k_mlp2(const unsigned short* __restrict__ hbin,
    const void* __restrict__ Wt, const void* __restrict__ bias,
    const void* x1, void* outb, const int row0, const int* __restrict__ flagp)
{
  const int f = *flagp;
  __shared__ float As[16*68];
  __shared__ float Bs[16*64];
  float acc[4][4];
  const int m0l = blockIdx.x*64, n0 = blockIdx.y*64;
  gemm_core<1024>(hbin, Wt, 256, m0l, n0, acc, As, Bs, f);
  const int tx=threadIdx.x&15, ty=threadIdx.x>>4;
  #pragma unroll
  for (int i=0;i<4;++i){
    const int grow = row0 + m0l + ty*4 + i;
    const int colb = n0 + tx*4;
    float4 xv = ldf4(x1, (size_t)grow*256 + colb, f);
    stf4(outb, (size_t)grow*256 + colb,
         xv.x + acc[i][0] + ldf(bias,colb+0,f),
         xv.y + acc[i][1] + ldf(bias,colb+1,f),
         xv.z + acc[i][2] + ldf(bias,colb+2,f),
         xv.w + acc[i][3] + ldf(bias,colb+3,f), f);
  }
}

extern "C" void kernel_launch(void* const* d_in, const int* in_sizes, int n_in,
                              void* d_out, int out_size, void* d_ws, size_t ws_size,
                              hipStream_t stream)
{
  const void* x   = d_in[0];
  const void* ce  = d_in[1];
  const void* g1  = d_in[2];
  const void* be1 = d_in[3];
  const void* Wq  = d_in[4];
  const void* bq  = d_in[5];
  const void* Wk  = d_in[6];
  const void* bk  = d_in[7];
  const void* Wv  = d_in[8];
  const void* bv  = d_in[9];
  const void* rb  = d_in[10];
  const void* Wo  = d_in[11];
  const void* bo  = d_in[12];
  const void* g2  = d_in[13];
  const void* be2 = d_in[14];
  const void* W1  = d_in[15];
  const void* b1  = d_in[16];
  const void* W2  = d_in[17];
  const void* b2  = d_in[18];

  char* ws = (char*)d_ws;
  const size_t SZ = (size_t)ROWS_*256*2;                 // 29,491,200 B
  unsigned short* kbuf = (unsigned short*)(ws);          // [0, SZ)
  unsigned short* vbuf = (unsigned short*)(ws + SZ);     // [SZ, 2SZ)
  unsigned short* xw   = (unsigned short*)(ws + 2*SZ);   // [2SZ,3SZ) later: ao
  unsigned short* qbuf = (unsigned short*)(ws + 3*SZ);   // [3SZ,4SZ) later: xn2
  unsigned short* aob  = xw;
  unsigned short* xn2  = qbuf;
  float* posq = (float*)(ws + 4*SZ);                     // 16KB
  float* posk = posq + 16*256;                           // 16KB
  int*   flag = (int*)(ws + 4*SZ + 32768);
  unsigned short* hb = (unsigned short*)ws;              // MLP chunk: [0,2SZ) reuses k,v
  void* x1 = d_out;                                      // x1 lives in d_out

  k_detect<<<1,64,0,stream>>>((const unsigned short*)x, flag);
  k_posqk<<<16,256,0,stream>>>(ce, Wq, bq, Wk, bk, posq, posk, flag);
  k_ln1<<<14400,256,0,stream>>>(x, g1, be1, xw, flag);
  dim3 g94(900,4);
  k_gemm_qkv<0><<<g94,256,0,stream>>>(xw, Wq, posq, nullptr, qbuf, flag);
  k_gemm_qkv<0><<<g94,256,0,stream>>>(xw, Wk, posk, nullptr, kbuf, flag);
  k_gemm_qkv<1><<<g94,256,0,stream>>>(xw, Wv, nullptr, bv, vbuf, flag);
  k_attn<<<15360,256,0,stream>>>(qbuf, kbuf, vbuf, rb, aob, flag);
  k_gemm_wo<<<g94,256,0,stream>>>(aob, Wo, bo, x, x1, flag);
  k_ln2<<<14400,256,0,stream>>>(x1, g2, be2, xn2, flag);
  for (int chk=0; chk<2; ++chk){
    const int row0 = chk*28800;
    k_mlp1<<<dim3(450,16),256,0,stream>>>(xn2, W1, b1, hb, row0, flag);
    k_mlp2<<<dim3(450, 4),256,0,stream>>>(hb, W2, b2, x1, d_out, row0, flag);
  }
}

// Round 3
// 526.154 us; speedup vs baseline: 2.7363x; 2.7363x over previous
//
#include <hip/hip_runtime.h>

#define DI __device__ __forceinline__

constexpr int SH_=2, SW_=3;
constexpr int ROWS_=57600;            // B*NW*T*N == B*T*H*W
constexpr float SCALE_=0.17677669529663687f;   // 32^-0.5

typedef unsigned short u16x8 __attribute__((ext_vector_type(8)));
typedef short bf16x8 __attribute__((ext_vector_type(8)));
typedef float f32x4 __attribute__((ext_vector_type(4)));

DI float bf2f(unsigned short u){ return __uint_as_float(((unsigned int)u)<<16); }
DI unsigned short f2bf(float f){
  unsigned int u = __float_as_uint(f);
  u += 0x7fffu + ((u>>16)&1u);          // round to nearest even
  return (unsigned short)(u>>16);
}
// flag f: 1 = external buffers are fp32, 0 = bf16
DI float ldf(const void* p, size_t i, int f){
  return f ? ((const float*)p)[i] : bf2f(((const unsigned short*)p)[i]);
}
DI float4 ldf4(const void* p, size_t i, int f){
  if (f) return *((const float4*)((const float*)p + i));
  ushort4 u = *((const ushort4*)((const unsigned short*)p + i));
  return make_float4(bf2f(u.x),bf2f(u.y),bf2f(u.z),bf2f(u.w));
}
DI void stf1(void* p, size_t i, float v, int f){
  if (f) ((float*)p)[i]=v; else ((unsigned short*)p)[i]=f2bf(v);
}

// ---------------- dtype detection: fp32-as-bf16 is detectable ----------------
__global__ void k_detect(const unsigned short* __restrict__ xu, int* __restrict__ flag){
  unsigned short u = xu[threadIdx.x*2];
  int insane = ((u>>7)&0xFF) > 0xC0;
  unsigned long long m = __ballot(insane);
  if (threadIdx.x==0) *flag = m ? 1 : 0;
}

// ---------------- one-time weight convert+transpose to bf16 WT[n][k] ---------
__global__ __launch_bounds__(256) void k_prepw(
    const void* __restrict__ Wq, const void* __restrict__ Wk,
    const void* __restrict__ Wv, const void* __restrict__ Wo,
    const void* __restrict__ W1, const void* __restrict__ W2,
    unsigned short* __restrict__ wt, const int* __restrict__ flagp)
{
  const int f = *flagp;
  const void* src; int kb, total; size_t off;
  switch(blockIdx.y){
    case 0: src=Wq; kb=8;  total=65536;  off=0;      break;
    case 1: src=Wk; kb=8;  total=65536;  off=65536;  break;
    case 2: src=Wv; kb=8;  total=65536;  off=131072; break;
    case 3: src=Wo; kb=8;  total=65536;  off=196608; break;
    case 4: src=W1; kb=8;  total=262144; off=262144; break;   // [256][1024]
    default:src=W2; kb=10; total=262144; off=524288; break;   // [1024][256]
  }
  const int i = blockIdx.x*256 + threadIdx.x;
  if (i >= total) return;
  const int K = 1<<kb, N = total>>kb;
  const int n = i>>kb, k = i&(K-1);
  wt[off + (size_t)n*K + k] = f2bf(ldf(src, (size_t)k*N + n, f));
}

// ---------------- per-(b,t) positional bias folded through Wq/Wk -------------
__global__ __launch_bounds__(256) void k_posqk(const void* __restrict__ ce,
    const void* __restrict__ Wq, const void* __restrict__ bq,
    const void* __restrict__ Wk, const void* __restrict__ bk,
    float* __restrict__ posq, float* __restrict__ posk, const int* __restrict__ flagp)
{
  const int f = *flagp;
  const int bt = blockIdx.x, co = threadIdx.x;
  float aq = ldf(bq,co,f), ak = ldf(bk,co,f);
  for (int ci=0; ci<256; ++ci){
    float cv = ldf(ce,bt*256+ci,f);
    aq += cv*ldf(Wq,ci*256+co,f);
    ak += cv*ldf(Wk,ci*256+co,f);
  }
  posq[bt*256+co]=aq; posk[bt*256+co]=ak;
}

// ---------------- LN1 + cyclic shift + window partition ----------------------
__global__ __launch_bounds__(256) void k_ln1(const void* __restrict__ x,
    const void* __restrict__ g, const void* __restrict__ be,
    unsigned short* __restrict__ xw, const int* __restrict__ flagp)
{
  const int f = *flagp;
  const int lane = threadIdx.x & 63;
  const int wv   = threadIdx.x >> 6;
  const int rs   = blockIdx.x*4 + wv;           // spatial row (b,t,r,c)
  float4 u = ldf4(x, (size_t)rs*256 + lane*4, f);
  float s = u.x+u.y+u.z+u.w;
  #pragma unroll
  for (int o=32;o;o>>=1) s += __shfl_xor(s,o,64);
  const float mean = s*(1.f/256.f);
  float d0=u.x-mean, d1=u.y-mean, d2=u.z-mean, d3=u.w-mean;
  float qv = d0*d0+d1*d1+d2*d2+d3*d3;
  #pragma unroll
  for (int o=32;o;o>>=1) qv += __shfl_xor(qv,o,64);
  const float rstd = rsqrtf(qv*(1.f/256.f)+1e-5f);
  float4 gu = ldf4(g, lane*4, f);
  float4 bu = ldf4(be, lane*4, f);
  ushort4 o;
  o.x = f2bf(d0*rstd*gu.x+bu.x);
  o.y = f2bf(d1*rstd*gu.y+bu.y);
  o.z = f2bf(d2*rstd*gu.z+bu.z);
  o.w = f2bf(d3*rstd*gu.w+bu.w);
  const int c = rs % 60, r = (rs/60)%60, t = (rs/3600)&7, b = rs/28800;
  int r2 = r - SH_; if (r2<0) r2+=60;
  int c2 = c - SW_; if (c2<0) c2+=60;
  const int a=r2/5, ii=r2%5, bb=c2/6, jj=c2%6;
  const int rw = ((b*120 + a*10+bb)*8 + t)*30 + ii*6+jj;
  *reinterpret_cast<ushort4*>(xw + (size_t)rw*256 + lane*4) = o;
}

// ---------------- LN2 (spatial layout, x1 in out-dtype, bf16 out) ------------
__global__ __launch_bounds__(256) void k_ln2(const void* __restrict__ x1,
    const void* __restrict__ g, const void* __restrict__ be,
    unsigned short* __restrict__ xn2, const int* __restrict__ flagp)
{
  const int f = *flagp;
  const int lane = threadIdx.x & 63;
  const int wv   = threadIdx.x >> 6;
  const int rs   = blockIdx.x*4 + wv;
  float4 v = ldf4(x1, (size_t)rs*256 + lane*4, f);
  float s = v.x+v.y+v.z+v.w;
  #pragma unroll
  for (int o=32;o;o>>=1) s += __shfl_xor(s,o,64);
  const float mean = s*(1.f/256.f);
  float d0=v.x-mean, d1=v.y-mean, d2=v.z-mean, d3=v.w-mean;
  float qv = d0*d0+d1*d1+d2*d2+d3*d3;
  #pragma unroll
  for (int o=32;o;o>>=1) qv += __shfl_xor(qv,o,64);
  const float rstd = rsqrtf(qv*(1.f/256.f)+1e-5f);
  float4 gu = ldf4(g, lane*4, f);
  float4 bu = ldf4(be, lane*4, f);
  ushort4 o;
  o.x = f2bf(d0*rstd*gu.x+bu.x);
  o.y = f2bf(d1*rstd*gu.y+bu.y);
  o.z = f2bf(d2*rstd*gu.z+bu.z);
  o.w = f2bf(d3*rstd*gu.w+bu.w);
  *reinterpret_cast<ushort4*>(xn2 + (size_t)rs*256 + lane*4) = o;
}

// ---------------- MFMA 64x64 GEMM core ---------------------------------------
// A: [M][K] bf16 row-major. WT: [N][K] bf16 row-major. 4 waves: 2x2 of 32x32.
// Fragment layout (m89-verified): a_frag lane l = A[m0+wm+mi*16+(l&15)][k0+8*(l>>4)+j]
// b_frag lane l = WT[n0+wn+ni*16+(l&15)][k0+8*(l>>4)+j]; D col=l&15, row=4*(l>>4)+r.
template<int K>
DI void mfma_core(const unsigned short* __restrict__ A, const unsigned short* __restrict__ WT,
                  const int m0, const int n0, f32x4 acc[2][2],
                  unsigned short* __restrict__ As, unsigned short* __restrict__ Bs)
{
  const int tid = threadIdx.x;
  const int sr = tid>>2, sc = (tid&3)*8;
  const int lane = tid&63, wave = tid>>6;
  const int wm = (wave>>1)*32, wn = (wave&1)*32;
  const int fr = lane&15, kg = (lane>>4)*8;
  #pragma unroll
  for (int i=0;i<2;++i)
    #pragma unroll
    for (int j=0;j<2;++j) acc[i][j] = (f32x4){0.f,0.f,0.f,0.f};
  for (int k0=0; k0<K; k0+=32){
    u16x8 va = *reinterpret_cast<const u16x8*>(A  + (size_t)(m0+sr)*K + k0 + sc);
    u16x8 vb = *reinterpret_cast<const u16x8*>(WT + (size_t)(n0+sr)*K + k0 + sc);
    *reinterpret_cast<u16x8*>(As + sr*40 + sc) = va;
    *reinterpret_cast<u16x8*>(Bs + sr*40 + sc) = vb;
    __syncthreads();
    bf16x8 a0 = *reinterpret_cast<const bf16x8*>(As + (wm+fr)*40 + kg);
    bf16x8 a1 = *reinterpret_cast<const bf16x8*>(As + (wm+16+fr)*40 + kg);
    bf16x8 b0 = *reinterpret_cast<const bf16x8*>(Bs + (wn+fr)*40 + kg);
    bf16x8 b1 = *reinterpret_cast<const bf16x8*>(Bs + (wn+16+fr)*40 + kg);
    acc[0][0] = __builtin_amdgcn_mfma_f32_16x16x32_bf16(a0,b0,acc[0][0],0,0,0);
    acc[0][1] = __builtin_amdgcn_mfma_f32_16x16x32_bf16(a0,b1,acc[0][1],0,0,0);
    acc[1][0] = __builtin_amdgcn_mfma_f32_16x16x32_bf16(a1,b0,acc[1][0],0,0,0);
    acc[1][1] = __builtin_amdgcn_mfma_f32_16x16x32_bf16(a1,b1,acc[1][1],0,0,0);
    __syncthreads();
  }
}

// ---------------- QKV projections -------------------------------------------
template<int BIASMODE>
__global__ __launch_bounds__(256) void k_gemm_qkv(const unsigned short* __restrict__ Ain,
    const unsigned short* __restrict__ WT, const float* __restrict__ posb,
    const void* __restrict__ bias, unsigned short* __restrict__ outb,
    const int* __restrict__ flagp)
{
  __shared__ unsigned short As[64*40], Bs[64*40];
  f32x4 acc[2][2];
  const int m0 = blockIdx.x*64, n0 = blockIdx.y*64;
  mfma_core<256>(Ain, WT, m0, n0, acc, As, Bs);
  const int f = *flagp;
  const int lane = threadIdx.x&63, wave = threadIdx.x>>6;
  const int wm = (wave>>1)*32, wn = (wave&1)*32;
  const int fr = lane&15, fq = lane>>4;
  #pragma unroll
  for (int mi=0;mi<2;++mi)
    #pragma unroll
    for (int ni=0;ni<2;++ni){
      const int col = n0 + wn + ni*16 + fr;
      #pragma unroll
      for (int r=0;r<4;++r){
        const int row = m0 + wm + mi*16 + fq*4 + r;
        const int bt2 = (row/28800)*8 + (row/30)%8;
        const float bvv = (BIASMODE==0) ? posb[bt2*256+col] : ldf(bias,col,f);
        outb[(size_t)row*256 + col] = f2bf(acc[mi][ni][r] + bvv);
      }
    }
}

// ---------------- attention: one block per (window*T, head) ------------------
__global__ __launch_bounds__(256) void k_attn(const unsigned short* __restrict__ q,
    const unsigned short* __restrict__ k, const unsigned short* __restrict__ v,
    const void* __restrict__ relb, unsigned short* __restrict__ ao,
    const int* __restrict__ flagp)
{
  const int f = *flagp;
  __shared__ float qs[30*33], ks[30*33], vs[30*33], sc[900], mx[30], inv[30];
  const int tid = threadIdx.x;
  const int blk = blockIdx.x;
  const int h  = blk & 7;
  const int bt = blk >> 3;            // (bw*T + t)
  const int wi = (bt>>3) % 120;
  const size_t base = (size_t)bt*30*256 + h*32;
  if (tid < 240){
    const int n = tid>>3, dq = tid&7;
    const size_t src = base + n*256 + dq*4;
    ushort4 uq = *reinterpret_cast<const ushort4*>(q + src);
    ushort4 uk = *reinterpret_cast<const ushort4*>(k + src);
    ushort4 uv = *reinterpret_cast<const ushort4*>(v + src);
    const int d0 = n*33 + dq*4;
    qs[d0]=bf2f(uq.x); qs[d0+1]=bf2f(uq.y); qs[d0+2]=bf2f(uq.z); qs[d0+3]=bf2f(uq.w);
    ks[d0]=bf2f(uk.x); ks[d0+1]=bf2f(uk.y); ks[d0+2]=bf2f(uk.z); ks[d0+3]=bf2f(uk.w);
    vs[d0]=bf2f(uv.x); vs[d0+1]=bf2f(uv.y); vs[d0+2]=bf2f(uv.z); vs[d0+3]=bf2f(uv.w);
  }
  __syncthreads();
  const int a = wi/10, bb = wi%10;
  for (int e=tid; e<900; e+=256){
    const int n = e/30, m = e - n*30;
    float s2 = 0.f;
    #pragma unroll
    for (int d=0; d<32; ++d) s2 += qs[n*33+d]*ks[m*33+d];
    const int in_=n/6, jn=n-in_*6, im=m/6, jm=m-im*6;
    const int ridx = (in_-im+4)*11 + (jn-jm+5);
    const float bi = ldf(relb, ridx*8+h, f);
    const int rn=a*5+in_, cn=bb*6+jn, rm=a*5+im, cm=bb*6+jm;
    const int ln_=(rn<55?0:(rn<58?1:2))*3 + (cn<54?0:(cn<57?1:2));
    const int lm_=(rm<55?0:(rm<58?1:2))*3 + (cm<54?0:(cm<57?1:2));
    sc[e] = s2*SCALE_ + bi + (ln_==lm_ ? 0.f : -100.f);
  }
  __syncthreads();
  if (tid<30){
    float m2=-1e30f;
    for (int j2=0;j2<30;++j2) m2 = fmaxf(m2, sc[tid*30+j2]);
    float su=0.f;
    for (int j2=0;j2<30;++j2) su += __expf(sc[tid*30+j2]-m2);
    mx[tid]=m2; inv[tid]=1.f/su;
  }
  __syncthreads();
  for (int e=tid; e<900; e+=256){
    const int n=e/30;
    sc[e] = __expf(sc[e]-mx[n])*inv[n];
  }
  __syncthreads();
  for (int e=tid; e<960; e+=256){
    const int n=e>>5, d=e&31;
    float s2=0.f;
    #pragma unroll
    for (int m=0;m<30;++m) s2 += sc[n*30+m]*vs[m*33+d];
    ao[base + n*256 + d] = f2bf(s2);
  }
}

// ---------------- Wo projection + window reverse + un-shift + residual -------
__global__ __launch_bounds__(256) void k_gemm_wo(const unsigned short* __restrict__ Ain,
    const unsigned short* __restrict__ WT, const void* __restrict__ bias,
    const void* __restrict__ xin, void* __restrict__ x1, const int* __restrict__ flagp)
{
  __shared__ unsigned short As[64*40], Bs[64*40];
  f32x4 acc[2][2];
  const int m0 = blockIdx.x*64, n0 = blockIdx.y*64;
  mfma_core<256>(Ain, WT, m0, n0, acc, As, Bs);
  const int f = *flagp;
  const int lane = threadIdx.x&63, wave = threadIdx.x>>6;
  const int wm = (wave>>1)*32, wn = (wave&1)*32;
  const int fr = lane&15, fq = lane>>4;
  #pragma unroll
  for (int mi=0;mi<2;++mi)
    #pragma unroll
    for (int r=0;r<4;++r){
      const int rw = m0 + wm + mi*16 + fq*4 + r;
      const int n = rw%30, t = (rw/30)%8, bw = rw/240;
      const int b = bw/120, wi = bw%120;
      const int a = wi/10, bb2 = wi%10, ii = n/6, jj = n%6;
      int rr = a*5+ii+SH_; if (rr>=60) rr-=60;
      int cc = bb2*6+jj+SW_; if (cc>=60) cc-=60;
      const size_t srow = ((size_t)((b*8+t)*60 + rr)*60 + cc);
      #pragma unroll
      for (int ni=0;ni<2;++ni){
        const int col = n0 + wn + ni*16 + fr;
        const float val = ldf(xin, srow*256+col, f) + acc[mi][ni][r] + ldf(bias,col,f);
        stf1(x1, srow*256+col, val, f);
      }
    }
}

// ---------------- MLP1: xn2 @ W1 + b1 -> exact GELU -> h ---------------------
__global__ __launch_bounds__(256) void k_mlp1(const unsigned short* __restrict__ Ain,
    const unsigned short* __restrict__ WT, const void* __restrict__ bias,
    unsigned short* __restrict__ hb, const int row0, const int* __restrict__ flagp)
{
  __shared__ unsigned short As[64*40], Bs[64*40];
  f32x4 acc[2][2];
  const int m0 = row0 + blockIdx.x*64, n0 = blockIdx.y*64;
  mfma_core<256>(Ain, WT, m0, n0, acc, As, Bs);
  const int f = *flagp;
  const int lane = threadIdx.x&63, wave = threadIdx.x>>6;
  const int wm = (wave>>1)*32, wn = (wave&1)*32;
  const int fr = lane&15, fq = lane>>4;
  #pragma unroll
  for (int mi=0;mi<2;++mi)
    #pragma unroll
    for (int ni=0;ni<2;++ni){
      const int col = n0 + wn + ni*16 + fr;
      const float bv = ldf(bias,col,f);
      #pragma unroll
      for (int r=0;r<4;++r){
        const int rl = m0 - row0 + wm + mi*16 + fq*4 + r;
        const float vv = acc[mi][ni][r] + bv;
        const float gg = 0.5f*vv*(1.f+erff(vv*0.70710678118654752f));
        hb[(size_t)rl*1024 + col] = f2bf(gg);
      }
    }
}

// ---------------- MLP2: h @ W2 + b2 + x1 -> out ------------------------------
__global__ __launch_bounds__(256) void k_mlp2(const unsigned short* __restrict__ hbin,
    const unsigned short* __restrict__ WT, const void* __restrict__ bias,
    const void* x1, void* outb, const int row0, const int* __restrict__ flagp)
{
  __shared__ unsigned short As[64*40], Bs[64*40];
  f32x4 acc[2][2];
  const int m0l = blockIdx.x*64, n0 = blockIdx.y*64;
  mfma_core<1024>(hbin, WT, m0l, n0, acc, As, Bs);
  const int f = *flagp;
  const int lane = threadIdx.x&63, wave = threadIdx.x>>6;
  const int wm = (wave>>1)*32, wn = (wave&1)*32;
  const int fr = lane&15, fq = lane>>4;
  #pragma unroll
  for (int mi=0;mi<2;++mi)
    #pragma unroll
    for (int ni=0;ni<2;++ni){
      const int col = n0 + wn + ni*16 + fr;
      const float bv = ldf(bias,col,f);
      #pragma unroll
      for (int r=0;r<4;++r){
        const int grow = row0 + m0l + wm + mi*16 + fq*4 + r;
        const float val = ldf(x1, (size_t)grow*256+col, f) + acc[mi][ni][r] + bv;
        stf1(outb, (size_t)grow*256+col, val, f);
      }
    }
}

extern "C" void kernel_launch(void* const* d_in, const int* in_sizes, int n_in,
                              void* d_out, int out_size, void* d_ws, size_t ws_size,
                              hipStream_t stream)
{
  const void* x   = d_in[0];
  const void* ce  = d_in[1];
  const void* g1  = d_in[2];
  const void* be1 = d_in[3];
  const void* Wq  = d_in[4];
  const void* bq  = d_in[5];
  const void* Wk  = d_in[6];
  const void* bk  = d_in[7];
  const void* Wv  = d_in[8];
  const void* bv  = d_in[9];
  const void* rb  = d_in[10];
  const void* Wo  = d_in[11];
  const void* bo  = d_in[12];
  const void* g2  = d_in[13];
  const void* be2 = d_in[14];
  const void* W1  = d_in[15];
  const void* b1  = d_in[16];
  const void* W2  = d_in[17];
  const void* b2  = d_in[18];

  char* ws = (char*)d_ws;
  const size_t SZ = (size_t)ROWS_*256*2;                 // 29,491,200 B
  unsigned short* kbuf = (unsigned short*)(ws);          // [0, SZ)
  unsigned short* vbuf = (unsigned short*)(ws + SZ);     // [SZ, 2SZ)
  unsigned short* xw   = (unsigned short*)(ws + 2*SZ);   // [2SZ,3SZ) later: ao
  unsigned short* qbuf = (unsigned short*)(ws + 3*SZ);   // [3SZ,4SZ) later: xn2
  unsigned short* aob  = xw;
  unsigned short* xn2  = qbuf;
  float* posq = (float*)(ws + 4*SZ);                     // 16KB
  float* posk = posq + 16*256;                           // 16KB
  int*   flag = (int*)(ws + 4*SZ + 32768);
  unsigned short* wt = (unsigned short*)(ws + 4*SZ + 65536);  // 1.5MB bf16 WT
  unsigned short* hb = (unsigned short*)ws;              // MLP chunk: [0,2SZ)
  void* x1 = d_out;                                      // x1 lives in d_out

  unsigned short* wtq = wt;
  unsigned short* wtk = wt + 65536;
  unsigned short* wtv = wt + 131072;
  unsigned short* wto = wt + 196608;
  unsigned short* wt1 = wt + 262144;
  unsigned short* wt2 = wt + 524288;

  k_detect<<<1,64,0,stream>>>((const unsigned short*)x, flag);
  k_prepw<<<dim3(1024,6),256,0,stream>>>(Wq,Wk,Wv,Wo,W1,W2, wt, flag);
  k_posqk<<<16,256,0,stream>>>(ce, Wq, bq, Wk, bk, posq, posk, flag);
  k_ln1<<<14400,256,0,stream>>>(x, g1, be1, xw, flag);
  dim3 g94(900,4);
  k_gemm_qkv<0><<<g94,256,0,stream>>>(xw, wtq, posq, nullptr, qbuf, flag);
  k_gemm_qkv<0><<<g94,256,0,stream>>>(xw, wtk, posk, nullptr, kbuf, flag);
  k_gemm_qkv<1><<<g94,256,0,stream>>>(xw, wtv, nullptr, bv, vbuf, flag);
  k_attn<<<15360,256,0,stream>>>(qbuf, kbuf, vbuf, rb, aob, flag);
  k_gemm_wo<<<g94,256,0,stream>>>(aob, wto, bo, x, x1, flag);
  k_ln2<<<14400,256,0,stream>>>(x1, g2, be2, xn2, flag);
  for (int chk=0; chk<2; ++chk){
    const int row0 = chk*28800;
    k_mlp1<<<dim3(450,16),256,0,stream>>>(xn2, wt1, b1, hb, row0, flag);
    k_mlp2<<<dim3(450, 4),256,0,stream>>>(hb, wt2, b2, x1, d_out, row0, flag);
  }
}

// Round 4
// 439.657 us; speedup vs baseline: 3.2746x; 1.1967x over previous
//
#include <hip/hip_runtime.h>

#define DI __device__ __forceinline__

constexpr int SH_=2, SW_=3;
constexpr int ROWS_=57600;            // B*NW*T*N == B*T*H*W
constexpr float SCALE_=0.17677669529663687f;   // 32^-0.5

typedef unsigned short u16x8 __attribute__((ext_vector_type(8)));
typedef short bf16x8 __attribute__((ext_vector_type(8)));
typedef float f32x4 __attribute__((ext_vector_type(4)));
typedef float f32x16 __attribute__((ext_vector_type(16)));

DI float bf2f(unsigned short u){ return __uint_as_float(((unsigned int)u)<<16); }
DI unsigned short f2bf(float f){
  unsigned int u = __float_as_uint(f);
  u += 0x7fffu + ((u>>16)&1u);          // round to nearest even
  return (unsigned short)(u>>16);
}
// flag f: 1 = external buffers are fp32, 0 = bf16
DI float ldf(const void* p, size_t i, int f){
  return f ? ((const float*)p)[i] : bf2f(((const unsigned short*)p)[i]);
}
DI float4 ldf4(const void* p, size_t i, int f){
  if (f) return *((const float4*)((const float*)p + i));
  ushort4 u = *((const ushort4*)((const unsigned short*)p + i));
  return make_float4(bf2f(u.x),bf2f(u.y),bf2f(u.z),bf2f(u.w));
}
DI void stf1(void* p, size_t i, float v, int f){
  if (f) ((float*)p)[i]=v; else ((unsigned short*)p)[i]=f2bf(v);
}

// async global->LDS, 16B per lane. LDS dest = wave-uniform base + lane*16.
DI void gload16(const void* g, void* l){
  __builtin_amdgcn_global_load_lds((const __attribute__((address_space(1))) unsigned int*)g,
                                   (__attribute__((address_space(3))) unsigned int*)l, 16, 0, 0);
}

// ---------------- dtype detection: fp32-as-bf16 is detectable ----------------
__global__ void k_detect(const unsigned short* __restrict__ xu, int* __restrict__ flag){
  unsigned short u = xu[threadIdx.x*2];
  int insane = ((u>>7)&0xFF) > 0xC0;
  unsigned long long m = __ballot(insane);
  if (threadIdx.x==0) *flag = m ? 1 : 0;
}

// ---------------- one-time weight convert+transpose to bf16 WT[n][k] ---------
__global__ __launch_bounds__(256) void k_prepw(
    const void* __restrict__ Wq, const void* __restrict__ Wk,
    const void* __restrict__ Wv, const void* __restrict__ Wo,
    const void* __restrict__ W1, const void* __restrict__ W2,
    unsigned short* __restrict__ wt, const int* __restrict__ flagp)
{
  const int f = *flagp;
  const void* src; int kb, total; size_t off;
  switch(blockIdx.y){
    case 0: src=Wq; kb=8;  total=65536;  off=0;      break;
    case 1: src=Wk; kb=8;  total=65536;  off=65536;  break;
    case 2: src=Wv; kb=8;  total=65536;  off=131072; break;
    case 3: src=Wo; kb=8;  total=65536;  off=196608; break;
    case 4: src=W1; kb=8;  total=262144; off=262144; break;   // [256][1024]
    default:src=W2; kb=10; total=262144; off=524288; break;   // [1024][256]
  }
  const int i = blockIdx.x*256 + threadIdx.x;
  if (i >= total) return;
  const int K = 1<<kb, N = total>>kb;
  const int n = i>>kb, k = i&(K-1);
  wt[off + (size_t)n*K + k] = f2bf(ldf(src, (size_t)k*N + n, f));
}

// ---------------- per-(b,t) positional bias folded through Wq/Wk -------------
__global__ __launch_bounds__(256) void k_posqk(const void* __restrict__ ce,
    const void* __restrict__ Wq, const void* __restrict__ bq,
    const void* __restrict__ Wk, const void* __restrict__ bk,
    float* __restrict__ posq, float* __restrict__ posk, const int* __restrict__ flagp)
{
  const int f = *flagp;
  const int bt = blockIdx.x, co = threadIdx.x;
  float aq = ldf(bq,co,f), ak = ldf(bk,co,f);
  for (int ci=0; ci<256; ++ci){
    float cv = ldf(ce,bt*256+ci,f);
    aq += cv*ldf(Wq,ci*256+co,f);
    ak += cv*ldf(Wk,ci*256+co,f);
  }
  posq[bt*256+co]=aq; posk[bt*256+co]=ak;
}

// ---------------- LN1 + cyclic shift + window partition ----------------------
__global__ __launch_bounds__(256) void k_ln1(const void* __restrict__ x,
    const void* __restrict__ g, const void* __restrict__ be,
    unsigned short* __restrict__ xw, const int* __restrict__ flagp)
{
  const int f = *flagp;
  const int lane = threadIdx.x & 63;
  const int wv   = threadIdx.x >> 6;
  const int rs   = blockIdx.x*4 + wv;           // spatial row (b,t,r,c)
  float4 u = ldf4(x, (size_t)rs*256 + lane*4, f);
  float s = u.x+u.y+u.z+u.w;
  #pragma unroll
  for (int o=32;o;o>>=1) s += __shfl_xor(s,o,64);
  const float mean = s*(1.f/256.f);
  float d0=u.x-mean, d1=u.y-mean, d2=u.z-mean, d3=u.w-mean;
  float qv = d0*d0+d1*d1+d2*d2+d3*d3;
  #pragma unroll
  for (int o=32;o;o>>=1) qv += __shfl_xor(qv,o,64);
  const float rstd = rsqrtf(qv*(1.f/256.f)+1e-5f);
  float4 gu = ldf4(g, lane*4, f);
  float4 bu = ldf4(be, lane*4, f);
  ushort4 o;
  o.x = f2bf(d0*rstd*gu.x+bu.x);
  o.y = f2bf(d1*rstd*gu.y+bu.y);
  o.z = f2bf(d2*rstd*gu.z+bu.z);
  o.w = f2bf(d3*rstd*gu.w+bu.w);
  const int c = rs % 60, r = (rs/60)%60, t = (rs/3600)&7, b = rs/28800;
  int r2 = r - SH_; if (r2<0) r2+=60;
  int c2 = c - SW_; if (c2<0) c2+=60;
  const int a=r2/5, ii=r2%5, bb=c2/6, jj=c2%6;
  const int rw = ((b*120 + a*10+bb)*8 + t)*30 + ii*6+jj;
  *reinterpret_cast<ushort4*>(xw + (size_t)rw*256 + lane*4) = o;
}

// ---------------- LN2 (spatial layout, x1 in out-dtype, bf16 out) ------------
__global__ __launch_bounds__(256) void k_ln2(const void* __restrict__ x1,
    const void* __restrict__ g, const void* __restrict__ be,
    unsigned short* __restrict__ xn2, const int* __restrict__ flagp)
{
  const int f = *flagp;
  const int lane = threadIdx.x & 63;
  const int wv   = threadIdx.x >> 6;
  const int rs   = blockIdx.x*4 + wv;
  float4 v = ldf4(x1, (size_t)rs*256 + lane*4, f);
  float s = v.x+v.y+v.z+v.w;
  #pragma unroll
  for (int o=32;o;o>>=1) s += __shfl_xor(s,o,64);
  const float mean = s*(1.f/256.f);
  float d0=v.x-mean, d1=v.y-mean, d2=v.z-mean, d3=v.w-mean;
  float qv = d0*d0+d1*d1+d2*d2+d3*d3;
  #pragma unroll
  for (int o=32;o;o>>=1) qv += __shfl_xor(qv,o,64);
  const float rstd = rsqrtf(qv*(1.f/256.f)+1e-5f);
  float4 gu = ldf4(g, lane*4, f);
  float4 bu = ldf4(be, lane*4, f);
  ushort4 o;
  o.x = f2bf(d0*rstd*gu.x+bu.x);
  o.y = f2bf(d1*rstd*gu.y+bu.y);
  o.z = f2bf(d2*rstd*gu.z+bu.z);
  o.w = f2bf(d3*rstd*gu.w+bu.w);
  *reinterpret_cast<ushort4*>(xn2 + (size_t)rs*256 + lane*4) = o;
}

// ---------------- MFMA 128x128 GEMM core (m97 structure) ---------------------
// A: [M][K] bf16 row-major. WT: [N][K] bf16 row-major. 4 waves, each owns a
// 64x64 quadrant (4x4 of 16x16 frags). Staging via global_load_lds width=16,
// LDS linear [128][32] per tile. 16 MFMA / K-step.
template<int K>
DI void mfma_core128(const unsigned short* __restrict__ A, const unsigned short* __restrict__ WT,
                     const int m0, const int n0, f32x4 acc[4][4],
                     unsigned short* As, unsigned short* Bs)
{
  const int tid = threadIdx.x, lane = tid&63, wave = tid>>6;
  const int wm = (wave>>1)*64, wn = (wave&1)*64;
  const int fr = lane&15, kg = (lane>>4)*8;
  #pragma unroll
  for (int i=0;i<4;++i)
    #pragma unroll
    for (int j=0;j<4;++j) acc[i][j] = (f32x4){0.f,0.f,0.f,0.f};
  const int c0 = wave*64 + lane;          // chunk id; row=c>>2, k-part=(c&3)*8
  const int r0 = c0>>2, p0 = (c0&3)*8;
  const int r1 = r0 + 64;                  // chunk c0+256
  unsigned short* As0 = As + wave*512;
  unsigned short* As1 = As + 2048 + wave*512;
  unsigned short* Bs0 = Bs + wave*512;
  unsigned short* Bs1 = Bs + 2048 + wave*512;
  const unsigned short* Ab0 = A  + (size_t)(m0+r0)*K + p0;
  const unsigned short* Ab1 = A  + (size_t)(m0+r1)*K + p0;
  const unsigned short* Wb0 = WT + (size_t)(n0+r0)*K + p0;
  const unsigned short* Wb1 = WT + (size_t)(n0+r1)*K + p0;
  for (int k0=0; k0<K; k0+=32){
    gload16(Ab0 + k0, As0);
    gload16(Ab1 + k0, As1);
    gload16(Wb0 + k0, Bs0);
    gload16(Wb1 + k0, Bs1);
    __syncthreads();                      // vmcnt(0) drain + barrier
    bf16x8 af[4], bfr[4];
    #pragma unroll
    for (int mi=0;mi<4;++mi) af[mi]  = *(const bf16x8*)(As + (wm+mi*16+fr)*32 + kg);
    #pragma unroll
    for (int ni=0;ni<4;++ni) bfr[ni] = *(const bf16x8*)(Bs + (wn+ni*16+fr)*32 + kg);
    #pragma unroll
    for (int mi=0;mi<4;++mi)
      #pragma unroll
      for (int ni=0;ni<4;++ni)
        acc[mi][ni] = __builtin_amdgcn_mfma_f32_16x16x32_bf16(af[mi], bfr[ni], acc[mi][ni], 0,0,0);
    __syncthreads();
  }
}

// ---------------- fused QKV projection (N=768: q|k|v) ------------------------
__global__ __launch_bounds__(256) void k_gemm_qkv(const unsigned short* __restrict__ Ain,
    const unsigned short* __restrict__ WT, const float* __restrict__ posq,
    const float* __restrict__ posk, const void* __restrict__ bv,
    unsigned short* __restrict__ qb, unsigned short* __restrict__ kb,
    unsigned short* __restrict__ vb2, const int* __restrict__ flagp)
{
  __shared__ __align__(16) unsigned short As[128*32], Bs[128*32];
  f32x4 acc[4][4];
  const int m0 = blockIdx.x*128, n0g = blockIdx.y*128;
  mfma_core128<256>(Ain, WT, m0, n0g, acc, As, Bs);
  const int f = *flagp;
  const int lane = threadIdx.x&63, wave = threadIdx.x>>6;
  const int wm = (wave>>1)*64, wn = (wave&1)*64;
  const int fr = lane&15, fq = lane>>4;
  const int seg = blockIdx.y>>1;
  unsigned short* ob = seg==0? qb : (seg==1? kb : vb2);
  const float* posb = seg==0? posq : posk;
  #pragma unroll
  for (int mi=0;mi<4;++mi){
    #pragma unroll
    for (int r=0;r<4;++r){
      const int row = m0+wm+mi*16+fq*4+r;
      const int bt2 = (row/28800)*8 + (row/30)%8;
      #pragma unroll
      for (int ni=0;ni<4;++ni){
        const int colm = (n0g + wn + ni*16 + fr) & 255;
        const float bvv = (seg<2) ? posb[bt2*256+colm] : ldf(bv,colm,f);
        ob[(size_t)row*256 + colm] = f2bf(acc[mi][ni][r] + bvv);
      }
    }
  }
}

// ---------------- MFMA attention: one wave per (bt, head) --------------------
// S^T = K.Q^T via mfma_32x32x16 (frags straight from global); in-register
// softmax (lane owns score column n); P->LDS bf16; PV = V^T.P^T via MFMA.
__global__ __launch_bounds__(256) void k_attn(const unsigned short* __restrict__ q,
    const unsigned short* __restrict__ k, const unsigned short* __restrict__ v,
    const void* __restrict__ relb, unsigned short* __restrict__ ao,
    const int* __restrict__ flagp)
{
  __shared__ __align__(16) unsigned short vt[4][32*40];   // per-wave V^T [d][m]
  __shared__ __align__(16) unsigned short pa[4][32*40];   // per-wave P [n][m]
  const int f = *flagp;
  const int tid = threadIdx.x, lane = tid&63, wave = tid>>6;
  const int task = blockIdx.x*4 + wave;      // (bt, head)
  const int h = task & 7, bt = task >> 3;
  const int wi = (bt>>3) % 120;
  const int a_ = wi/10, bb_ = wi%10;
  const size_t base = (size_t)bt*7680 + h*32;
  unsigned short* vtw = &vt[wave][0];
  unsigned short* paw = &pa[wave][0];
  // stage V transposed (rows m -> cols), zero-pad m=30,31
  if (lane < 60){
    const int m = lane>>1, hf = lane&1;
    const unsigned short* src = v + base + (size_t)m*256 + hf*16;
    u16x8 r0 = *(const u16x8*)(src);
    u16x8 r1 = *(const u16x8*)(src+8);
    #pragma unroll
    for (int j=0;j<8;++j){ vtw[(hf*16+j)*40+m] = r0[j]; vtw[(hf*16+8+j)*40+m] = r1[j]; }
  }
  vtw[(lane>>1)*40 + 30 + (lane&1)] = 0;
  // QK^T: accS[r] = scores[n=lane&31][m_r], m_r=(r&3)+8*(r>>2)+4*(lane>>5)
  const int n  = lane&31;
  const int hl = lane>>5;
  f32x16 accS = {};
  {
    const unsigned short* ka = k + base + (size_t)n*256 + hl*8;
    const unsigned short* qa = q + base + (size_t)n*256 + hl*8;
    bf16x8 a0 = *(const bf16x8*)(ka);
    bf16x8 b0 = *(const bf16x8*)(qa);
    accS = __builtin_amdgcn_mfma_f32_32x32x16_bf16(a0, b0, accS, 0,0,0);
    bf16x8 a1 = *(const bf16x8*)(ka+16);
    bf16x8 b1 = *(const bf16x8*)(qa+16);
    accS = __builtin_amdgcn_mfma_f32_32x32x16_bf16(a1, b1, accS, 0,0,0);
  }
  // softmax over m (per-lane: 16 regs + partner half via shfl_xor 32)
  const int nc  = (n < 30) ? n : 29;
  const int in_ = nc/6, jn = nc - in_*6;
  const int rn = a_*5+in_, cn = bb_*6+jn;
  const int lnl = (rn<55?0:(rn<58?1:2))*3 + (cn<54?0:(cn<57?1:2));
  #pragma unroll
  for (int r=0;r<16;++r){
    const int m = (r&3) + 8*(r>>2) + 4*hl;
    if (m < 30){
      const int im = m/6, jm = m - im*6;
      const int ridx = (in_-im+4)*11 + (jn-jm+5);
      const float bi = ldf(relb, ridx*8+h, f);
      const int rm = a_*5+im, cm = bb_*6+jm;
      const int lml = (rm<55?0:(rm<58?1:2))*3 + (cm<54?0:(cm<57?1:2));
      accS[r] = accS[r]*SCALE_ + bi + (lnl==lml ? 0.f : -100.f);
    } else accS[r] = -1e30f;
  }
  float mx = accS[0];
  #pragma unroll
  for (int r=1;r<16;++r) mx = fmaxf(mx, accS[r]);
  mx = fmaxf(mx, __shfl_xor(mx, 32, 64));
  float sum = 0.f;
  #pragma unroll
  for (int r=0;r<16;++r){ accS[r] = __expf(accS[r]-mx); sum += accS[r]; }
  sum += __shfl_xor(sum, 32, 64);
  const float inv = 1.f/sum;
  #pragma unroll
  for (int r=0;r<16;++r){
    const int m = (r&3)+8*(r>>2)+4*hl;
    paw[n*40 + m] = f2bf(accS[r]);
  }
  // PV: accO[r] = out[n][d_r]
  f32x16 accO = {};
  #pragma unroll
  for (int ks=0; ks<2; ++ks){
    bf16x8 av  = *(const bf16x8*)(vtw + n*40 + ks*16 + hl*8);
    bf16x8 pv  = *(const bf16x8*)(paw + n*40 + ks*16 + hl*8);
    accO = __builtin_amdgcn_mfma_f32_32x32x16_bf16(av, pv, accO, 0,0,0);
  }
  if (n < 30){
    #pragma unroll
    for (int g4=0; g4<4; ++g4){
      const int d0 = 8*g4 + 4*hl;
      ushort4 o;
      o.x = f2bf(accO[g4*4+0]*inv);
      o.y = f2bf(accO[g4*4+1]*inv);
      o.z = f2bf(accO[g4*4+2]*inv);
      o.w = f2bf(accO[g4*4+3]*inv);
      *(ushort4*)(ao + base + (size_t)n*256 + d0) = o;
    }
  }
}

// ---------------- Wo projection + window reverse + un-shift + residual -------
__global__ __launch_bounds__(256) void k_gemm_wo(const unsigned short* __restrict__ Ain,
    const unsigned short* __restrict__ WT, const void* __restrict__ bias,
    const void* __restrict__ xin, void* __restrict__ x1, const int* __restrict__ flagp)
{
  __shared__ __align__(16) unsigned short As[128*32], Bs[128*32];
  f32x4 acc[4][4];
  const int m0 = blockIdx.x*128, n0 = blockIdx.y*128;
  mfma_core128<256>(Ain, WT, m0, n0, acc, As, Bs);
  const int f = *flagp;
  const int lane = threadIdx.x&63, wave = threadIdx.x>>6;
  const int wm = (wave>>1)*64, wn = (wave&1)*64;
  const int fr = lane&15, fq = lane>>4;
  #pragma unroll
  for (int mi=0;mi<4;++mi){
    #pragma unroll
    for (int r=0;r<4;++r){
      const int rw = m0+wm+mi*16+fq*4+r;
      const int nn = rw%30, t = (rw/30)%8, bw = rw/240;
      const int b = bw/120, wi = bw%120;
      const int a = wi/10, bb2 = wi%10, ii = nn/6, jj = nn%6;
      int rr = a*5+ii+SH_; if (rr>=60) rr-=60;
      int cc = bb2*6+jj+SW_; if (cc>=60) cc-=60;
      const size_t srow = ((size_t)((b*8+t)*60 + rr)*60 + cc);
      #pragma unroll
      for (int ni=0;ni<4;++ni){
        const int col = n0 + wn + ni*16 + fr;
        const float val = ldf(xin, srow*256+col, f) + acc[mi][ni][r] + ldf(bias,col,f);
        stf1(x1, srow*256+col, val, f);
      }
    }
  }
}

// ---------------- MLP1: xn2 @ W1 + b1 -> exact GELU -> h ---------------------
__global__ __launch_bounds__(256) void k_mlp1(const unsigned short* __restrict__ Ain,
    const unsigned short* __restrict__ WT, const void* __restrict__ bias,
    unsigned short* __restrict__ hb, const int row0, const int* __restrict__ flagp)
{
  __shared__ __align__(16) unsigned short As[128*32], Bs[128*32];
  f32x4 acc[4][4];
  const int m0 = row0 + blockIdx.x*128, n0 = blockIdx.y*128;
  mfma_core128<256>(Ain, WT, m0, n0, acc, As, Bs);
  const int f = *flagp;
  const int lane = threadIdx.x&63, wave = threadIdx.x>>6;
  const int wm = (wave>>1)*64, wn = (wave&1)*64;
  const int fr = lane&15, fq = lane>>4;
  #pragma unroll
  for (int mi=0;mi<4;++mi){
    #pragma unroll
    for (int ni=0;ni<4;++ni){
      const int col = n0 + wn + ni*16 + fr;
      const float bv = ldf(bias,col,f);
      #pragma unroll
      for (int r=0;r<4;++r){
        const int rl = m0 - row0 + wm + mi*16 + fq*4 + r;
        const float vv = acc[mi][ni][r] + bv;
        const float gg = 0.5f*vv*(1.f+erff(vv*0.70710678118654752f));
        hb[(size_t)rl*1024 + col] = f2bf(gg);
      }
    }
  }
}

// ---------------- MLP2: h @ W2 + b2 + x1 -> out ------------------------------
__global__ __launch_bounds__(256) void k_mlp2(const unsigned short* __restrict__ hbin,
    const unsigned short* __restrict__ WT, const void* __restrict__ bias,
    const void* x1, void* outb, const int row0, const int* __restrict__ flagp)
{
  __shared__ __align__(16) unsigned short As[128*32], Bs[128*32];
  f32x4 acc[4][4];
  const int m0l = blockIdx.x*128, n0 = blockIdx.y*128;
  mfma_core128<1024>(hbin, WT, m0l, n0, acc, As, Bs);
  const int f = *flagp;
  const int lane = threadIdx.x&63, wave = threadIdx.x>>6;
  const int wm = (wave>>1)*64, wn = (wave&1)*64;
  const int fr = lane&15, fq = lane>>4;
  #pragma unroll
  for (int mi=0;mi<4;++mi){
    #pragma unroll
    for (int ni=0;ni<4;++ni){
      const int col = n0 + wn + ni*16 + fr;
      const float bv = ldf(bias,col,f);
      #pragma unroll
      for (int r=0;r<4;++r){
        const int grow = row0 + m0l + wm + mi*16 + fq*4 + r;
        const float val = ldf(x1, (size_t)grow*256+col, f) + acc[mi][ni][r] + bv;
        stf1(outb, (size_t)grow*256+col, val, f);
      }
    }
  }
}

extern "C" void kernel_launch(void* const* d_in, const int* in_sizes, int n_in,
                              void* d_out, int out_size, void* d_ws, size_t ws_size,
                              hipStream_t stream)
{
  const void* x   = d_in[0];
  const void* ce  = d_in[1];
  const void* g1  = d_in[2];
  const void* be1 = d_in[3];
  const void* Wq  = d_in[4];
  const void* bq  = d_in[5];
  const void* Wk  = d_in[6];
  const void* bk  = d_in[7];
  const void* Wv  = d_in[8];
  const void* bv  = d_in[9];
  const void* rb  = d_in[10];
  const void* Wo  = d_in[11];
  const void* bo  = d_in[12];
  const void* g2  = d_in[13];
  const void* be2 = d_in[14];
  const void* W1  = d_in[15];
  const void* b1  = d_in[16];
  const void* W2  = d_in[17];
  const void* b2  = d_in[18];

  char* ws = (char*)d_ws;
  const size_t SZ = (size_t)ROWS_*256*2;                 // 29,491,200 B
  unsigned short* kbuf = (unsigned short*)(ws);          // [0, SZ)
  unsigned short* vbuf = (unsigned short*)(ws + SZ);     // [SZ, 2SZ)
  unsigned short* xw   = (unsigned short*)(ws + 2*SZ);   // [2SZ,3SZ) later: ao
  unsigned short* qbuf = (unsigned short*)(ws + 3*SZ);   // [3SZ,4SZ) later: xn2
  unsigned short* aob  = xw;
  unsigned short* xn2  = qbuf;
  float* posq = (float*)(ws + 4*SZ);                     // 16KB
  float* posk = posq + 16*256;                           // 16KB
  int*   flag = (int*)(ws + 4*SZ + 32768);
  unsigned short* wt = (unsigned short*)(ws + 4*SZ + 65536);  // 1.5MB bf16 WT
  unsigned short* hb = (unsigned short*)ws;              // MLP chunk: [0,2SZ)
  void* x1 = d_out;                                      // x1 lives in d_out

  unsigned short* wtqkv = wt;            // q|k|v contiguous: WT[768][256]
  unsigned short* wto = wt + 196608;
  unsigned short* wt1 = wt + 262144;
  unsigned short* wt2 = wt + 524288;

  k_detect<<<1,64,0,stream>>>((const unsigned short*)x, flag);
  k_prepw<<<dim3(1024,6),256,0,stream>>>(Wq,Wk,Wv,Wo,W1,W2, wt, flag);
  k_posqk<<<16,256,0,stream>>>(ce, Wq, bq, Wk, bk, posq, posk, flag);
  k_ln1<<<14400,256,0,stream>>>(x, g1, be1, xw, flag);
  k_gemm_qkv<<<dim3(450,6),256,0,stream>>>(xw, wtqkv, posq, posk, bv, qbuf, kbuf, vbuf, flag);
  k_attn<<<3840,256,0,stream>>>(qbuf, kbuf, vbuf, rb, aob, flag);
  k_gemm_wo<<<dim3(450,2),256,0,stream>>>(aob, wto, bo, x, x1, flag);
  k_ln2<<<14400,256,0,stream>>>(x1, g2, be2, xn2, flag);
  for (int chk=0; chk<2; ++chk){
    const int row0 = chk*28800;
    k_mlp1<<<dim3(225,8),256,0,stream>>>(xn2, wt1, b1, hb, row0, flag);
    k_mlp2<<<dim3(225,2),256,0,stream>>>(hb, wt2, b2, x1, d_out, row0, flag);
  }
}

// Round 5
// 399.926 us; speedup vs baseline: 3.5999x; 1.0993x over previous
//
#include <hip/hip_runtime.h>

#define DI __device__ __forceinline__

constexpr int SH_=2, SW_=3;
constexpr int ROWS_=57600;            // B*NW*T*N == B*T*H*W
constexpr float SCALE_=0.17677669529663687f;   // 32^-0.5

typedef unsigned short u16x8 __attribute__((ext_vector_type(8)));
typedef short bf16x8 __attribute__((ext_vector_type(8)));
typedef float f32x4 __attribute__((ext_vector_type(4)));
typedef float f32x16 __attribute__((ext_vector_type(16)));

DI float bf2f(unsigned short u){ return __uint_as_float(((unsigned int)u)<<16); }
DI unsigned short f2bf(float f){
  unsigned int u = __float_as_uint(f);
  u += 0x7fffu + ((u>>16)&1u);          // round to nearest even
  return (unsigned short)(u>>16);
}
// flag f: 1 = external buffers are fp32, 0 = bf16
DI float ldf(const void* p, size_t i, int f){
  return f ? ((const float*)p)[i] : bf2f(((const unsigned short*)p)[i]);
}
DI float4 ldf4(const void* p, size_t i, int f){
  if (f) return *((const float4*)((const float*)p + i));
  ushort4 u = *((const ushort4*)((const unsigned short*)p + i));
  return make_float4(bf2f(u.x),bf2f(u.y),bf2f(u.z),bf2f(u.w));
}
DI void stf1(void* p, size_t i, float v, int f){
  if (f) ((float*)p)[i]=v; else ((unsigned short*)p)[i]=f2bf(v);
}

// async global->LDS, 16B per lane. LDS dest = wave-uniform base + lane*16.
DI void gload16(const void* g, void* l){
  __builtin_amdgcn_global_load_lds((const __attribute__((address_space(1))) unsigned int*)g,
                                   (__attribute__((address_space(3))) unsigned int*)l, 16, 0, 0);
}

// XCD-bijective remap (m204): n-tile varies fastest within an XCD so all
// n-tiles of one A-panel run consecutively on the same XCD -> A L2-reuse.
DI void xcd_remap(int wg, int nb, int nn, int& mt, int& nt){
  const int q = nb>>3, r = nb&7;
  const int x = wg & 7, i = wg >> 3;
  const int base = (x<r) ? x*(q+1) : r*(q+1) + (x-r)*q;
  const int work = base + i;
  mt = work / nn; nt = work - mt*nn;
}

// ---------------- dtype detection: fp32-as-bf16 is detectable ----------------
__global__ void k_detect(const unsigned short* __restrict__ xu, int* __restrict__ flag){
  unsigned short u = xu[threadIdx.x*2];
  int insane = ((u>>7)&0xFF) > 0xC0;
  unsigned long long m = __ballot(insane);
  if (threadIdx.x==0) *flag = m ? 1 : 0;
}

// ---------------- one-time weight convert+transpose to bf16 WT[n][k] ---------
__global__ __launch_bounds__(256) void k_prepw(
    const void* __restrict__ Wq, const void* __restrict__ Wk,
    const void* __restrict__ Wv, const void* __restrict__ Wo,
    const void* __restrict__ W1, const void* __restrict__ W2,
    unsigned short* __restrict__ wt, const int* __restrict__ flagp)
{
  const int f = *flagp;
  const void* src; int kb, total; size_t off;
  switch(blockIdx.y){
    case 0: src=Wq; kb=8;  total=65536;  off=0;      break;
    case 1: src=Wk; kb=8;  total=65536;  off=65536;  break;
    case 2: src=Wv; kb=8;  total=65536;  off=131072; break;
    case 3: src=Wo; kb=8;  total=65536;  off=196608; break;
    case 4: src=W1; kb=8;  total=262144; off=262144; break;   // [256][1024]
    default:src=W2; kb=10; total=262144; off=524288; break;   // [1024][256]
  }
  const int i = blockIdx.x*256 + threadIdx.x;
  if (i >= total) return;
  const int K = 1<<kb, N = total>>kb;
  const int n = i>>kb, k = i&(K-1);
  wt[off + (size_t)n*K + k] = f2bf(ldf(src, (size_t)k*N + n, f));
}

// ---------------- per-(b,t) positional bias folded through Wq/Wk -------------
__global__ __launch_bounds__(256) void k_posqk(const void* __restrict__ ce,
    const void* __restrict__ Wq, const void* __restrict__ bq,
    const void* __restrict__ Wk, const void* __restrict__ bk,
    float* __restrict__ posq, float* __restrict__ posk, const int* __restrict__ flagp)
{
  const int f = *flagp;
  const int bt = blockIdx.x, co = threadIdx.x;
  float aq = ldf(bq,co,f), ak = ldf(bk,co,f);
  for (int ci=0; ci<256; ++ci){
    float cv = ldf(ce,bt*256+ci,f);
    aq += cv*ldf(Wq,ci*256+co,f);
    ak += cv*ldf(Wk,ci*256+co,f);
  }
  posq[bt*256+co]=aq; posk[bt*256+co]=ak;
}

// ---------------- LN1 + cyclic shift + window partition ----------------------
__global__ __launch_bounds__(256) void k_ln1(const void* __restrict__ x,
    const void* __restrict__ g, const void* __restrict__ be,
    unsigned short* __restrict__ xw, const int* __restrict__ flagp)
{
  const int f = *flagp;
  const int lane = threadIdx.x & 63;
  const int wv   = threadIdx.x >> 6;
  const int rs   = blockIdx.x*4 + wv;           // spatial row (b,t,r,c)
  float4 u = ldf4(x, (size_t)rs*256 + lane*4, f);
  float s = u.x+u.y+u.z+u.w;
  #pragma unroll
  for (int o=32;o;o>>=1) s += __shfl_xor(s,o,64);
  const float mean = s*(1.f/256.f);
  float d0=u.x-mean, d1=u.y-mean, d2=u.z-mean, d3=u.w-mean;
  float qv = d0*d0+d1*d1+d2*d2+d3*d3;
  #pragma unroll
  for (int o=32;o;o>>=1) qv += __shfl_xor(qv,o,64);
  const float rstd = rsqrtf(qv*(1.f/256.f)+1e-5f);
  float4 gu = ldf4(g, lane*4, f);
  float4 bu = ldf4(be, lane*4, f);
  ushort4 o;
  o.x = f2bf(d0*rstd*gu.x+bu.x);
  o.y = f2bf(d1*rstd*gu.y+bu.y);
  o.z = f2bf(d2*rstd*gu.z+bu.z);
  o.w = f2bf(d3*rstd*gu.w+bu.w);
  const int c = rs % 60, r = (rs/60)%60, t = (rs/3600)&7, b = rs/28800;
  int r2 = r - SH_; if (r2<0) r2+=60;
  int c2 = c - SW_; if (c2<0) c2+=60;
  const int a=r2/5, ii=r2%5, bb=c2/6, jj=c2%6;
  const int rw = ((b*120 + a*10+bb)*8 + t)*30 + ii*6+jj;
  *reinterpret_cast<ushort4*>(xw + (size_t)rw*256 + lane*4) = o;
}

// ---------------- LN2 (spatial layout, x1 in out-dtype, bf16 out) ------------
__global__ __launch_bounds__(256) void k_ln2(const void* __restrict__ x1,
    const void* __restrict__ g, const void* __restrict__ be,
    unsigned short* __restrict__ xn2, const int* __restrict__ flagp)
{
  const int f = *flagp;
  const int lane = threadIdx.x & 63;
  const int wv   = threadIdx.x >> 6;
  const int rs   = blockIdx.x*4 + wv;
  float4 v = ldf4(x1, (size_t)rs*256 + lane*4, f);
  float s = v.x+v.y+v.z+v.w;
  #pragma unroll
  for (int o=32;o;o>>=1) s += __shfl_xor(s,o,64);
  const float mean = s*(1.f/256.f);
  float d0=v.x-mean, d1=v.y-mean, d2=v.z-mean, d3=v.w-mean;
  float qv = d0*d0+d1*d1+d2*d2+d3*d3;
  #pragma unroll
  for (int o=32;o;o>>=1) qv += __shfl_xor(qv,o,64);
  const float rstd = rsqrtf(qv*(1.f/256.f)+1e-5f);
  float4 gu = ldf4(g, lane*4, f);
  float4 bu = ldf4(be, lane*4, f);
  ushort4 o;
  o.x = f2bf(d0*rstd*gu.x+bu.x);
  o.y = f2bf(d1*rstd*gu.y+bu.y);
  o.z = f2bf(d2*rstd*gu.z+bu.z);
  o.w = f2bf(d3*rstd*gu.w+bu.w);
  *reinterpret_cast<ushort4*>(xn2 + (size_t)rs*256 + lane*4) = o;
}

// ---------------- MFMA 128x128 GEMM core, dbuf + counted vmcnt ---------------
// A: [M][K] bf16 row-major. WT: [N][K] bf16 row-major. 4 waves, each a 64x64
// quadrant. LDS: A[2][128*32] + B[2][128*32] shorts (32KB). Staging source is
// part-swizzled (part ^= row&3) so the XOR'd ds_read is conflict-reduced
// (8-way -> 4-way) while global_load_lds writes stay lane-linear (rule 21).
template<int K>
DI void mfma_core128(const unsigned short* __restrict__ A, const unsigned short* __restrict__ WT,
                     const int m0, const int n0, f32x4 acc[4][4], unsigned short* lds)
{
  constexpr int STEPS = K/32;
  const int tid = threadIdx.x, lane = tid&63, wave = tid>>6;
  const int wm = (wave>>1)*64, wn = (wave&1)*64;
  const int fr = lane&15;
  const int kqs = ((lane>>4) ^ (fr&3))*8;   // swizzled k-part offset (shorts)
  #pragma unroll
  for (int i=0;i<4;++i)
    #pragma unroll
    for (int j=0;j<4;++j) acc[i][j] = (f32x4){0.f,0.f,0.f,0.f};
  const int c0 = wave*64 + lane;            // chunk 0..255 -> row=c>>2, part=c&3
  const int r0 = c0>>2, pp = c0&3;
  const int pl = pp ^ (r0&3);               // inverse-swizzled source part
  const unsigned short* Ab0 = A  + (size_t)(m0+r0)*K    + pl*8;
  const unsigned short* Ab1 = A  + (size_t)(m0+r0+64)*K + pl*8;
  const unsigned short* Wb0 = WT + (size_t)(n0+r0)*K    + pl*8;
  const unsigned short* Wb1 = WT + (size_t)(n0+r0+64)*K + pl*8;
  unsigned short* Alds = lds;               // [2][4096]
  unsigned short* Blds = lds + 8192;        // [2][4096]
  const int wsl = wave*512;
  #define STAGE_(d,k0) do{ \
    gload16(Ab0+(k0), Alds + (d)*4096 + wsl); \
    gload16(Ab1+(k0), Alds + (d)*4096 + 2048 + wsl); \
    gload16(Wb0+(k0), Blds + (d)*4096 + wsl); \
    gload16(Wb1+(k0), Blds + (d)*4096 + 2048 + wsl); }while(0)
  STAGE_(0,0);
  int cur = 0;
  for (int t=0; t<STEPS; ++t){
    if (t+1 < STEPS){
      STAGE_(cur^1, (t+1)*32);
      asm volatile("s_waitcnt vmcnt(4)" ::: "memory");
    } else {
      asm volatile("s_waitcnt vmcnt(0)" ::: "memory");
    }
    __builtin_amdgcn_s_barrier();
    const unsigned short* At = Alds + cur*4096;
    const unsigned short* Bt = Blds + cur*4096;
    bf16x8 af[4], bfv[4];
    #pragma unroll
    for (int mi=0;mi<4;++mi) af[mi]  = *(const bf16x8*)(At + (wm+mi*16+fr)*32 + kqs);
    #pragma unroll
    for (int ni=0;ni<4;++ni) bfv[ni] = *(const bf16x8*)(Bt + (wn+ni*16+fr)*32 + kqs);
    #pragma unroll
    for (int mi=0;mi<4;++mi)
      #pragma unroll
      for (int ni=0;ni<4;++ni)
        acc[mi][ni] = __builtin_amdgcn_mfma_f32_16x16x32_bf16(af[mi], bfv[ni], acc[mi][ni], 0,0,0);
    __builtin_amdgcn_s_barrier();
    cur ^= 1;
  }
  #undef STAGE_
}

// ---------------- fused QKV projection (N=768: q|k|v) ------------------------
__global__ __launch_bounds__(256) void k_gemm_qkv(const unsigned short* __restrict__ Ain,
    const unsigned short* __restrict__ WT, const float* __restrict__ posq,
    const float* __restrict__ posk, const void* __restrict__ bv,
    unsigned short* __restrict__ qb, unsigned short* __restrict__ kb,
    unsigned short* __restrict__ vb2, const int* __restrict__ flagp)
{
  __shared__ __align__(16) unsigned short lds[16384];
  f32x4 acc[4][4];
  int mt, nt; xcd_remap(blockIdx.x, 2700, 6, mt, nt);
  const int m0 = mt*128, n0g = nt*128;
  mfma_core128<256>(Ain, WT, m0, n0g, acc, lds);
  const int f = *flagp;
  const int lane = threadIdx.x&63, wave = threadIdx.x>>6;
  const int wm = (wave>>1)*64, wn = (wave&1)*64;
  const int fr = lane&15, fq = lane>>4;
  const int seg = nt>>1;
  unsigned short* ob = seg==0? qb : (seg==1? kb : vb2);
  const float* posb = seg==0? posq : posk;
  #pragma unroll
  for (int mi=0;mi<4;++mi){
    #pragma unroll
    for (int r=0;r<4;++r){
      const int row = m0+wm+mi*16+fq*4+r;
      const int bt2 = (row/28800)*8 + (row/30)%8;
      #pragma unroll
      for (int ni=0;ni<4;++ni){
        const int colm = (n0g + wn + ni*16 + fr) & 255;
        const float bvv = (seg<2) ? posb[bt2*256+colm] : ldf(bv,colm,f);
        ob[(size_t)row*256 + colm] = f2bf(acc[mi][ni][r] + bvv);
      }
    }
  }
}

// ---------------- MFMA attention: one wave per (bt, head) --------------------
__global__ __launch_bounds__(256) void k_attn(const unsigned short* __restrict__ q,
    const unsigned short* __restrict__ k, const unsigned short* __restrict__ v,
    const void* __restrict__ relb, unsigned short* __restrict__ ao,
    const int* __restrict__ flagp)
{
  __shared__ __align__(16) unsigned short vt[4][32*40];   // per-wave V^T [d][m]
  __shared__ __align__(16) unsigned short pa[4][32*40];   // per-wave P [n][m]
  const int f = *flagp;
  const int tid = threadIdx.x, lane = tid&63, wave = tid>>6;
  const int task = blockIdx.x*4 + wave;      // (bt, head)
  const int h = task & 7, bt = task >> 3;
  const int wi = (bt>>3) % 120;
  const int a_ = wi/10, bb_ = wi%10;
  const size_t base = (size_t)bt*7680 + h*32;
  unsigned short* vtw = &vt[wave][0];
  unsigned short* paw = &pa[wave][0];
  // stage V transposed (rows m -> cols), zero-pad m=30,31
  if (lane < 60){
    const int m = lane>>1, hf = lane&1;
    const unsigned short* src = v + base + (size_t)m*256 + hf*16;
    u16x8 r0 = *(const u16x8*)(src);
    u16x8 r1 = *(const u16x8*)(src+8);
    #pragma unroll
    for (int j=0;j<8;++j){ vtw[(hf*16+j)*40+m] = r0[j]; vtw[(hf*16+8+j)*40+m] = r1[j]; }
  }
  vtw[(lane>>1)*40 + 30 + (lane&1)] = 0;
  // QK^T: accS[r] = scores[n=lane&31][m_r], m_r=(r&3)+8*(r>>2)+4*(lane>>5)
  const int n  = lane&31;
  const int hl = lane>>5;
  f32x16 accS = {};
  {
    const unsigned short* ka = k + base + (size_t)n*256 + hl*8;
    const unsigned short* qa = q + base + (size_t)n*256 + hl*8;
    bf16x8 a0 = *(const bf16x8*)(ka);
    bf16x8 b0 = *(const bf16x8*)(qa);
    accS = __builtin_amdgcn_mfma_f32_32x32x16_bf16(a0, b0, accS, 0,0,0);
    bf16x8 a1 = *(const bf16x8*)(ka+16);
    bf16x8 b1 = *(const bf16x8*)(qa+16);
    accS = __builtin_amdgcn_mfma_f32_32x32x16_bf16(a1, b1, accS, 0,0,0);
  }
  // softmax over m (per-lane: 16 regs + partner half via shfl_xor 32)
  const int nc  = (n < 30) ? n : 29;
  const int in_ = nc/6, jn = nc - in_*6;
  const int rn = a_*5+in_, cn = bb_*6+jn;
  const int lnl = (rn<55?0:(rn<58?1:2))*3 + (cn<54?0:(cn<57?1:2));
  #pragma unroll
  for (int r=0;r<16;++r){
    const int m = (r&3) + 8*(r>>2) + 4*hl;
    if (m < 30){
      const int im = m/6, jm = m - im*6;
      const int ridx = (in_-im+4)*11 + (jn-jm+5);
      const float bi = ldf(relb, ridx*8+h, f);
      const int rm = a_*5+im, cm = bb_*6+jm;
      const int lml = (rm<55?0:(rm<58?1:2))*3 + (cm<54?0:(cm<57?1:2));
      accS[r] = accS[r]*SCALE_ + bi + (lnl==lml ? 0.f : -100.f);
    } else accS[r] = -1e30f;
  }
  float mx = accS[0];
  #pragma unroll
  for (int r=1;r<16;++r) mx = fmaxf(mx, accS[r]);
  mx = fmaxf(mx, __shfl_xor(mx, 32, 64));
  float sum = 0.f;
  #pragma unroll
  for (int r=0;r<16;++r){ accS[r] = __expf(accS[r]-mx); sum += accS[r]; }
  sum += __shfl_xor(sum, 32, 64);
  const float inv = 1.f/sum;
  #pragma unroll
  for (int r=0;r<16;++r){
    const int m = (r&3)+8*(r>>2)+4*hl;
    paw[n*40 + m] = f2bf(accS[r]);
  }
  // PV: accO[r] = out[n][d_r]
  f32x16 accO = {};
  #pragma unroll
  for (int ks=0; ks<2; ++ks){
    bf16x8 av  = *(const bf16x8*)(vtw + n*40 + ks*16 + hl*8);
    bf16x8 pv  = *(const bf16x8*)(paw + n*40 + ks*16 + hl*8);
    accO = __builtin_amdgcn_mfma_f32_32x32x16_bf16(av, pv, accO, 0,0,0);
  }
  if (n < 30){
    #pragma unroll
    for (int g4=0; g4<4; ++g4){
      const int d0 = 8*g4 + 4*hl;
      ushort4 o;
      o.x = f2bf(accO[g4*4+0]*inv);
      o.y = f2bf(accO[g4*4+1]*inv);
      o.z = f2bf(accO[g4*4+2]*inv);
      o.w = f2bf(accO[g4*4+3]*inv);
      *(ushort4*)(ao + base + (size_t)n*256 + d0) = o;
    }
  }
}

// ---------------- Wo projection + window reverse + un-shift + residual -------
__global__ __launch_bounds__(256) void k_gemm_wo(const unsigned short* __restrict__ Ain,
    const unsigned short* __restrict__ WT, const void* __restrict__ bias,
    const void* __restrict__ xin, void* __restrict__ x1, const int* __restrict__ flagp)
{
  __shared__ __align__(16) unsigned short lds[16384];
  f32x4 acc[4][4];
  int mt, nt; xcd_remap(blockIdx.x, 900, 2, mt, nt);
  const int m0 = mt*128, n0 = nt*128;
  mfma_core128<256>(Ain, WT, m0, n0, acc, lds);
  const int f = *flagp;
  const int lane = threadIdx.x&63, wave = threadIdx.x>>6;
  const int wm = (wave>>1)*64, wn = (wave&1)*64;
  const int fr = lane&15, fq = lane>>4;
  #pragma unroll
  for (int mi=0;mi<4;++mi){
    #pragma unroll
    for (int r=0;r<4;++r){
      const int rw = m0+wm+mi*16+fq*4+r;
      const int nn = rw%30, t = (rw/30)%8, bw = rw/240;
      const int b = bw/120, wi = bw%120;
      const int a = wi/10, bb2 = wi%10, ii = nn/6, jj = nn%6;
      int rr = a*5+ii+SH_; if (rr>=60) rr-=60;
      int cc = bb2*6+jj+SW_; if (cc>=60) cc-=60;
      const size_t srow = ((size_t)((b*8+t)*60 + rr)*60 + cc);
      #pragma unroll
      for (int ni=0;ni<4;++ni){
        const int col = n0 + wn + ni*16 + fr;
        const float val = ldf(xin, srow*256+col, f) + acc[mi][ni][r] + ldf(bias,col,f);
        stf1(x1, srow*256+col, val, f);
      }
    }
  }
}

// ---------------- MLP1: xn2 @ W1 + b1 -> exact GELU -> h ---------------------
__global__ __launch_bounds__(256) void k_mlp1(const unsigned short* __restrict__ Ain,
    const unsigned short* __restrict__ WT, const void* __restrict__ bias,
    unsigned short* __restrict__ hb, const int row0, const int* __restrict__ flagp)
{
  __shared__ __align__(16) unsigned short lds[16384];
  f32x4 acc[4][4];
  int mt, nt; xcd_remap(blockIdx.x, 1800, 8, mt, nt);
  const int m0 = row0 + mt*128, n0 = nt*128;
  mfma_core128<256>(Ain, WT, m0, n0, acc, lds);
  const int f = *flagp;
  const int lane = threadIdx.x&63, wave = threadIdx.x>>6;
  const int wm = (wave>>1)*64, wn = (wave&1)*64;
  const int fr = lane&15, fq = lane>>4;
  #pragma unroll
  for (int mi=0;mi<4;++mi){
    #pragma unroll
    for (int ni=0;ni<4;++ni){
      const int col = n0 + wn + ni*16 + fr;
      const float bv = ldf(bias,col,f);
      #pragma unroll
      for (int r=0;r<4;++r){
        const int rl = m0 - row0 + wm + mi*16 + fq*4 + r;
        const float vv = acc[mi][ni][r] + bv;
        const float gg = 0.5f*vv*(1.f+erff(vv*0.70710678118654752f));
        hb[(size_t)rl*1024 + col] = f2bf(gg);
      }
    }
  }
}

// ---------------- MLP2: h @ W2 + b2 + x1 -> out ------------------------------
__global__ __launch_bounds__(256) void k_mlp2(const unsigned short* __restrict__ hbin,
    const unsigned short* __restrict__ WT, const void* __restrict__ bias,
    const void* x1, void* outb, const int row0, const int* __restrict__ flagp)
{
  __shared__ __align__(16) unsigned short lds[16384];
  f32x4 acc[4][4];
  int mt, nt; xcd_remap(blockIdx.x, 450, 2, mt, nt);
  const int m0l = mt*128, n0 = nt*128;
  mfma_core128<1024>(hbin, WT, m0l, n0, acc, lds);
  const int f = *flagp;
  const int lane = threadIdx.x&63, wave = threadIdx.x>>6;
  const int wm = (wave>>1)*64, wn = (wave&1)*64;
  const int fr = lane&15, fq = lane>>4;
  #pragma unroll
  for (int mi=0;mi<4;++mi){
    #pragma unroll
    for (int ni=0;ni<4;++ni){
      const int col = n0 + wn + ni*16 + fr;
      const float bv = ldf(bias,col,f);
      #pragma unroll
      for (int r=0;r<4;++r){
        const int grow = row0 + m0l + wm + mi*16 + fq*4 + r;
        const float val = ldf(x1, (size_t)grow*256+col, f) + acc[mi][ni][r] + bv;
        stf1(outb, (size_t)grow*256+col, val, f);
      }
    }
  }
}

extern "C" void kernel_launch(void* const* d_in, const int* in_sizes, int n_in,
                              void* d_out, int out_size, void* d_ws, size_t ws_size,
                              hipStream_t stream)
{
  const void* x   = d_in[0];
  const void* ce  = d_in[1];
  const void* g1  = d_in[2];
  const void* be1 = d_in[3];
  const void* Wq  = d_in[4];
  const void* bq  = d_in[5];
  const void* Wk  = d_in[6];
  const void* bk  = d_in[7];
  const void* Wv  = d_in[8];
  const void* bv  = d_in[9];
  const void* rb  = d_in[10];
  const void* Wo  = d_in[11];
  const void* bo  = d_in[12];
  const void* g2  = d_in[13];
  const void* be2 = d_in[14];
  const void* W1  = d_in[15];
  const void* b1  = d_in[16];
  const void* W2  = d_in[17];
  const void* b2  = d_in[18];

  char* ws = (char*)d_ws;
  const size_t SZ = (size_t)ROWS_*256*2;                 // 29,491,200 B
  unsigned short* kbuf = (unsigned short*)(ws);          // [0, SZ)
  unsigned short* vbuf = (unsigned short*)(ws + SZ);     // [SZ, 2SZ)
  unsigned short* xw   = (unsigned short*)(ws + 2*SZ);   // [2SZ,3SZ) later: ao
  unsigned short* qbuf = (unsigned short*)(ws + 3*SZ);   // [3SZ,4SZ) later: xn2
  unsigned short* aob  = xw;
  unsigned short* xn2  = qbuf;
  float* posq = (float*)(ws + 4*SZ);                     // 16KB
  float* posk = posq + 16*256;                           // 16KB
  int*   flag = (int*)(ws + 4*SZ + 32768);
  unsigned short* wt = (unsigned short*)(ws + 4*SZ + 65536);  // 1.5MB bf16 WT
  unsigned short* hb = (unsigned short*)ws;              // MLP chunk: [0,2SZ)
  void* x1 = d_out;                                      // x1 lives in d_out

  unsigned short* wtqkv = wt;            // q|k|v contiguous: WT[768][256]
  unsigned short* wto = wt + 196608;
  unsigned short* wt1 = wt + 262144;
  unsigned short* wt2 = wt + 524288;

  k_detect<<<1,64,0,stream>>>((const unsigned short*)x, flag);
  k_prepw<<<dim3(1024,6),256,0,stream>>>(Wq,Wk,Wv,Wo,W1,W2, wt, flag);
  k_posqk<<<16,256,0,stream>>>(ce, Wq, bq, Wk, bk, posq, posk, flag);
  k_ln1<<<14400,256,0,stream>>>(x, g1, be1, xw, flag);
  k_gemm_qkv<<<2700,256,0,stream>>>(xw, wtqkv, posq, posk, bv, qbuf, kbuf, vbuf, flag);
  k_attn<<<3840,256,0,stream>>>(qbuf, kbuf, vbuf, rb, aob, flag);
  k_gemm_wo<<<900,256,0,stream>>>(aob, wto, bo, x, x1, flag);
  k_ln2<<<14400,256,0,stream>>>(x1, g2, be2, xn2, flag);
  for (int chk=0; chk<2; ++chk){
    const int row0 = chk*28800;
    k_mlp1<<<1800,256,0,stream>>>(xn2, wt1, b1, hb, row0, flag);
    k_mlp2<<<450,256,0,stream>>>(hb, wt2, b2, x1, d_out, row0, flag);
  }
}

// Round 6
// 389.066 us; speedup vs baseline: 3.7004x; 1.0279x over previous
//
#include <hip/hip_runtime.h>

#define DI __device__ __forceinline__

constexpr int SH_=2, SW_=3;
constexpr int ROWS_=57600;            // B*NW*T*N == B*T*H*W
constexpr float SCALE_=0.17677669529663687f;   // 32^-0.5

typedef unsigned short u16x8 __attribute__((ext_vector_type(8)));
typedef short bf16x8 __attribute__((ext_vector_type(8)));
typedef float f32x4 __attribute__((ext_vector_type(4)));
typedef float f32x16 __attribute__((ext_vector_type(16)));

DI float bf2f(unsigned short u){ return __uint_as_float(((unsigned int)u)<<16); }
DI unsigned short f2bf(float f){
  unsigned int u = __float_as_uint(f);
  u += 0x7fffu + ((u>>16)&1u);          // round to nearest even
  return (unsigned short)(u>>16);
}
// flag f: 1 = external buffers are fp32, 0 = bf16
DI float ldf(const void* p, size_t i, int f){
  return f ? ((const float*)p)[i] : bf2f(((const unsigned short*)p)[i]);
}
DI float4 ldf4(const void* p, size_t i, int f){
  if (f) return *((const float4*)((const float*)p + i));
  ushort4 u = *((const ushort4*)((const unsigned short*)p + i));
  return make_float4(bf2f(u.x),bf2f(u.y),bf2f(u.z),bf2f(u.w));
}
DI void stf1(void* p, size_t i, float v, int f){
  if (f) ((float*)p)[i]=v; else ((unsigned short*)p)[i]=f2bf(v);
}

// async global->LDS, 16B per lane. LDS dest = wave-uniform base + lane*16.
DI void gload16(const void* g, void* l){
  __builtin_amdgcn_global_load_lds((const __attribute__((address_space(1))) unsigned int*)g,
                                   (__attribute__((address_space(3))) unsigned int*)l, 16, 0, 0);
}

// XCD-bijective remap (m204): n-tile varies fastest within an XCD so all
// n-tiles of one A-panel run consecutively on the same XCD -> A L2-reuse.
DI void xcd_remap(int wg, int nb, int nn, int& mt, int& nt){
  const int q = nb>>3, r = nb&7;
  const int x = wg & 7, i = wg >> 3;
  const int base = (x<r) ? x*(q+1) : r*(q+1) + (x-r)*q;
  const int work = base + i;
  mt = work / nn; nt = work - mt*nn;
}

// ---------------- dtype detection: fp32-as-bf16 is detectable ----------------
__global__ void k_detect(const unsigned short* __restrict__ xu, int* __restrict__ flag){
  unsigned short u = xu[threadIdx.x*2];
  int insane = ((u>>7)&0xFF) > 0xC0;
  unsigned long long m = __ballot(insane);
  if (threadIdx.x==0) *flag = m ? 1 : 0;
}

// ---------------- one-time weight convert+transpose to bf16 WT[n][k] ---------
__global__ __launch_bounds__(256) void k_prepw(
    const void* __restrict__ Wq, const void* __restrict__ Wk,
    const void* __restrict__ Wv, const void* __restrict__ Wo,
    const void* __restrict__ W1, const void* __restrict__ W2,
    unsigned short* __restrict__ wt, const int* __restrict__ flagp)
{
  const int f = *flagp;
  const void* src; int kb, total; size_t off;
  switch(blockIdx.y){
    case 0: src=Wq; kb=8;  total=65536;  off=0;      break;
    case 1: src=Wk; kb=8;  total=65536;  off=65536;  break;
    case 2: src=Wv; kb=8;  total=65536;  off=131072; break;
    case 3: src=Wo; kb=8;  total=65536;  off=196608; break;
    case 4: src=W1; kb=8;  total=262144; off=262144; break;   // [256][1024]
    default:src=W2; kb=10; total=262144; off=524288; break;   // [1024][256]
  }
  const int i = blockIdx.x*256 + threadIdx.x;
  if (i >= total) return;
  const int K = 1<<kb, N = total>>kb;
  const int n = i>>kb, k = i&(K-1);
  wt[off + (size_t)n*K + k] = f2bf(ldf(src, (size_t)k*N + n, f));
}

// ---------------- per-(b,t) positional bias folded through Wq/Wk -------------
__global__ __launch_bounds__(256) void k_posqk(const void* __restrict__ ce,
    const void* __restrict__ Wq, const void* __restrict__ bq,
    const void* __restrict__ Wk, const void* __restrict__ bk,
    float* __restrict__ posq, float* __restrict__ posk, const int* __restrict__ flagp)
{
  const int f = *flagp;
  const int bt = blockIdx.x, co = threadIdx.x;
  float aq = ldf(bq,co,f), ak = ldf(bk,co,f);
  for (int ci=0; ci<256; ++ci){
    float cv = ldf(ce,bt*256+ci,f);
    aq += cv*ldf(Wq,ci*256+co,f);
    ak += cv*ldf(Wk,ci*256+co,f);
  }
  posq[bt*256+co]=aq; posk[bt*256+co]=ak;
}

// ---------------- LN1 + cyclic shift + window partition ----------------------
__global__ __launch_bounds__(256) void k_ln1(const void* __restrict__ x,
    const void* __restrict__ g, const void* __restrict__ be,
    unsigned short* __restrict__ xw, const int* __restrict__ flagp)
{
  const int f = *flagp;
  const int lane = threadIdx.x & 63;
  const int wv   = threadIdx.x >> 6;
  const int rs   = blockIdx.x*4 + wv;           // spatial row (b,t,r,c)
  float4 u = ldf4(x, (size_t)rs*256 + lane*4, f);
  float s = u.x+u.y+u.z+u.w;
  #pragma unroll
  for (int o=32;o;o>>=1) s += __shfl_xor(s,o,64);
  const float mean = s*(1.f/256.f);
  float d0=u.x-mean, d1=u.y-mean, d2=u.z-mean, d3=u.w-mean;
  float qv = d0*d0+d1*d1+d2*d2+d3*d3;
  #pragma unroll
  for (int o=32;o;o>>=1) qv += __shfl_xor(qv,o,64);
  const float rstd = rsqrtf(qv*(1.f/256.f)+1e-5f);
  float4 gu = ldf4(g, lane*4, f);
  float4 bu = ldf4(be, lane*4, f);
  ushort4 o;
  o.x = f2bf(d0*rstd*gu.x+bu.x);
  o.y = f2bf(d1*rstd*gu.y+bu.y);
  o.z = f2bf(d2*rstd*gu.z+bu.z);
  o.w = f2bf(d3*rstd*gu.w+bu.w);
  const int c = rs % 60, r = (rs/60)%60, t = (rs/3600)&7, b = rs/28800;
  int r2 = r - SH_; if (r2<0) r2+=60;
  int c2 = c - SW_; if (c2<0) c2+=60;
  const int a=r2/5, ii=r2%5, bb=c2/6, jj=c2%6;
  const int rw = ((b*120 + a*10+bb)*8 + t)*30 + ii*6+jj;
  *reinterpret_cast<ushort4*>(xw + (size_t)rw*256 + lane*4) = o;
}

// ---------------- LN2 (spatial layout, x1 in out-dtype, bf16 out) ------------
__global__ __launch_bounds__(256) void k_ln2(const void* __restrict__ x1,
    const void* __restrict__ g, const void* __restrict__ be,
    unsigned short* __restrict__ xn2, const int* __restrict__ flagp)
{
  const int f = *flagp;
  const int lane = threadIdx.x & 63;
  const int wv   = threadIdx.x >> 6;
  const int rs   = blockIdx.x*4 + wv;
  float4 v = ldf4(x1, (size_t)rs*256 + lane*4, f);
  float s = v.x+v.y+v.z+v.w;
  #pragma unroll
  for (int o=32;o;o>>=1) s += __shfl_xor(s,o,64);
  const float mean = s*(1.f/256.f);
  float d0=v.x-mean, d1=v.y-mean, d2=v.z-mean, d3=v.w-mean;
  float qv = d0*d0+d1*d1+d2*d2+d3*d3;
  #pragma unroll
  for (int o=32;o;o>>=1) qv += __shfl_xor(qv,o,64);
  const float rstd = rsqrtf(qv*(1.f/256.f)+1e-5f);
  float4 gu = ldf4(g, lane*4, f);
  float4 bu = ldf4(be, lane*4, f);
  ushort4 o;
  o.x = f2bf(d0*rstd*gu.x+bu.x);
  o.y = f2bf(d1*rstd*gu.y+bu.y);
  o.z = f2bf(d2*rstd*gu.z+bu.z);
  o.w = f2bf(d3*rstd*gu.w+bu.w);
  *reinterpret_cast<ushort4*>(xn2 + (size_t)rs*256 + lane*4) = o;
}

// ---------------- MFMA 128x128 GEMM core, 3-deep pipeline --------------------
// A: [M][K] bf16 row-major. WT: [N][K] bf16 row-major. 4 waves, each a 64x64
// quadrant. LDS: 3 buffers x (A 128x32 + B 128x32) shorts = 48KB. Counted
// vmcnt(8): tiles t,t+1,t+2 in flight; awaited tile has aged 2 compute phases
// (covers ~900cy HBM latency). Stage target at step t was last read at t-1,
// fully consumed before t-1's end barrier -> no race.
template<int K>
DI void mfma_core128(const unsigned short* __restrict__ A, const unsigned short* __restrict__ WT,
                     const int m0, const int n0, f32x4 acc[4][4], unsigned short* lds)
{
  constexpr int STEPS = K/32;
  const int tid = threadIdx.x, lane = tid&63, wave = tid>>6;
  const int wm = (wave>>1)*64, wn = (wave&1)*64;
  const int fr = lane&15;
  const int kqs = ((lane>>4) ^ (fr&3))*8;   // swizzled k-part offset (shorts)
  #pragma unroll
  for (int i=0;i<4;++i)
    #pragma unroll
    for (int j=0;j<4;++j) acc[i][j] = (f32x4){0.f,0.f,0.f,0.f};
  const int c0 = wave*64 + lane;            // chunk 0..255 -> row=c>>2, part=c&3
  const int r0 = c0>>2, pp = c0&3;
  const int pl = pp ^ (r0&3);               // inverse-swizzled source part
  const unsigned short* Ab0 = A  + (size_t)(m0+r0)*K    + pl*8;
  const unsigned short* Ab1 = A  + (size_t)(m0+r0+64)*K + pl*8;
  const unsigned short* Wb0 = WT + (size_t)(n0+r0)*K    + pl*8;
  const unsigned short* Wb1 = WT + (size_t)(n0+r0+64)*K + pl*8;
  const int wsl = wave*512;
  #define STAGE_(d,k0) do{ \
    unsigned short* bse = lds + (d)*8192; \
    gload16(Ab0+(k0), bse + wsl); \
    gload16(Ab1+(k0), bse + 2048 + wsl); \
    gload16(Wb0+(k0), bse + 4096 + wsl); \
    gload16(Wb1+(k0), bse + 6144 + wsl); }while(0)
  STAGE_(0,0);
  STAGE_(1,32);
  int cur = 0;
  for (int t=0; t<STEPS; ++t){
    if (t+2 < STEPS){
      int nb = cur+2; if (nb>=3) nb-=3;
      STAGE_(nb, (t+2)*32);
      asm volatile("s_waitcnt vmcnt(8)" ::: "memory");
    } else if (t+2 == STEPS){
      asm volatile("s_waitcnt vmcnt(4)" ::: "memory");
    } else {
      asm volatile("s_waitcnt vmcnt(0)" ::: "memory");
    }
    __builtin_amdgcn_s_barrier();
    const unsigned short* At = lds + cur*8192;
    const unsigned short* Bt = At + 4096;
    bf16x8 af[4], bfv[4];
    #pragma unroll
    for (int mi=0;mi<4;++mi) af[mi]  = *(const bf16x8*)(At + (wm+mi*16+fr)*32 + kqs);
    #pragma unroll
    for (int ni=0;ni<4;++ni) bfv[ni] = *(const bf16x8*)(Bt + (wn+ni*16+fr)*32 + kqs);
    #pragma unroll
    for (int mi=0;mi<4;++mi)
      #pragma unroll
      for (int ni=0;ni<4;++ni)
        acc[mi][ni] = __builtin_amdgcn_mfma_f32_16x16x32_bf16(af[mi], bfv[ni], acc[mi][ni], 0,0,0);
    __builtin_amdgcn_s_barrier();
    cur = (cur+1==3)?0:cur+1;
  }
  #undef STAGE_
}

// ---------------- fused QKV projection (N=768: q|k|v) ------------------------
__global__ __launch_bounds__(256) void k_gemm_qkv(const unsigned short* __restrict__ Ain,
    const unsigned short* __restrict__ WT, const float* __restrict__ posq,
    const float* __restrict__ posk, const void* __restrict__ bv,
    unsigned short* __restrict__ qb, unsigned short* __restrict__ kb,
    unsigned short* __restrict__ vb2, const int* __restrict__ flagp)
{
  __shared__ __align__(16) unsigned short lds[24576];
  f32x4 acc[4][4];
  int mt, nt; xcd_remap(blockIdx.x, 2700, 6, mt, nt);
  const int m0 = mt*128, n0g = nt*128;
  mfma_core128<256>(Ain, WT, m0, n0g, acc, lds);
  const int f = *flagp;
  const int lane = threadIdx.x&63, wave = threadIdx.x>>6;
  const int wm = (wave>>1)*64, wn = (wave&1)*64;
  const int fr = lane&15, fq = lane>>4;
  const int seg = nt>>1;
  unsigned short* ob = seg==0? qb : (seg==1? kb : vb2);
  const float* posb = seg==0? posq : posk;
  #pragma unroll
  for (int mi=0;mi<4;++mi){
    #pragma unroll
    for (int r=0;r<4;++r){
      const int row = m0+wm+mi*16+fq*4+r;
      const int bt2 = (row/28800)*8 + (row/30)%8;
      #pragma unroll
      for (int ni=0;ni<4;++ni){
        const int colm = (n0g + wn + ni*16 + fr) & 255;
        const float bvv = (seg<2) ? posb[bt2*256+colm] : ldf(bv,colm,f);
        ob[(size_t)row*256 + colm] = f2bf(acc[mi][ni][r] + bvv);
      }
    }
  }
}

// ---------------- MFMA attention: one wave per (bt, head) --------------------
__global__ __launch_bounds__(256) void k_attn(const unsigned short* __restrict__ q,
    const unsigned short* __restrict__ k, const unsigned short* __restrict__ v,
    const void* __restrict__ relb, unsigned short* __restrict__ ao,
    const int* __restrict__ flagp)
{
  __shared__ __align__(16) unsigned short vt[4][32*40];   // per-wave V^T [d][m]
  __shared__ __align__(16) unsigned short pa[4][32*40];   // per-wave P [n][m]
  const int f = *flagp;
  const int tid = threadIdx.x, lane = tid&63, wave = tid>>6;
  const int task = blockIdx.x*4 + wave;      // (bt, head)
  const int h = task & 7, bt = task >> 3;
  const int wi = (bt>>3) % 120;
  const int a_ = wi/10, bb_ = wi%10;
  const size_t base = (size_t)bt*7680 + h*32;
  unsigned short* vtw = &vt[wave][0];
  unsigned short* paw = &pa[wave][0];
  // stage V transposed (rows m -> cols), zero-pad m=30,31
  if (lane < 60){
    const int m = lane>>1, hf = lane&1;
    const unsigned short* src = v + base + (size_t)m*256 + hf*16;
    u16x8 r0 = *(const u16x8*)(src);
    u16x8 r1 = *(const u16x8*)(src+8);
    #pragma unroll
    for (int j=0;j<8;++j){ vtw[(hf*16+j)*40+m] = r0[j]; vtw[(hf*16+8+j)*40+m] = r1[j]; }
  }
  vtw[(lane>>1)*40 + 30 + (lane&1)] = 0;
  // QK^T: accS[r] = scores[n=lane&31][m_r], m_r=(r&3)+8*(r>>2)+4*(lane>>5)
  const int n  = lane&31;
  const int hl = lane>>5;
  f32x16 accS = {};
  {
    const unsigned short* ka = k + base + (size_t)n*256 + hl*8;
    const unsigned short* qa = q + base + (size_t)n*256 + hl*8;
    bf16x8 a0 = *(const bf16x8*)(ka);
    bf16x8 b0 = *(const bf16x8*)(qa);
    accS = __builtin_amdgcn_mfma_f32_32x32x16_bf16(a0, b0, accS, 0,0,0);
    bf16x8 a1 = *(const bf16x8*)(ka+16);
    bf16x8 b1 = *(const bf16x8*)(qa+16);
    accS = __builtin_amdgcn_mfma_f32_32x32x16_bf16(a1, b1, accS, 0,0,0);
  }
  // softmax over m (per-lane: 16 regs + partner half via shfl_xor 32)
  const int nc  = (n < 30) ? n : 29;
  const int in_ = nc/6, jn = nc - in_*6;
  const int rn = a_*5+in_, cn = bb_*6+jn;
  const int lnl = (rn<55?0:(rn<58?1:2))*3 + (cn<54?0:(cn<57?1:2));
  #pragma unroll
  for (int r=0;r<16;++r){
    const int m = (r&3) + 8*(r>>2) + 4*hl;
    if (m < 30){
      const int im = m/6, jm = m - im*6;
      const int ridx = (in_-im+4)*11 + (jn-jm+5);
      const float bi = ldf(relb, ridx*8+h, f);
      const int rm = a_*5+im, cm = bb_*6+jm;
      const int lml = (rm<55?0:(rm<58?1:2))*3 + (cm<54?0:(cm<57?1:2));
      accS[r] = accS[r]*SCALE_ + bi + (lnl==lml ? 0.f : -100.f);
    } else accS[r] = -1e30f;
  }
  float mx = accS[0];
  #pragma unroll
  for (int r=1;r<16;++r) mx = fmaxf(mx, accS[r]);
  mx = fmaxf(mx, __shfl_xor(mx, 32, 64));
  float sum = 0.f;
  #pragma unroll
  for (int r=0;r<16;++r){ accS[r] = __expf(accS[r]-mx); sum += accS[r]; }
  sum += __shfl_xor(sum, 32, 64);
  const float inv = 1.f/sum;
  #pragma unroll
  for (int r=0;r<16;++r){
    const int m = (r&3)+8*(r>>2)+4*hl;
    paw[n*40 + m] = f2bf(accS[r]);
  }
  // PV: accO[r] = out[n][d_r]
  f32x16 accO = {};
  #pragma unroll
  for (int ks=0; ks<2; ++ks){
    bf16x8 av  = *(const bf16x8*)(vtw + n*40 + ks*16 + hl*8);
    bf16x8 pv  = *(const bf16x8*)(paw + n*40 + ks*16 + hl*8);
    accO = __builtin_amdgcn_mfma_f32_32x32x16_bf16(av, pv, accO, 0,0,0);
  }
  if (n < 30){
    #pragma unroll
    for (int g4=0; g4<4; ++g4){
      const int d0 = 8*g4 + 4*hl;
      ushort4 o;
      o.x = f2bf(accO[g4*4+0]*inv);
      o.y = f2bf(accO[g4*4+1]*inv);
      o.z = f2bf(accO[g4*4+2]*inv);
      o.w = f2bf(accO[g4*4+3]*inv);
      *(ushort4*)(ao + base + (size_t)n*256 + d0) = o;
    }
  }
}

// ---------------- Wo projection + window reverse + un-shift + residual -------
__global__ __launch_bounds__(256) void k_gemm_wo(const unsigned short* __restrict__ Ain,
    const unsigned short* __restrict__ WT, const void* __restrict__ bias,
    const void* __restrict__ xin, void* __restrict__ x1, const int* __restrict__ flagp)
{
  __shared__ __align__(16) unsigned short lds[24576];
  f32x4 acc[4][4];
  int mt, nt; xcd_remap(blockIdx.x, 900, 2, mt, nt);
  const int m0 = mt*128, n0 = nt*128;
  mfma_core128<256>(Ain, WT, m0, n0, acc, lds);
  const int f = *flagp;
  const int lane = threadIdx.x&63, wave = threadIdx.x>>6;
  const int wm = (wave>>1)*64, wn = (wave&1)*64;
  const int fr = lane&15, fq = lane>>4;
  #pragma unroll
  for (int mi=0;mi<4;++mi){
    #pragma unroll
    for (int r=0;r<4;++r){
      const int rw = m0+wm+mi*16+fq*4+r;
      const int nn = rw%30, t = (rw/30)%8, bw = rw/240;
      const int b = bw/120, wi = bw%120;
      const int a = wi/10, bb2 = wi%10, ii = nn/6, jj = nn%6;
      int rr = a*5+ii+SH_; if (rr>=60) rr-=60;
      int cc = bb2*6+jj+SW_; if (cc>=60) cc-=60;
      const size_t srow = ((size_t)((b*8+t)*60 + rr)*60 + cc);
      #pragma unroll
      for (int ni=0;ni<4;++ni){
        const int col = n0 + wn + ni*16 + fr;
        const float val = ldf(xin, srow*256+col, f) + acc[mi][ni][r] + ldf(bias,col,f);
        stf1(x1, srow*256+col, val, f);
      }
    }
  }
}

// ---------------- MLP1: xn2 @ W1 + b1 -> exact GELU -> h ---------------------
__global__ __launch_bounds__(256) void k_mlp1(const unsigned short* __restrict__ Ain,
    const unsigned short* __restrict__ WT, const void* __restrict__ bias,
    unsigned short* __restrict__ hb, const int row0, const int* __restrict__ flagp)
{
  __shared__ __align__(16) unsigned short lds[24576];
  f32x4 acc[4][4];
  int mt, nt; xcd_remap(blockIdx.x, 1800, 8, mt, nt);
  const int m0 = row0 + mt*128, n0 = nt*128;
  mfma_core128<256>(Ain, WT, m0, n0, acc, lds);
  const int f = *flagp;
  const int lane = threadIdx.x&63, wave = threadIdx.x>>6;
  const int wm = (wave>>1)*64, wn = (wave&1)*64;
  const int fr = lane&15, fq = lane>>4;
  #pragma unroll
  for (int mi=0;mi<4;++mi){
    #pragma unroll
    for (int ni=0;ni<4;++ni){
      const int col = n0 + wn + ni*16 + fr;
      const float bv = ldf(bias,col,f);
      #pragma unroll
      for (int r=0;r<4;++r){
        const int rl = m0 - row0 + wm + mi*16 + fq*4 + r;
        const float vv = acc[mi][ni][r] + bv;
        const float gg = 0.5f*vv*(1.f+erff(vv*0.70710678118654752f));
        hb[(size_t)rl*1024 + col] = f2bf(gg);
      }
    }
  }
}

// ---------------- MLP2: h @ W2 + b2 + x1 -> out ------------------------------
__global__ __launch_bounds__(256) void k_mlp2(const unsigned short* __restrict__ hbin,
    const unsigned short* __restrict__ WT, const void* __restrict__ bias,
    const void* x1, void* outb, const int row0, const int* __restrict__ flagp)
{
  __shared__ __align__(16) unsigned short lds[24576];
  f32x4 acc[4][4];
  int mt, nt; xcd_remap(blockIdx.x, 450, 2, mt, nt);
  const int m0l = mt*128, n0 = nt*128;
  mfma_core128<1024>(hbin, WT, m0l, n0, acc, lds);
  const int f = *flagp;
  const int lane = threadIdx.x&63, wave = threadIdx.x>>6;
  const int wm = (wave>>1)*64, wn = (wave&1)*64;
  const int fr = lane&15, fq = lane>>4;
  #pragma unroll
  for (int mi=0;mi<4;++mi){
    #pragma unroll
    for (int ni=0;ni<4;++ni){
      const int col = n0 + wn + ni*16 + fr;
      const float bv = ldf(bias,col,f);
      #pragma unroll
      for (int r=0;r<4;++r){
        const int grow = row0 + m0l + wm + mi*16 + fq*4 + r;
        const float val = ldf(x1, (size_t)grow*256+col, f) + acc[mi][ni][r] + bv;
        stf1(outb, (size_t)grow*256+col, val, f);
      }
    }
  }
}

extern "C" void kernel_launch(void* const* d_in, const int* in_sizes, int n_in,
                              void* d_out, int out_size, void* d_ws, size_t ws_size,
                              hipStream_t stream)
{
  const void* x   = d_in[0];
  const void* ce  = d_in[1];
  const void* g1  = d_in[2];
  const void* be1 = d_in[3];
  const void* Wq  = d_in[4];
  const void* bq  = d_in[5];
  const void* Wk  = d_in[6];
  const void* bk  = d_in[7];
  const void* Wv  = d_in[8];
  const void* bv  = d_in[9];
  const void* rb  = d_in[10];
  const void* Wo  = d_in[11];
  const void* bo  = d_in[12];
  const void* g2  = d_in[13];
  const void* be2 = d_in[14];
  const void* W1  = d_in[15];
  const void* b1  = d_in[16];
  const void* W2  = d_in[17];
  const void* b2  = d_in[18];

  char* ws = (char*)d_ws;
  const size_t SZ = (size_t)ROWS_*256*2;                 // 29,491,200 B
  unsigned short* kbuf = (unsigned short*)(ws);          // [0, SZ)
  unsigned short* vbuf = (unsigned short*)(ws + SZ);     // [SZ, 2SZ)
  unsigned short* xw   = (unsigned short*)(ws + 2*SZ);   // [2SZ,3SZ) later: ao
  unsigned short* qbuf = (unsigned short*)(ws + 3*SZ);   // [3SZ,4SZ) later: xn2
  unsigned short* aob  = xw;
  unsigned short* xn2  = qbuf;
  float* posq = (float*)(ws + 4*SZ);                     // 16KB
  float* posk = posq + 16*256;                           // 16KB
  int*   flag = (int*)(ws + 4*SZ + 32768);
  unsigned short* wt = (unsigned short*)(ws + 4*SZ + 65536);  // 1.5MB bf16 WT
  unsigned short* hb = (unsigned short*)ws;              // MLP chunk: [0,2SZ)
  void* x1 = d_out;                                      // x1 lives in d_out

  unsigned short* wtqkv = wt;            // q|k|v contiguous: WT[768][256]
  unsigned short* wto = wt + 196608;
  unsigned short* wt1 = wt + 262144;
  unsigned short* wt2 = wt + 524288;

  k_detect<<<1,64,0,stream>>>((const unsigned short*)x, flag);
  k_prepw<<<dim3(1024,6),256,0,stream>>>(Wq,Wk,Wv,Wo,W1,W2, wt, flag);
  k_posqk<<<16,256,0,stream>>>(ce, Wq, bq, Wk, bk, posq, posk, flag);
  k_ln1<<<14400,256,0,stream>>>(x, g1, be1, xw, flag);
  k_gemm_qkv<<<2700,256,0,stream>>>(xw, wtqkv, posq, posk, bv, qbuf, kbuf, vbuf, flag);
  k_attn<<<3840,256,0,stream>>>(qbuf, kbuf, vbuf, rb, aob, flag);
  k_gemm_wo<<<900,256,0,stream>>>(aob, wto, bo, x, x1, flag);
  k_ln2<<<14400,256,0,stream>>>(x1, g2, be2, xn2, flag);
  for (int chk=0; chk<2; ++chk){
    const int row0 = chk*28800;
    k_mlp1<<<1800,256,0,stream>>>(xn2, wt1, b1, hb, row0, flag);
    k_mlp2<<<450,256,0,stream>>>(hb, wt2, b2, x1, d_out, row0, flag);
  }
}

// Round 7
// 338.262 us; speedup vs baseline: 4.2562x; 1.1502x over previous
//
#include <hip/hip_runtime.h>

#define DI __device__ __forceinline__

constexpr int SH_=2, SW_=3;
constexpr int ROWS_=57600;            // B*NW*T*N == B*T*H*W
constexpr float SCALE_=0.17677669529663687f;   // 32^-0.5

typedef unsigned short u16x8 __attribute__((ext_vector_type(8)));
typedef short bf16x8 __attribute__((ext_vector_type(8)));
typedef float f32x4 __attribute__((ext_vector_type(4)));
typedef float f32x16 __attribute__((ext_vector_type(16)));

DI float bf2f(unsigned short u){ return __uint_as_float(((unsigned int)u)<<16); }
DI unsigned short f2bf(float f){
  unsigned int u = __float_as_uint(f);
  u += 0x7fffu + ((u>>16)&1u);          // round to nearest even
  return (unsigned short)(u>>16);
}
// flag f: 1 = external buffers are fp32, 0 = bf16
DI float ldf(const void* p, size_t i, int f){
  return f ? ((const float*)p)[i] : bf2f(((const unsigned short*)p)[i]);
}
DI float4 ldf4(const void* p, size_t i, int f){
  if (f) return *((const float4*)((const float*)p + i));
  ushort4 u = *((const ushort4*)((const unsigned short*)p + i));
  return make_float4(bf2f(u.x),bf2f(u.y),bf2f(u.z),bf2f(u.w));
}
DI void stf1(void* p, size_t i, float v, int f){
  if (f) ((float*)p)[i]=v; else ((unsigned short*)p)[i]=f2bf(v);
}

// async global->LDS, 16B per lane. LDS dest = wave-uniform base + lane*16.
DI void gload16(const void* g, void* l){
  __builtin_amdgcn_global_load_lds((const __attribute__((address_space(1))) unsigned int*)g,
                                   (__attribute__((address_space(3))) unsigned int*)l, 16, 0, 0);
}

// XCD-bijective remap (m204): n-tile varies fastest within an XCD so all
// n-tiles of one A-panel run consecutively on the same XCD -> A L2-reuse.
DI void xcd_remap(int wg, int nb, int nn, int& mt, int& nt){
  const int q = nb>>3, r = nb&7;
  const int x = wg & 7, i = wg >> 3;
  const int base = (x<r) ? x*(q+1) : r*(q+1) + (x-r)*q;
  const int work = base + i;
  mt = work / nn; nt = work - mt*nn;
}

// ---------------- dtype detection: fp32-as-bf16 is detectable ----------------
__global__ void k_detect(const unsigned short* __restrict__ xu, int* __restrict__ flag){
  unsigned short u = xu[threadIdx.x*2];
  int insane = ((u>>7)&0xFF) > 0xC0;
  unsigned long long m = __ballot(insane);
  if (threadIdx.x==0) *flag = m ? 1 : 0;
}

// ---------------- one-time weight convert+transpose to bf16 WT[n][k] ---------
__global__ __launch_bounds__(256) void k_prepw(
    const void* __restrict__ Wq, const void* __restrict__ Wk,
    const void* __restrict__ Wv, const void* __restrict__ Wo,
    const void* __restrict__ W1, const void* __restrict__ W2,
    unsigned short* __restrict__ wt, const int* __restrict__ flagp)
{
  const int f = *flagp;
  const void* src; int kb, total; size_t off;
  switch(blockIdx.y){
    case 0: src=Wq; kb=8;  total=65536;  off=0;      break;
    case 1: src=Wk; kb=8;  total=65536;  off=65536;  break;
    case 2: src=Wv; kb=8;  total=65536;  off=131072; break;
    case 3: src=Wo; kb=8;  total=65536;  off=196608; break;
    case 4: src=W1; kb=8;  total=262144; off=262144; break;   // [256][1024]
    default:src=W2; kb=10; total=262144; off=524288; break;   // [1024][256]
  }
  const int i = blockIdx.x*256 + threadIdx.x;
  if (i >= total) return;
  const int K = 1<<kb, N = total>>kb;
  const int n = i>>kb, k = i&(K-1);
  wt[off + (size_t)n*K + k] = f2bf(ldf(src, (size_t)k*N + n, f));
}

// ---------------- per-(b,t) positional bias folded through Wq/Wk -------------
__global__ __launch_bounds__(256) void k_posqk(const void* __restrict__ ce,
    const void* __restrict__ Wq, const void* __restrict__ bq,
    const void* __restrict__ Wk, const void* __restrict__ bk,
    float* __restrict__ posq, float* __restrict__ posk, const int* __restrict__ flagp)
{
  const int f = *flagp;
  const int bt = blockIdx.x, co = threadIdx.x;
  float aq = ldf(bq,co,f), ak = ldf(bk,co,f);
  for (int ci=0; ci<256; ++ci){
    float cv = ldf(ce,bt*256+ci,f);
    aq += cv*ldf(Wq,ci*256+co,f);
    ak += cv*ldf(Wk,ci*256+co,f);
  }
  posq[bt*256+co]=aq; posk[bt*256+co]=ak;
}

// ---------------- LN1 + cyclic shift + window partition ----------------------
__global__ __launch_bounds__(256) void k_ln1(const void* __restrict__ x,
    const void* __restrict__ g, const void* __restrict__ be,
    unsigned short* __restrict__ xw, const int* __restrict__ flagp)
{
  const int f = *flagp;
  const int lane = threadIdx.x & 63;
  const int wv   = threadIdx.x >> 6;
  const int rs   = blockIdx.x*4 + wv;           // spatial row (b,t,r,c)
  float4 u = ldf4(x, (size_t)rs*256 + lane*4, f);
  float s = u.x+u.y+u.z+u.w;
  #pragma unroll
  for (int o=32;o;o>>=1) s += __shfl_xor(s,o,64);
  const float mean = s*(1.f/256.f);
  float d0=u.x-mean, d1=u.y-mean, d2=u.z-mean, d3=u.w-mean;
  float qv = d0*d0+d1*d1+d2*d2+d3*d3;
  #pragma unroll
  for (int o=32;o;o>>=1) qv += __shfl_xor(qv,o,64);
  const float rstd = rsqrtf(qv*(1.f/256.f)+1e-5f);
  float4 gu = ldf4(g, lane*4, f);
  float4 bu = ldf4(be, lane*4, f);
  ushort4 o;
  o.x = f2bf(d0*rstd*gu.x+bu.x);
  o.y = f2bf(d1*rstd*gu.y+bu.y);
  o.z = f2bf(d2*rstd*gu.z+bu.z);
  o.w = f2bf(d3*rstd*gu.w+bu.w);
  const int c = rs % 60, r = (rs/60)%60, t = (rs/3600)&7, b = rs/28800;
  int r2 = r - SH_; if (r2<0) r2+=60;
  int c2 = c - SW_; if (c2<0) c2+=60;
  const int a=r2/5, ii=r2%5, bb=c2/6, jj=c2%6;
  const int rw = ((b*120 + a*10+bb)*8 + t)*30 + ii*6+jj;
  *reinterpret_cast<ushort4*>(xw + (size_t)rw*256 + lane*4) = o;
}

// ---------------- LN2 (spatial layout, x1 in out-dtype, bf16 out) ------------
__global__ __launch_bounds__(256) void k_ln2(const void* __restrict__ x1,
    const void* __restrict__ g, const void* __restrict__ be,
    unsigned short* __restrict__ xn2, const int* __restrict__ flagp)
{
  const int f = *flagp;
  const int lane = threadIdx.x & 63;
  const int wv   = threadIdx.x >> 6;
  const int rs   = blockIdx.x*4 + wv;
  float4 v = ldf4(x1, (size_t)rs*256 + lane*4, f);
  float s = v.x+v.y+v.z+v.w;
  #pragma unroll
  for (int o=32;o;o>>=1) s += __shfl_xor(s,o,64);
  const float mean = s*(1.f/256.f);
  float d0=v.x-mean, d1=v.y-mean, d2=v.z-mean, d3=v.w-mean;
  float qv = d0*d0+d1*d1+d2*d2+d3*d3;
  #pragma unroll
  for (int o=32;o;o>>=1) qv += __shfl_xor(qv,o,64);
  const float rstd = rsqrtf(qv*(1.f/256.f)+1e-5f);
  float4 gu = ldf4(g, lane*4, f);
  float4 bu = ldf4(be, lane*4, f);
  ushort4 o;
  o.x = f2bf(d0*rstd*gu.x+bu.x);
  o.y = f2bf(d1*rstd*gu.y+bu.y);
  o.z = f2bf(d2*rstd*gu.z+bu.z);
  o.w = f2bf(d3*rstd*gu.w+bu.w);
  *reinterpret_cast<ushort4*>(xn2 + (size_t)rs*256 + lane*4) = o;
}

// ---------------- MFMA 128x128 GEMM core: 8 waves, 3-deep pipeline -----------
// A: [M][K] bf16 row-major. WT: [N][K] bf16 row-major. 8 waves, each a 64x32
// quadrant (acc 4x2 f32x4 = 32 AGPR -> ~88 regs total -> 5 waves/SIMD).
// LDS: 3 buffers x (A 128x32 + B 128x32 shorts) = 48KB. Waves 0-3 stage A,
// waves 4-7 stage B; 2 gloads/wave/step; counted vmcnt(4) (tile t aged 2
// compute phases). Source parts pre-swizzled (pl = pp^(row&3)), ds_read uses
// matching kqs XOR -> canonical fragment after double-XOR cancel.
template<int K>
DI void mfma_core128(const unsigned short* __restrict__ A, const unsigned short* __restrict__ WT,
                     const int m0, const int n0, f32x4 acc[4][2], unsigned short* lds)
{
  constexpr int STEPS = K/32;
  const int tid = threadIdx.x, lane = tid&63, wave = tid>>6;
  const int wm = (wave>>2)*64, wn = (wave&3)*32;
  const int fr = lane&15;
  const int kqs = ((lane>>4) ^ (fr&3))*8;   // swizzled k-part offset (shorts)
  #pragma unroll
  for (int i=0;i<4;++i)
    #pragma unroll
    for (int j=0;j<2;++j) acc[i][j] = (f32x4){0.f,0.f,0.f,0.f};
  const int isB = wave>>2;                  // waves 0-3: A, waves 4-7: B
  const int c0 = (wave&3)*128 + lane;       // chunk id in half [0,512)
  const int c1 = c0 + 64;
  const int r0=c0>>2, p0=((c0&3)^(r0&3));
  const int r1=c1>>2, p1=((c1&3)^(r1&3));
  const unsigned short* gb = isB ? (WT + (size_t)n0*K) : (A + (size_t)m0*K);
  const unsigned short* g0 = gb + (size_t)r0*K + p0*8;
  const unsigned short* g1 = gb + (size_t)r1*K + p1*8;
  const int ldso = isB*4096 + (wave&3)*1024;   // shorts
  #define STAGE_(d,k0) do{ \
    unsigned short* bse = lds + (d)*8192 + ldso; \
    gload16(g0+(k0), bse); \
    gload16(g1+(k0), bse+512); }while(0)
  STAGE_(0,0);
  STAGE_(1,32);
  int cur = 0;
  for (int t=0; t<STEPS; ++t){
    if (t+2 < STEPS){
      int nb = cur+2; if (nb>=3) nb-=3;
      STAGE_(nb, (t+2)*32);
      asm volatile("s_waitcnt vmcnt(4)" ::: "memory");
    } else if (t+2 == STEPS){
      asm volatile("s_waitcnt vmcnt(2)" ::: "memory");
    } else {
      asm volatile("s_waitcnt vmcnt(0)" ::: "memory");
    }
    __builtin_amdgcn_s_barrier();
    const unsigned short* At = lds + cur*8192;
    const unsigned short* Bt = At + 4096;
    bf16x8 af[4], bfv[2];
    #pragma unroll
    for (int mi=0;mi<4;++mi) af[mi]  = *(const bf16x8*)(At + (wm+mi*16+fr)*32 + kqs);
    #pragma unroll
    for (int ni=0;ni<2;++ni) bfv[ni] = *(const bf16x8*)(Bt + (wn+ni*16+fr)*32 + kqs);
    #pragma unroll
    for (int mi=0;mi<4;++mi)
      #pragma unroll
      for (int ni=0;ni<2;++ni)
        acc[mi][ni] = __builtin_amdgcn_mfma_f32_16x16x32_bf16(af[mi], bfv[ni], acc[mi][ni], 0,0,0);
    __builtin_amdgcn_s_barrier();
    cur = (cur+1==3)?0:cur+1;
  }
  #undef STAGE_
}

// ---------------- fused QKV projection (N=768: q|k|v) ------------------------
__global__ __launch_bounds__(512,5) void k_gemm_qkv(const unsigned short* __restrict__ Ain,
    const unsigned short* __restrict__ WT, const float* __restrict__ posq,
    const float* __restrict__ posk, const void* __restrict__ bv,
    unsigned short* __restrict__ qb, unsigned short* __restrict__ kb,
    unsigned short* __restrict__ vb2, const int* __restrict__ flagp)
{
  __shared__ __align__(16) unsigned short lds[24576];
  f32x4 acc[4][2];
  int mt, nt; xcd_remap(blockIdx.x, 2700, 6, mt, nt);
  const int m0 = mt*128, n0g = nt*128;
  mfma_core128<256>(Ain, WT, m0, n0g, acc, lds);
  const int f = *flagp;
  const int lane = threadIdx.x&63, wave = threadIdx.x>>6;
  const int wm = (wave>>2)*64, wn = (wave&3)*32;
  const int fr = lane&15, fq = lane>>4;
  const int seg = nt>>1;
  unsigned short* ob = seg==0? qb : (seg==1? kb : vb2);
  const float* posb = seg==0? posq : posk;
  #pragma unroll
  for (int mi=0;mi<4;++mi){
    #pragma unroll
    for (int r=0;r<4;++r){
      const int row = m0+wm+mi*16+fq*4+r;
      const int bt2 = (row/28800)*8 + (row/30)%8;
      #pragma unroll
      for (int ni=0;ni<2;++ni){
        const int colm = (n0g + wn + ni*16 + fr) & 255;
        const float bvv = (seg<2) ? posb[bt2*256+colm] : ldf(bv,colm,f);
        ob[(size_t)row*256 + colm] = f2bf(acc[mi][ni][r] + bvv);
      }
    }
  }
}

// ---------------- MFMA attention: one wave per (bt, head) --------------------
__global__ __launch_bounds__(256) void k_attn(const unsigned short* __restrict__ q,
    const unsigned short* __restrict__ k, const unsigned short* __restrict__ v,
    const void* __restrict__ relb, unsigned short* __restrict__ ao,
    const int* __restrict__ flagp)
{
  __shared__ __align__(16) unsigned short vt[4][32*40];   // per-wave V^T [d][m]
  __shared__ __align__(16) unsigned short pa[4][32*40];   // per-wave P [n][m]
  const int f = *flagp;
  const int tid = threadIdx.x, lane = tid&63, wave = tid>>6;
  const int task = blockIdx.x*4 + wave;      // (bt, head)
  const int h = task & 7, bt = task >> 3;
  const int wi = (bt>>3) % 120;
  const int a_ = wi/10, bb_ = wi%10;
  const size_t base = (size_t)bt*7680 + h*32;
  unsigned short* vtw = &vt[wave][0];
  unsigned short* paw = &pa[wave][0];
  // stage V transposed (rows m -> cols), zero-pad m=30,31
  if (lane < 60){
    const int m = lane>>1, hf = lane&1;
    const unsigned short* src = v + base + (size_t)m*256 + hf*16;
    u16x8 r0 = *(const u16x8*)(src);
    u16x8 r1 = *(const u16x8*)(src+8);
    #pragma unroll
    for (int j=0;j<8;++j){ vtw[(hf*16+j)*40+m] = r0[j]; vtw[(hf*16+8+j)*40+m] = r1[j]; }
  }
  vtw[(lane>>1)*40 + 30 + (lane&1)] = 0;
  // QK^T: accS[r] = scores[n=lane&31][m_r], m_r=(r&3)+8*(r>>2)+4*(lane>>5)
  const int n  = lane&31;
  const int hl = lane>>5;
  f32x16 accS = {};
  {
    const unsigned short* ka = k + base + (size_t)n*256 + hl*8;
    const unsigned short* qa = q + base + (size_t)n*256 + hl*8;
    bf16x8 a0 = *(const bf16x8*)(ka);
    bf16x8 b0 = *(const bf16x8*)(qa);
    accS = __builtin_amdgcn_mfma_f32_32x32x16_bf16(a0, b0, accS, 0,0,0);
    bf16x8 a1 = *(const bf16x8*)(ka+16);
    bf16x8 b1 = *(const bf16x8*)(qa+16);
    accS = __builtin_amdgcn_mfma_f32_32x32x16_bf16(a1, b1, accS, 0,0,0);
  }
  // softmax over m (per-lane: 16 regs + partner half via shfl_xor 32)
  const int nc  = (n < 30) ? n : 29;
  const int in_ = nc/6, jn = nc - in_*6;
  const int rn = a_*5+in_, cn = bb_*6+jn;
  const int lnl = (rn<55?0:(rn<58?1:2))*3 + (cn<54?0:(cn<57?1:2));
  #pragma unroll
  for (int r=0;r<16;++r){
    const int m = (r&3) + 8*(r>>2) + 4*hl;
    if (m < 30){
      const int im = m/6, jm = m - im*6;
      const int ridx = (in_-im+4)*11 + (jn-jm+5);
      const float bi = ldf(relb, ridx*8+h, f);
      const int rm = a_*5+im, cm = bb_*6+jm;
      const int lml = (rm<55?0:(rm<58?1:2))*3 + (cm<54?0:(cm<57?1:2));
      accS[r] = accS[r]*SCALE_ + bi + (lnl==lml ? 0.f : -100.f);
    } else accS[r] = -1e30f;
  }
  float mx = accS[0];
  #pragma unroll
  for (int r=1;r<16;++r) mx = fmaxf(mx, accS[r]);
  mx = fmaxf(mx, __shfl_xor(mx, 32, 64));
  float sum = 0.f;
  #pragma unroll
  for (int r=0;r<16;++r){ accS[r] = __expf(accS[r]-mx); sum += accS[r]; }
  sum += __shfl_xor(sum, 32, 64);
  const float inv = 1.f/sum;
  #pragma unroll
  for (int r=0;r<16;++r){
    const int m = (r&3)+8*(r>>2)+4*hl;
    paw[n*40 + m] = f2bf(accS[r]);
  }
  // PV: accO[r] = out[n][d_r]
  f32x16 accO = {};
  #pragma unroll
  for (int ks=0; ks<2; ++ks){
    bf16x8 av  = *(const bf16x8*)(vtw + n*40 + ks*16 + hl*8);
    bf16x8 pv  = *(const bf16x8*)(paw + n*40 + ks*16 + hl*8);
    accO = __builtin_amdgcn_mfma_f32_32x32x16_bf16(av, pv, accO, 0,0,0);
  }
  if (n < 30){
    #pragma unroll
    for (int g4=0; g4<4; ++g4){
      const int d0 = 8*g4 + 4*hl;
      ushort4 o;
      o.x = f2bf(accO[g4*4+0]*inv);
      o.y = f2bf(accO[g4*4+1]*inv);
      o.z = f2bf(accO[g4*4+2]*inv);
      o.w = f2bf(accO[g4*4+3]*inv);
      *(ushort4*)(ao + base + (size_t)n*256 + d0) = o;
    }
  }
}

// ---------------- Wo projection + window reverse + un-shift + residual -------
__global__ __launch_bounds__(512,5) void k_gemm_wo(const unsigned short* __restrict__ Ain,
    const unsigned short* __restrict__ WT, const void* __restrict__ bias,
    const void* __restrict__ xin, void* __restrict__ x1, const int* __restrict__ flagp)
{
  __shared__ __align__(16) unsigned short lds[24576];
  f32x4 acc[4][2];
  int mt, nt; xcd_remap(blockIdx.x, 900, 2, mt, nt);
  const int m0 = mt*128, n0 = nt*128;
  mfma_core128<256>(Ain, WT, m0, n0, acc, lds);
  const int f = *flagp;
  const int lane = threadIdx.x&63, wave = threadIdx.x>>6;
  const int wm = (wave>>2)*64, wn = (wave&3)*32;
  const int fr = lane&15, fq = lane>>4;
  #pragma unroll
  for (int mi=0;mi<4;++mi){
    #pragma unroll
    for (int r=0;r<4;++r){
      const int rw = m0+wm+mi*16+fq*4+r;
      const int nn = rw%30, t = (rw/30)%8, bw = rw/240;
      const int b = bw/120, wi = bw%120;
      const int a = wi/10, bb2 = wi%10, ii = nn/6, jj = nn%6;
      int rr = a*5+ii+SH_; if (rr>=60) rr-=60;
      int cc = bb2*6+jj+SW_; if (cc>=60) cc-=60;
      const size_t srow = ((size_t)((b*8+t)*60 + rr)*60 + cc);
      #pragma unroll
      for (int ni=0;ni<2;++ni){
        const int col = n0 + wn + ni*16 + fr;
        const float val = ldf(xin, srow*256+col, f) + acc[mi][ni][r] + ldf(bias,col,f);
        stf1(x1, srow*256+col, val, f);
      }
    }
  }
}

// ---------------- MLP1: xn2 @ W1 + b1 -> exact GELU -> h ---------------------
__global__ __launch_bounds__(512,5) void k_mlp1(const unsigned short* __restrict__ Ain,
    const unsigned short* __restrict__ WT, const void* __restrict__ bias,
    unsigned short* __restrict__ hb, const int row0, const int* __restrict__ flagp)
{
  __shared__ __align__(16) unsigned short lds[24576];
  f32x4 acc[4][2];
  int mt, nt; xcd_remap(blockIdx.x, 1800, 8, mt, nt);
  const int m0 = row0 + mt*128, n0 = nt*128;
  mfma_core128<256>(Ain, WT, m0, n0, acc, lds);
  const int f = *flagp;
  const int lane = threadIdx.x&63, wave = threadIdx.x>>6;
  const int wm = (wave>>2)*64, wn = (wave&3)*32;
  const int fr = lane&15, fq = lane>>4;
  #pragma unroll
  for (int mi=0;mi<4;++mi){
    #pragma unroll
    for (int ni=0;ni<2;++ni){
      const int col = n0 + wn + ni*16 + fr;
      const float bv = ldf(bias,col,f);
      #pragma unroll
      for (int r=0;r<4;++r){
        const int rl = m0 - row0 + wm + mi*16 + fq*4 + r;
        const float vv = acc[mi][ni][r] + bv;
        const float gg = 0.5f*vv*(1.f+erff(vv*0.70710678118654752f));
        hb[(size_t)rl*1024 + col] = f2bf(gg);
      }
    }
  }
}

// ---------------- MLP2: h @ W2 + b2 + x1 -> out ------------------------------
__global__ __launch_bounds__(512,5) void k_mlp2(const unsigned short* __restrict__ hbin,
    const unsigned short* __restrict__ WT, const void* __restrict__ bias,
    const void* x1, void* outb, const int row0, const int* __restrict__ flagp)
{
  __shared__ __align__(16) unsigned short lds[24576];
  f32x4 acc[4][2];
  int mt, nt; xcd_remap(blockIdx.x, 450, 2, mt, nt);
  const int m0l = mt*128, n0 = nt*128;
  mfma_core128<1024>(hbin, WT, m0l, n0, acc, lds);
  const int f = *flagp;
  const int lane = threadIdx.x&63, wave = threadIdx.x>>6;
  const int wm = (wave>>2)*64, wn = (wave&3)*32;
  const int fr = lane&15, fq = lane>>4;
  #pragma unroll
  for (int mi=0;mi<4;++mi){
    #pragma unroll
    for (int ni=0;ni<2;++ni){
      const int col = n0 + wn + ni*16 + fr;
      const float bv = ldf(bias,col,f);
      #pragma unroll
      for (int r=0;r<4;++r){
        const int grow = row0 + m0l + wm + mi*16 + fq*4 + r;
        const float val = ldf(x1, (size_t)grow*256+col, f) + acc[mi][ni][r] + bv;
        stf1(outb, (size_t)grow*256+col, val, f);
      }
    }
  }
}

extern "C" void kernel_launch(void* const* d_in, const int* in_sizes, int n_in,
                              void* d_out, int out_size, void* d_ws, size_t ws_size,
                              hipStream_t stream)
{
  const void* x   = d_in[0];
  const void* ce  = d_in[1];
  const void* g1  = d_in[2];
  const void* be1 = d_in[3];
  const void* Wq  = d_in[4];
  const void* bq  = d_in[5];
  const void* Wk  = d_in[6];
  const void* bk  = d_in[7];
  const void* Wv  = d_in[8];
  const void* bv  = d_in[9];
  const void* rb  = d_in[10];
  const void* Wo  = d_in[11];
  const void* bo  = d_in[12];
  const void* g2  = d_in[13];
  const void* be2 = d_in[14];
  const void* W1  = d_in[15];
  const void* b1  = d_in[16];
  const void* W2  = d_in[17];
  const void* b2  = d_in[18];

  char* ws = (char*)d_ws;
  const size_t SZ = (size_t)ROWS_*256*2;                 // 29,491,200 B
  unsigned short* kbuf = (unsigned short*)(ws);          // [0, SZ)
  unsigned short* vbuf = (unsigned short*)(ws + SZ);     // [SZ, 2SZ)
  unsigned short* xw   = (unsigned short*)(ws + 2*SZ);   // [2SZ,3SZ) later: ao
  unsigned short* qbuf = (unsigned short*)(ws + 3*SZ);   // [3SZ,4SZ) later: xn2
  unsigned short* aob  = xw;
  unsigned short* xn2  = qbuf;
  float* posq = (float*)(ws + 4*SZ);                     // 16KB
  float* posk = posq + 16*256;                           // 16KB
  int*   flag = (int*)(ws + 4*SZ + 32768);
  unsigned short* wt = (unsigned short*)(ws + 4*SZ + 65536);  // 1.5MB bf16 WT
  unsigned short* hb = (unsigned short*)ws;              // MLP chunk: [0,2SZ)
  void* x1 = d_out;                                      // x1 lives in d_out

  unsigned short* wtqkv = wt;            // q|k|v contiguous: WT[768][256]
  unsigned short* wto = wt + 196608;
  unsigned short* wt1 = wt + 262144;
  unsigned short* wt2 = wt + 524288;

  k_detect<<<1,64,0,stream>>>((const unsigned short*)x, flag);
  k_prepw<<<dim3(1024,6),256,0,stream>>>(Wq,Wk,Wv,Wo,W1,W2, wt, flag);
  k_posqk<<<16,256,0,stream>>>(ce, Wq, bq, Wk, bk, posq, posk, flag);
  k_ln1<<<14400,256,0,stream>>>(x, g1, be1, xw, flag);
  k_gemm_qkv<<<2700,512,0,stream>>>(xw, wtqkv, posq, posk, bv, qbuf, kbuf, vbuf, flag);
  k_attn<<<3840,256,0,stream>>>(qbuf, kbuf, vbuf, rb, aob, flag);
  k_gemm_wo<<<900,512,0,stream>>>(aob, wto, bo, x, x1, flag);
  k_ln2<<<14400,256,0,stream>>>(x1, g2, be2, xn2, flag);
  for (int chk=0; chk<2; ++chk){
    const int row0 = chk*28800;
    k_mlp1<<<1800,512,0,stream>>>(xn2, wt1, b1, hb, row0, flag);
    k_mlp2<<<450,512,0,stream>>>(hb, wt2, b2, x1, d_out, row0, flag);
  }
}

// Round 8
// 305.890 us; speedup vs baseline: 4.7066x; 1.1058x over previous
//
#include <hip/hip_runtime.h>

#define DI __device__ __forceinline__

constexpr int SH_=2, SW_=3;
constexpr int ROWS_=57600;            // B*NW*T*N == B*T*H*W
constexpr float SCALE_=0.17677669529663687f;   // 32^-0.5

typedef unsigned short u16x8 __attribute__((ext_vector_type(8)));
typedef short bf16x8 __attribute__((ext_vector_type(8)));
typedef float f32x4 __attribute__((ext_vector_type(4)));
typedef float f32x16 __attribute__((ext_vector_type(16)));

DI float bf2f(unsigned short u){ return __uint_as_float(((unsigned int)u)<<16); }
DI unsigned short f2bf(float f){
  unsigned int u = __float_as_uint(f);
  u += 0x7fffu + ((u>>16)&1u);          // round to nearest even
  return (unsigned short)(u>>16);
}
// flag f: 1 = external buffers are fp32, 0 = bf16
DI float ldf(const void* p, size_t i, int f){
  return f ? ((const float*)p)[i] : bf2f(((const unsigned short*)p)[i]);
}
DI float4 ldf4(const void* p, size_t i, int f){
  if (f) return *((const float4*)((const float*)p + i));
  ushort4 u = *((const ushort4*)((const unsigned short*)p + i));
  return make_float4(bf2f(u.x),bf2f(u.y),bf2f(u.z),bf2f(u.w));
}

// async global->LDS, 16B per lane. LDS dest = wave-uniform base + lane*16.
DI void gload16(const void* g, void* l){
  __builtin_amdgcn_global_load_lds((const __attribute__((address_space(1))) unsigned int*)g,
                                   (__attribute__((address_space(3))) unsigned int*)l, 16, 0, 0);
}

// XCD-bijective remap (m204): n-tile varies fastest within an XCD so all
// n-tiles of one A-panel run consecutively on the same XCD -> A L2-reuse.
DI void xcd_remap(int wg, int nb, int nn, int& mt, int& nt){
  const int q = nb>>3, r = nb&7;
  const int x = wg & 7, i = wg >> 3;
  const int base = (x<r) ? x*(q+1) : r*(q+1) + (x-r)*q;
  const int work = base + i;
  mt = work / nn; nt = work - mt*nn;
}

// ---------------- dtype detection: fp32-as-bf16 is detectable ----------------
__global__ void k_detect(const unsigned short* __restrict__ xu, int* __restrict__ flag){
  unsigned short u = xu[threadIdx.x*2];
  int insane = ((u>>7)&0xFF) > 0xC0;
  unsigned long long m = __ballot(insane);
  if (threadIdx.x==0) *flag = m ? 1 : 0;
}

// ---------------- one-time weight convert+transpose to bf16 WT[n][k] ---------
__global__ __launch_bounds__(256) void k_prepw(
    const void* __restrict__ Wq, const void* __restrict__ Wk,
    const void* __restrict__ Wv, const void* __restrict__ Wo,
    const void* __restrict__ W1, const void* __restrict__ W2,
    unsigned short* __restrict__ wt, const int* __restrict__ flagp)
{
  const int f = *flagp;
  const void* src; int kb, total; size_t off;
  switch(blockIdx.y){
    case 0: src=Wq; kb=8;  total=65536;  off=0;      break;
    case 1: src=Wk; kb=8;  total=65536;  off=65536;  break;
    case 2: src=Wv; kb=8;  total=65536;  off=131072; break;
    case 3: src=Wo; kb=8;  total=65536;  off=196608; break;
    case 4: src=W1; kb=8;  total=262144; off=262144; break;   // [256][1024]
    default:src=W2; kb=10; total=262144; off=524288; break;   // [1024][256]
  }
  const int i = blockIdx.x*256 + threadIdx.x;
  if (i >= total) return;
  const int K = 1<<kb, N = total>>kb;
  const int n = i>>kb, k = i&(K-1);
  wt[off + (size_t)n*K + k] = f2bf(ldf(src, (size_t)k*N + n, f));
}

// ---------------- per-(b,t) positional bias folded through Wq/Wk -------------
__global__ __launch_bounds__(256) void k_posqk(const void* __restrict__ ce,
    const void* __restrict__ Wq, const void* __restrict__ bq,
    const void* __restrict__ Wk, const void* __restrict__ bk,
    float* __restrict__ posq, float* __restrict__ posk, const int* __restrict__ flagp)
{
  const int f = *flagp;
  const int bt = blockIdx.x, co = threadIdx.x;
  float aq = ldf(bq,co,f), ak = ldf(bk,co,f);
  for (int ci=0; ci<256; ++ci){
    float cv = ldf(ce,bt*256+ci,f);
    aq += cv*ldf(Wq,ci*256+co,f);
    ak += cv*ldf(Wk,ci*256+co,f);
  }
  posq[bt*256+co]=aq; posk[bt*256+co]=ak;
}

// ---------------- LN1 + cyclic shift + window partition ----------------------
__global__ __launch_bounds__(256) void k_ln1(const void* __restrict__ x,
    const void* __restrict__ g, const void* __restrict__ be,
    unsigned short* __restrict__ xw, const int* __restrict__ flagp)
{
  const int f = *flagp;
  const int lane = threadIdx.x & 63;
  const int wv   = threadIdx.x >> 6;
  const int rs   = blockIdx.x*4 + wv;           // spatial row (b,t,r,c)
  float4 u = ldf4(x, (size_t)rs*256 + lane*4, f);
  float s = u.x+u.y+u.z+u.w;
  #pragma unroll
  for (int o=32;o;o>>=1) s += __shfl_xor(s,o,64);
  const float mean = s*(1.f/256.f);
  float d0=u.x-mean, d1=u.y-mean, d2=u.z-mean, d3=u.w-mean;
  float qv = d0*d0+d1*d1+d2*d2+d3*d3;
  #pragma unroll
  for (int o=32;o;o>>=1) qv += __shfl_xor(qv,o,64);
  const float rstd = rsqrtf(qv*(1.f/256.f)+1e-5f);
  float4 gu = ldf4(g, lane*4, f);
  float4 bu = ldf4(be, lane*4, f);
  ushort4 o;
  o.x = f2bf(d0*rstd*gu.x+bu.x);
  o.y = f2bf(d1*rstd*gu.y+bu.y);
  o.z = f2bf(d2*rstd*gu.z+bu.z);
  o.w = f2bf(d3*rstd*gu.w+bu.w);
  const int c = rs % 60, r = (rs/60)%60, t = (rs/3600)&7, b = rs/28800;
  int r2 = r - SH_; if (r2<0) r2+=60;
  int c2 = c - SW_; if (c2<0) c2+=60;
  const int a=r2/5, ii=r2%5, bb=c2/6, jj=c2%6;
  const int rw = ((b*120 + a*10+bb)*8 + t)*30 + ii*6+jj;
  *reinterpret_cast<ushort4*>(xw + (size_t)rw*256 + lane*4) = o;
}

// ---------------- LN2 (x1b bf16 in ws, bf16 out) ------------------------------
__global__ __launch_bounds__(256) void k_ln2(const unsigned short* __restrict__ x1b,
    const void* __restrict__ g, const void* __restrict__ be,
    unsigned short* __restrict__ xn2, const int* __restrict__ flagp)
{
  const int f = *flagp;
  const int lane = threadIdx.x & 63;
  const int wv   = threadIdx.x >> 6;
  const int rs   = blockIdx.x*4 + wv;
  float4 v = ldf4(x1b, (size_t)rs*256 + lane*4, 0);
  float s = v.x+v.y+v.z+v.w;
  #pragma unroll
  for (int o=32;o;o>>=1) s += __shfl_xor(s,o,64);
  const float mean = s*(1.f/256.f);
  float d0=v.x-mean, d1=v.y-mean, d2=v.z-mean, d3=v.w-mean;
  float qv = d0*d0+d1*d1+d2*d2+d3*d3;
  #pragma unroll
  for (int o=32;o;o>>=1) qv += __shfl_xor(qv,o,64);
  const float rstd = rsqrtf(qv*(1.f/256.f)+1e-5f);
  float4 gu = ldf4(g, lane*4, f);
  float4 bu = ldf4(be, lane*4, f);
  ushort4 o;
  o.x = f2bf(d0*rstd*gu.x+bu.x);
  o.y = f2bf(d1*rstd*gu.y+bu.y);
  o.z = f2bf(d2*rstd*gu.z+bu.z);
  o.w = f2bf(d3*rstd*gu.w+bu.w);
  *reinterpret_cast<ushort4*>(xn2 + (size_t)rs*256 + lane*4) = o;
}

// ---------------- MFMA 128x128 GEMM core: 8 waves, 3-deep pipeline -----------
template<int K>
DI void mfma_core128(const unsigned short* __restrict__ A, const unsigned short* __restrict__ WT,
                     const int m0, const int n0, f32x4 acc[4][2], unsigned short* lds)
{
  constexpr int STEPS = K/32;
  const int tid = threadIdx.x, lane = tid&63, wave = tid>>6;
  const int wm = (wave>>2)*64, wn = (wave&3)*32;
  const int fr = lane&15;
  const int kqs = ((lane>>4) ^ (fr&3))*8;   // swizzled k-part offset (shorts)
  #pragma unroll
  for (int i=0;i<4;++i)
    #pragma unroll
    for (int j=0;j<2;++j) acc[i][j] = (f32x4){0.f,0.f,0.f,0.f};
  const int isB = wave>>2;                  // waves 0-3: A, waves 4-7: B
  const int c0 = (wave&3)*128 + lane;       // chunk id in half [0,512)
  const int c1 = c0 + 64;
  const int r0=c0>>2, p0=((c0&3)^(r0&3));
  const int r1=c1>>2, p1=((c1&3)^(r1&3));
  const unsigned short* gb = isB ? (WT + (size_t)n0*K) : (A + (size_t)m0*K);
  const unsigned short* g0 = gb + (size_t)r0*K + p0*8;
  const unsigned short* g1 = gb + (size_t)r1*K + p1*8;
  const int ldso = isB*4096 + (wave&3)*1024;   // shorts
  #define STAGE_(d,k0) do{ \
    unsigned short* bse = lds + (d)*8192 + ldso; \
    gload16(g0+(k0), bse); \
    gload16(g1+(k0), bse+512); }while(0)
  STAGE_(0,0);
  STAGE_(1,32);
  int cur = 0;
  for (int t=0; t<STEPS; ++t){
    if (t+2 < STEPS){
      int nb = cur+2; if (nb>=3) nb-=3;
      STAGE_(nb, (t+2)*32);
      asm volatile("s_waitcnt vmcnt(4)" ::: "memory");
    } else if (t+2 == STEPS){
      asm volatile("s_waitcnt vmcnt(2)" ::: "memory");
    } else {
      asm volatile("s_waitcnt vmcnt(0)" ::: "memory");
    }
    __builtin_amdgcn_s_barrier();
    const unsigned short* At = lds + cur*8192;
    const unsigned short* Bt = At + 4096;
    bf16x8 af[4], bfv[2];
    #pragma unroll
    for (int mi=0;mi<4;++mi) af[mi]  = *(const bf16x8*)(At + (wm+mi*16+fr)*32 + kqs);
    #pragma unroll
    for (int ni=0;ni<2;++ni) bfv[ni] = *(const bf16x8*)(Bt + (wn+ni*16+fr)*32 + kqs);
    #pragma unroll
    for (int mi=0;mi<4;++mi)
      #pragma unroll
      for (int ni=0;ni<2;++ni)
        acc[mi][ni] = __builtin_amdgcn_mfma_f32_16x16x32_bf16(af[mi], bfv[ni], acc[mi][ni], 0,0,0);
    __builtin_amdgcn_s_barrier();
    cur = (cur+1==3)?0:cur+1;
  }
  #undef STAGE_
}

// ---------------- fused QKV projection (N=768: q|k|v) ------------------------
__global__ __launch_bounds__(512,5) void k_gemm_qkv(const unsigned short* __restrict__ Ain,
    const unsigned short* __restrict__ WT, const float* __restrict__ posq,
    const float* __restrict__ posk, const void* __restrict__ bv,
    unsigned short* __restrict__ qb, unsigned short* __restrict__ kb,
    unsigned short* __restrict__ vb2, const int* __restrict__ flagp)
{
  __shared__ __align__(16) unsigned short lds[24576];
  f32x4 acc[4][2];
  int mt, nt; xcd_remap(blockIdx.x, 2700, 6, mt, nt);
  const int m0 = mt*128;
  mfma_core128<256>(Ain, WT, m0, nt*128, acc, lds);
  const int f = *flagp;
  const int tid = threadIdx.x, lane = tid&63, wave = tid>>6;
  const int wm = (wave>>2)*64, wn = (wave&3)*32;
  const int fr = lane&15, fq = lane>>4;
  const int seg = nt>>1;
  unsigned short* ob = seg==0? qb : (seg==1? kb : vb2);
  const float* posb = seg==0? posq : posk;
  // ---- write acc(+bias) -> LDS [128][132] bf16 ----
  #pragma unroll
  for (int mi=0;mi<4;++mi){
    #pragma unroll
    for (int r=0;r<4;++r){
      const int row = wm+mi*16+fq*4+r;
      const int grow = m0+row;
      const int bt2 = (grow/28800)*8 + (grow/30)%8;
      #pragma unroll
      for (int ni=0;ni<2;++ni){
        const int lcol = wn+ni*16+fr;
        const int colm = (nt&1)*128 + lcol;
        const float bvv = (seg<2) ? posb[bt2*256+colm] : ldf(bv,colm,f);
        lds[row*132+lcol] = f2bf(acc[mi][ni][r] + bvv);
      }
    }
  }
  __syncthreads();
  // ---- readback wide: 4 threads/row, 4x u16x8 each ----
  const int row = tid>>2;
  unsigned short* dst = ob + (size_t)(m0+row)*256 + (nt&1)*128;
  #pragma unroll
  for (int j=0;j<4;++j){
    const int ci = j*4 + (tid&3);
    *(u16x8*)(dst + ci*8) = *(const u16x8*)(lds + row*132 + ci*8);
  }
}

// ---------------- MFMA attention: one wave per (bt, head) --------------------
__global__ __launch_bounds__(256) void k_attn(const unsigned short* __restrict__ q,
    const unsigned short* __restrict__ k, const unsigned short* __restrict__ v,
    const void* __restrict__ relb, unsigned short* __restrict__ ao,
    const int* __restrict__ flagp)
{
  __shared__ __align__(16) unsigned short vt[4][32*40];   // per-wave V^T [d][m]
  __shared__ __align__(16) unsigned short pa[4][32*40];   // per-wave P [n][m]
  const int f = *flagp;
  const int tid = threadIdx.x, lane = tid&63, wave = tid>>6;
  const int task = blockIdx.x*4 + wave;      // (bt, head)
  const int h = task & 7, bt = task >> 3;
  const int wi = (bt>>3) % 120;
  const int a_ = wi/10, bb_ = wi%10;
  const size_t base = (size_t)bt*7680 + h*32;
  unsigned short* vtw = &vt[wave][0];
  unsigned short* paw = &pa[wave][0];
  // stage V transposed (rows m -> cols), zero-pad m=30,31
  if (lane < 60){
    const int m = lane>>1, hf = lane&1;
    const unsigned short* src = v + base + (size_t)m*256 + hf*16;
    u16x8 r0 = *(const u16x8*)(src);
    u16x8 r1 = *(const u16x8*)(src+8);
    #pragma unroll
    for (int j=0;j<8;++j){ vtw[(hf*16+j)*40+m] = r0[j]; vtw[(hf*16+8+j)*40+m] = r1[j]; }
  }
  vtw[(lane>>1)*40 + 30 + (lane&1)] = 0;
  // QK^T: accS[r] = scores[n=lane&31][m_r], m_r=(r&3)+8*(r>>2)+4*(lane>>5)
  const int n  = lane&31;
  const int hl = lane>>5;
  f32x16 accS = {};
  {
    const unsigned short* ka = k + base + (size_t)n*256 + hl*8;
    const unsigned short* qa = q + base + (size_t)n*256 + hl*8;
    bf16x8 a0 = *(const bf16x8*)(ka);
    bf16x8 b0 = *(const bf16x8*)(qa);
    accS = __builtin_amdgcn_mfma_f32_32x32x16_bf16(a0, b0, accS, 0,0,0);
    bf16x8 a1 = *(const bf16x8*)(ka+16);
    bf16x8 b1 = *(const bf16x8*)(qa+16);
    accS = __builtin_amdgcn_mfma_f32_32x32x16_bf16(a1, b1, accS, 0,0,0);
  }
  // softmax over m (per-lane: 16 regs + partner half via shfl_xor 32)
  const int nc  = (n < 30) ? n : 29;
  const int in_ = nc/6, jn = nc - in_*6;
  const int rn = a_*5+in_, cn = bb_*6+jn;
  const int lnl = (rn<55?0:(rn<58?1:2))*3 + (cn<54?0:(cn<57?1:2));
  #pragma unroll
  for (int r=0;r<16;++r){
    const int m = (r&3) + 8*(r>>2) + 4*hl;
    if (m < 30){
      const int im = m/6, jm = m - im*6;
      const int ridx = (in_-im+4)*11 + (jn-jm+5);
      const float bi = ldf(relb, ridx*8+h, f);
      const int rm = a_*5+im, cm = bb_*6+jm;
      const int lml = (rm<55?0:(rm<58?1:2))*3 + (cm<54?0:(cm<57?1:2));
      accS[r] = accS[r]*SCALE_ + bi + (lnl==lml ? 0.f : -100.f);
    } else accS[r] = -1e30f;
  }
  float mx = accS[0];
  #pragma unroll
  for (int r=1;r<16;++r) mx = fmaxf(mx, accS[r]);
  mx = fmaxf(mx, __shfl_xor(mx, 32, 64));
  float sum = 0.f;
  #pragma unroll
  for (int r=0;r<16;++r){ accS[r] = __expf(accS[r]-mx); sum += accS[r]; }
  sum += __shfl_xor(sum, 32, 64);
  const float inv = 1.f/sum;
  #pragma unroll
  for (int r=0;r<16;++r){
    const int m = (r&3)+8*(r>>2)+4*hl;
    paw[n*40 + m] = f2bf(accS[r]);
  }
  // PV: accO[r] = out[n][d_r]
  f32x16 accO = {};
  #pragma unroll
  for (int ks=0; ks<2; ++ks){
    bf16x8 av  = *(const bf16x8*)(vtw + n*40 + ks*16 + hl*8);
    bf16x8 pv  = *(const bf16x8*)(paw + n*40 + ks*16 + hl*8);
    accO = __builtin_amdgcn_mfma_f32_32x32x16_bf16(av, pv, accO, 0,0,0);
  }
  if (n < 30){
    #pragma unroll
    for (int g4=0; g4<4; ++g4){
      const int d0 = 8*g4 + 4*hl;
      ushort4 o;
      o.x = f2bf(accO[g4*4+0]*inv);
      o.y = f2bf(accO[g4*4+1]*inv);
      o.z = f2bf(accO[g4*4+2]*inv);
      o.w = f2bf(accO[g4*4+3]*inv);
      *(ushort4*)(ao + base + (size_t)n*256 + d0) = o;
    }
  }
}

// ---------------- Wo projection + window reverse + un-shift + residual -------
// x1b: bf16 [ROWS][256] in ws (spatial layout).
__global__ __launch_bounds__(512,5) void k_gemm_wo(const unsigned short* __restrict__ Ain,
    const unsigned short* __restrict__ WT, const void* __restrict__ bias,
    const void* __restrict__ xin, unsigned short* __restrict__ x1b,
    const int* __restrict__ flagp)
{
  __shared__ __align__(16) unsigned short lds[24576];
  f32x4 acc[4][2];
  int mt, nt; xcd_remap(blockIdx.x, 900, 2, mt, nt);
  const int m0 = mt*128, n0 = nt*128;
  mfma_core128<256>(Ain, WT, m0, n0, acc, lds);
  const int f = *flagp;
  const int tid = threadIdx.x, lane = tid&63, wave = tid>>6;
  const int wm = (wave>>2)*64, wn = (wave&3)*32;
  const int fr = lane&15, fq = lane>>4;
  // ---- write acc+bias -> LDS bf16 ----
  #pragma unroll
  for (int mi=0;mi<4;++mi){
    #pragma unroll
    for (int ni=0;ni<2;++ni){
      const int lcol = wn+ni*16+fr;
      const float bvv = ldf(bias, n0+lcol, f);
      #pragma unroll
      for (int r=0;r<4;++r){
        const int row = wm+mi*16+fq*4+r;
        lds[row*132+lcol] = f2bf(acc[mi][ni][r] + bvv);
      }
    }
  }
  __syncthreads();
  // ---- readback: window-reverse row, add residual wide, store bf16 wide ----
  const int row = tid>>2;
  const int rw = m0+row;
  const int nn = rw%30, t = (rw/30)%8, bw = rw/240;
  const int b = bw/120, wi = bw%120;
  const int a = wi/10, bb2 = wi%10, ii = nn/6, jj = nn%6;
  int rr = a*5+ii+SH_; if (rr>=60) rr-=60;
  int cc = bb2*6+jj+SW_; if (cc>=60) cc-=60;
  const size_t srow = ((size_t)((b*8+t)*60 + rr)*60 + cc);
  #pragma unroll
  for (int j=0;j<4;++j){
    const int ci = j*4 + (tid&3);
    const int col = n0 + ci*8;
    u16x8 vv = *(const u16x8*)(lds + row*132 + ci*8);
    float4 xa = ldf4(xin, srow*256+col,   f);
    float4 xbv= ldf4(xin, srow*256+col+4, f);
    u16x8 o;
    o[0]=f2bf(bf2f(vv[0])+xa.x); o[1]=f2bf(bf2f(vv[1])+xa.y);
    o[2]=f2bf(bf2f(vv[2])+xa.z); o[3]=f2bf(bf2f(vv[3])+xa.w);
    o[4]=f2bf(bf2f(vv[4])+xbv.x); o[5]=f2bf(bf2f(vv[5])+xbv.y);
    o[6]=f2bf(bf2f(vv[6])+xbv.z); o[7]=f2bf(bf2f(vv[7])+xbv.w);
    *(u16x8*)(x1b + srow*256 + col) = o;
  }
}

// ---------------- MLP1: xn2 @ W1 + b1 -> exact GELU -> h ---------------------
__global__ __launch_bounds__(512,5) void k_mlp1(const unsigned short* __restrict__ Ain,
    const unsigned short* __restrict__ WT, const void* __restrict__ bias,
    unsigned short* __restrict__ hb, const int row0, const int* __restrict__ flagp)
{
  __shared__ __align__(16) unsigned short lds[24576];
  f32x4 acc[4][2];
  int mt, nt; xcd_remap(blockIdx.x, 1800, 8, mt, nt);
  const int m0 = row0 + mt*128, n0 = nt*128;
  mfma_core128<256>(Ain, WT, m0, n0, acc, lds);
  const int f = *flagp;
  const int tid = threadIdx.x, lane = tid&63, wave = tid>>6;
  const int wm = (wave>>2)*64, wn = (wave&3)*32;
  const int fr = lane&15, fq = lane>>4;
  #pragma unroll
  for (int mi=0;mi<4;++mi){
    #pragma unroll
    for (int ni=0;ni<2;++ni){
      const int lcol = wn+ni*16+fr;
      const float bvv = ldf(bias, n0+lcol, f);
      #pragma unroll
      for (int r=0;r<4;++r){
        const int row = wm+mi*16+fq*4+r;
        const float vv = acc[mi][ni][r] + bvv;
        lds[row*132+lcol] = f2bf(0.5f*vv*(1.f+erff(vv*0.70710678118654752f)));
      }
    }
  }
  __syncthreads();
  const int row = tid>>2;
  unsigned short* dst = hb + (size_t)(mt*128+row)*1024 + n0;
  #pragma unroll
  for (int j=0;j<4;++j){
    const int ci = j*4 + (tid&3);
    *(u16x8*)(dst + ci*8) = *(const u16x8*)(lds + row*132 + ci*8);
  }
}

// ---------------- MLP2: h @ W2 + b2 + x1 -> out ------------------------------
__global__ __launch_bounds__(512,5) void k_mlp2(const unsigned short* __restrict__ hbin,
    const unsigned short* __restrict__ WT, const void* __restrict__ bias,
    const unsigned short* __restrict__ x1b, void* __restrict__ outb,
    const int row0, const int* __restrict__ flagp)
{
  __shared__ __align__(16) unsigned short lds[24576];
  f32x4 acc[4][2];
  int mt, nt; xcd_remap(blockIdx.x, 450, 2, mt, nt);
  const int m0l = mt*128, n0 = nt*128;
  mfma_core128<1024>(hbin, WT, m0l, n0, acc, lds);
  const int f = *flagp;
  const int tid = threadIdx.x, lane = tid&63, wave = tid>>6;
  const int wm = (wave>>2)*64, wn = (wave&3)*32;
  const int fr = lane&15, fq = lane>>4;
  #pragma unroll
  for (int mi=0;mi<4;++mi){
    #pragma unroll
    for (int ni=0;ni<2;++ni){
      const int lcol = wn+ni*16+fr;
      const float bvv = ldf(bias, n0+lcol, f);
      #pragma unroll
      for (int r=0;r<4;++r){
        const int row = wm+mi*16+fq*4+r;
        lds[row*132+lcol] = f2bf(acc[mi][ni][r] + bvv);
      }
    }
  }
  __syncthreads();
  const int row = tid>>2;
  const size_t grow = (size_t)(row0 + m0l + row);
  #pragma unroll
  for (int j=0;j<4;++j){
    const int ci = j*4 + (tid&3);
    const int col = n0 + ci*8;
    u16x8 vv = *(const u16x8*)(lds + row*132 + ci*8);
    u16x8 xv = *(const u16x8*)(x1b + grow*256 + col);
    if (f){
      float4 o0, o1;
      o0.x=bf2f(vv[0])+bf2f(xv[0]); o0.y=bf2f(vv[1])+bf2f(xv[1]);
      o0.z=bf2f(vv[2])+bf2f(xv[2]); o0.w=bf2f(vv[3])+bf2f(xv[3]);
      o1.x=bf2f(vv[4])+bf2f(xv[4]); o1.y=bf2f(vv[5])+bf2f(xv[5]);
      o1.z=bf2f(vv[6])+bf2f(xv[6]); o1.w=bf2f(vv[7])+bf2f(xv[7]);
      *(float4*)((float*)outb + grow*256 + col)     = o0;
      *(float4*)((float*)outb + grow*256 + col + 4) = o1;
    } else {
      u16x8 o;
      #pragma unroll
      for (int e=0;e<8;++e) o[e] = f2bf(bf2f(vv[e])+bf2f(xv[e]));
      *(u16x8*)((unsigned short*)outb + grow*256 + col) = o;
    }
  }
}

extern "C" void kernel_launch(void* const* d_in, const int* in_sizes, int n_in,
                              void* d_out, int out_size, void* d_ws, size_t ws_size,
                              hipStream_t stream)
{
  const void* x   = d_in[0];
  const void* ce  = d_in[1];
  const void* g1  = d_in[2];
  const void* be1 = d_in[3];
  const void* Wq  = d_in[4];
  const void* bq  = d_in[5];
  const void* Wk  = d_in[6];
  const void* bk  = d_in[7];
  const void* Wv  = d_in[8];
  const void* bv  = d_in[9];
  const void* rb  = d_in[10];
  const void* Wo  = d_in[11];
  const void* bo  = d_in[12];
  const void* g2  = d_in[13];
  const void* be2 = d_in[14];
  const void* W1  = d_in[15];
  const void* b1  = d_in[16];
  const void* W2  = d_in[17];
  const void* b2  = d_in[18];

  char* ws = (char*)d_ws;
  const size_t SZ = (size_t)ROWS_*256*2;                 // 29,491,200 B
  unsigned short* kbuf = (unsigned short*)(ws);          // [0, SZ)   later: xn2
  unsigned short* vbuf = (unsigned short*)(ws + SZ);     // [SZ, 2SZ)
  unsigned short* xw   = (unsigned short*)(ws + 2*SZ);   // [2SZ,3SZ) later: ao
  unsigned short* qbuf = (unsigned short*)(ws + 3*SZ);   // [3SZ,4SZ) later: x1b
  unsigned short* aob  = xw;
  unsigned short* xn2  = kbuf;                           // q/k dead after attn
  unsigned short* x1b  = qbuf;                           // bf16 x1
  unsigned short* hb   = vbuf;                           // [SZ,3SZ): v+ao dead in MLP
  float* posq = (float*)(ws + 4*SZ);                     // 16KB
  float* posk = posq + 16*256;                           // 16KB
  int*   flag = (int*)(ws + 4*SZ + 32768);
  unsigned short* wt = (unsigned short*)(ws + 4*SZ + 65536);  // 1.5MB bf16 WT

  unsigned short* wtqkv = wt;            // q|k|v contiguous: WT[768][256]
  unsigned short* wto = wt + 196608;
  unsigned short* wt1 = wt + 262144;
  unsigned short* wt2 = wt + 524288;

  k_detect<<<1,64,0,stream>>>((const unsigned short*)x, flag);
  k_prepw<<<dim3(1024,6),256,0,stream>>>(Wq,Wk,Wv,Wo,W1,W2, wt, flag);
  k_posqk<<<16,256,0,stream>>>(ce, Wq, bq, Wk, bk, posq, posk, flag);
  k_ln1<<<14400,256,0,stream>>>(x, g1, be1, xw, flag);
  k_gemm_qkv<<<2700,512,0,stream>>>(xw, wtqkv, posq, posk, bv, qbuf, kbuf, vbuf, flag);
  k_attn<<<3840,256,0,stream>>>(qbuf, kbuf, vbuf, rb, aob, flag);
  k_gemm_wo<<<900,512,0,stream>>>(aob, wto, bo, x, x1b, flag);
  k_ln2<<<14400,256,0,stream>>>(x1b, g2, be2, xn2, flag);
  for (int chk=0; chk<2; ++chk){
    const int row0 = chk*28800;
    k_mlp1<<<1800,512,0,stream>>>(xn2, wt1, b1, hb, row0, flag);
    k_mlp2<<<450,512,0,stream>>>(hb, wt2, b2, x1b, d_out, row0, flag);
  }
}

// Round 9
// 278.663 us; speedup vs baseline: 5.1664x; 1.0977x over previous
//
#include <hip/hip_runtime.h>

#define DI __device__ __forceinline__

constexpr int SH_=2, SW_=3;
constexpr int ROWS_=57600;            // B*NW*T*N == B*T*H*W
constexpr float SCALE_=0.17677669529663687f;   // 32^-0.5

typedef unsigned short u16x8 __attribute__((ext_vector_type(8)));
typedef short bf16x8 __attribute__((ext_vector_type(8)));
typedef float f32x4 __attribute__((ext_vector_type(4)));
typedef float f32x16 __attribute__((ext_vector_type(16)));

DI float bf2f(unsigned short u){ return __uint_as_float(((unsigned int)u)<<16); }
DI unsigned short f2bf(float f){
  unsigned int u = __float_as_uint(f);
  u += 0x7fffu + ((u>>16)&1u);          // round to nearest even
  return (unsigned short)(u>>16);
}
// flag f: 1 = external buffers are fp32, 0 = bf16
DI float ldf(const void* p, size_t i, int f){
  return f ? ((const float*)p)[i] : bf2f(((const unsigned short*)p)[i]);
}
DI float4 ldf4(const void* p, size_t i, int f){
  if (f) return *((const float4*)((const float*)p + i));
  ushort4 u = *((const ushort4*)((const unsigned short*)p + i));
  return make_float4(bf2f(u.x),bf2f(u.y),bf2f(u.z),bf2f(u.w));
}

// async global->LDS, 16B per lane. LDS dest = wave-uniform base + lane*16.
DI void gload16(const void* g, void* l){
  __builtin_amdgcn_global_load_lds((const __attribute__((address_space(1))) unsigned int*)g,
                                   (__attribute__((address_space(3))) unsigned int*)l, 16, 0, 0);
}

// XCD-bijective remap (m204): n-tile varies fastest within an XCD so all
// n-tiles of one A-panel run consecutively on the same XCD -> A L2-reuse.
DI void xcd_remap(int wg, int nb, int nn, int& mt, int& nt){
  const int q = nb>>3, r = nb&7;
  const int x = wg & 7, i = wg >> 3;
  const int base = (x<r) ? x*(q+1) : r*(q+1) + (x-r)*q;
  const int work = base + i;
  mt = work / nn; nt = work - mt*nn;
}

// ---------------- dtype detection: fp32-as-bf16 is detectable ----------------
__global__ void k_detect(const unsigned short* __restrict__ xu, int* __restrict__ flag){
  unsigned short u = xu[threadIdx.x*2];
  int insane = ((u>>7)&0xFF) > 0xC0;
  unsigned long long m = __ballot(insane);
  if (threadIdx.x==0) *flag = m ? 1 : 0;
}

// ---------------- one-time weight convert+transpose to bf16 WT[n][k] ---------
__global__ __launch_bounds__(256) void k_prepw(
    const void* __restrict__ Wq, const void* __restrict__ Wk,
    const void* __restrict__ Wv, const void* __restrict__ Wo,
    const void* __restrict__ W1, const void* __restrict__ W2,
    unsigned short* __restrict__ wt, const int* __restrict__ flagp)
{
  const int f = *flagp;
  const void* src; int kb, total; size_t off;
  switch(blockIdx.y){
    case 0: src=Wq; kb=8;  total=65536;  off=0;      break;
    case 1: src=Wk; kb=8;  total=65536;  off=65536;  break;
    case 2: src=Wv; kb=8;  total=65536;  off=131072; break;
    case 3: src=Wo; kb=8;  total=65536;  off=196608; break;
    case 4: src=W1; kb=8;  total=262144; off=262144; break;   // [256][1024]
    default:src=W2; kb=10; total=262144; off=524288; break;   // [1024][256]
  }
  const int i = blockIdx.x*256 + threadIdx.x;
  if (i >= total) return;
  const int K = 1<<kb, N = total>>kb;
  const int n = i>>kb, k = i&(K-1);
  wt[off + (size_t)n*K + k] = f2bf(ldf(src, (size_t)k*N + n, f));
}

// ---------------- per-(b,t) positional bias via bf16 WT (contiguous k) -------
// posq[n] = bq[n] + sum_k ce[k]*WTq[n*256+k]; grid (16 bt, 2 mat).
__global__ __launch_bounds__(256) void k_posqk(const void* __restrict__ ce,
    const unsigned short* __restrict__ wtq, const unsigned short* __restrict__ wtk,
    const void* __restrict__ bq, const void* __restrict__ bk,
    float* __restrict__ posq, float* __restrict__ posk, const int* __restrict__ flagp)
{
  const int f = *flagp;
  const int bt = blockIdx.x, mat = blockIdx.y, co = threadIdx.x;
  __shared__ float ces[256];
  ces[co] = ldf(ce, bt*256+co, f);
  __syncthreads();
  const unsigned short* wr = (mat ? wtk : wtq) + (size_t)co*256;
  float s = ldf(mat ? bk : bq, co, f);
  #pragma unroll
  for (int k0=0;k0<256;k0+=8){
    u16x8 wv = *(const u16x8*)(wr + k0);
    #pragma unroll
    for (int j=0;j<8;++j) s += ces[k0+j]*bf2f(wv[j]);
  }
  (mat ? posk : posq)[bt*256+co] = s;
}

// ---------------- LN1 + cyclic shift + window partition ----------------------
__global__ __launch_bounds__(256) void k_ln1(const void* __restrict__ x,
    const void* __restrict__ g, const void* __restrict__ be,
    unsigned short* __restrict__ xw, const int* __restrict__ flagp)
{
  const int f = *flagp;
  const int lane = threadIdx.x & 63;
  const int wv   = threadIdx.x >> 6;
  const int rs   = blockIdx.x*4 + wv;           // spatial row (b,t,r,c)
  float4 u = ldf4(x, (size_t)rs*256 + lane*4, f);
  float s = u.x+u.y+u.z+u.w;
  #pragma unroll
  for (int o=32;o;o>>=1) s += __shfl_xor(s,o,64);
  const float mean = s*(1.f/256.f);
  float d0=u.x-mean, d1=u.y-mean, d2=u.z-mean, d3=u.w-mean;
  float qv = d0*d0+d1*d1+d2*d2+d3*d3;
  #pragma unroll
  for (int o=32;o;o>>=1) qv += __shfl_xor(qv,o,64);
  const float rstd = rsqrtf(qv*(1.f/256.f)+1e-5f);
  float4 gu = ldf4(g, lane*4, f);
  float4 bu = ldf4(be, lane*4, f);
  ushort4 o;
  o.x = f2bf(d0*rstd*gu.x+bu.x);
  o.y = f2bf(d1*rstd*gu.y+bu.y);
  o.z = f2bf(d2*rstd*gu.z+bu.z);
  o.w = f2bf(d3*rstd*gu.w+bu.w);
  const int c = rs % 60, r = (rs/60)%60, t = (rs/3600)&7, b = rs/28800;
  int r2 = r - SH_; if (r2<0) r2+=60;
  int c2 = c - SW_; if (c2<0) c2+=60;
  const int a=r2/5, ii=r2%5, bb=c2/6, jj=c2%6;
  const int rw = ((b*120 + a*10+bb)*8 + t)*30 + ii*6+jj;
  *reinterpret_cast<ushort4*>(xw + (size_t)rw*256 + lane*4) = o;
}

// ---------------- LN2 (x1b bf16 in ws, bf16 out) ------------------------------
__global__ __launch_bounds__(256) void k_ln2(const unsigned short* __restrict__ x1b,
    const void* __restrict__ g, const void* __restrict__ be,
    unsigned short* __restrict__ xn2, const int* __restrict__ flagp)
{
  const int f = *flagp;
  const int lane = threadIdx.x & 63;
  const int wv   = threadIdx.x >> 6;
  const int rs   = blockIdx.x*4 + wv;
  float4 v = ldf4(x1b, (size_t)rs*256 + lane*4, 0);
  float s = v.x+v.y+v.z+v.w;
  #pragma unroll
  for (int o=32;o;o>>=1) s += __shfl_xor(s,o,64);
  const float mean = s*(1.f/256.f);
  float d0=v.x-mean, d1=v.y-mean, d2=v.z-mean, d3=v.w-mean;
  float qv = d0*d0+d1*d1+d2*d2+d3*d3;
  #pragma unroll
  for (int o=32;o;o>>=1) qv += __shfl_xor(qv,o,64);
  const float rstd = rsqrtf(qv*(1.f/256.f)+1e-5f);
  float4 gu = ldf4(g, lane*4, f);
  float4 bu = ldf4(be, lane*4, f);
  ushort4 o;
  o.x = f2bf(d0*rstd*gu.x+bu.x);
  o.y = f2bf(d1*rstd*gu.y+bu.y);
  o.z = f2bf(d2*rstd*gu.z+bu.z);
  o.w = f2bf(d3*rstd*gu.w+bu.w);
  *reinterpret_cast<ushort4*>(xn2 + (size_t)rs*256 + lane*4) = o;
}

// ---------------- MFMA 128x128 GEMM core: 8 waves, 3-deep pipeline -----------
template<int K>
DI void mfma_core128(const unsigned short* __restrict__ A, const unsigned short* __restrict__ WT,
                     const int m0, const int n0, f32x4 acc[4][2], unsigned short* lds)
{
  constexpr int STEPS = K/32;
  const int tid = threadIdx.x, lane = tid&63, wave = tid>>6;
  const int wm = (wave>>2)*64, wn = (wave&3)*32;
  const int fr = lane&15;
  const int kqs = ((lane>>4) ^ (fr&3))*8;   // swizzled k-part offset (shorts)
  #pragma unroll
  for (int i=0;i<4;++i)
    #pragma unroll
    for (int j=0;j<2;++j) acc[i][j] = (f32x4){0.f,0.f,0.f,0.f};
  const int isB = wave>>2;                  // waves 0-3: A, waves 4-7: B
  const int c0 = (wave&3)*128 + lane;       // chunk id in half [0,512)
  const int c1 = c0 + 64;
  const int r0=c0>>2, p0=((c0&3)^(r0&3));
  const int r1=c1>>2, p1=((c1&3)^(r1&3));
  const unsigned short* gb = isB ? (WT + (size_t)n0*K) : (A + (size_t)m0*K);
  const unsigned short* g0 = gb + (size_t)r0*K + p0*8;
  const unsigned short* g1 = gb + (size_t)r1*K + p1*8;
  const int ldso = isB*4096 + (wave&3)*1024;   // shorts
  #define STAGE_(d,k0) do{ \
    unsigned short* bse = lds + (d)*8192 + ldso; \
    gload16(g0+(k0), bse); \
    gload16(g1+(k0), bse+512); }while(0)
  STAGE_(0,0);
  STAGE_(1,32);
  int cur = 0;
  for (int t=0; t<STEPS; ++t){
    if (t+2 < STEPS){
      int nb = cur+2; if (nb>=3) nb-=3;
      STAGE_(nb, (t+2)*32);
      asm volatile("s_waitcnt vmcnt(4)" ::: "memory");
    } else if (t+2 == STEPS){
      asm volatile("s_waitcnt vmcnt(2)" ::: "memory");
    } else {
      asm volatile("s_waitcnt vmcnt(0)" ::: "memory");
    }
    __builtin_amdgcn_s_barrier();
    const unsigned short* At = lds + cur*8192;
    const unsigned short* Bt = At + 4096;
    bf16x8 af[4], bfv[2];
    #pragma unroll
    for (int mi=0;mi<4;++mi) af[mi]  = *(const bf16x8*)(At + (wm+mi*16+fr)*32 + kqs);
    #pragma unroll
    for (int ni=0;ni<2;++ni) bfv[ni] = *(const bf16x8*)(Bt + (wn+ni*16+fr)*32 + kqs);
    #pragma unroll
    for (int mi=0;mi<4;++mi)
      #pragma unroll
      for (int ni=0;ni<2;++ni)
        acc[mi][ni] = __builtin_amdgcn_mfma_f32_16x16x32_bf16(af[mi], bfv[ni], acc[mi][ni], 0,0,0);
    __builtin_amdgcn_s_barrier();
    cur = (cur+1==3)?0:cur+1;
  }
  #undef STAGE_
}

// ---------------- fused QKV projection (N=768: q|k|v) ------------------------
__global__ __launch_bounds__(512,5) void k_gemm_qkv(const unsigned short* __restrict__ Ain,
    const unsigned short* __restrict__ WT, const float* __restrict__ posq,
    const float* __restrict__ posk, const void* __restrict__ bv,
    unsigned short* __restrict__ qb, unsigned short* __restrict__ kb,
    unsigned short* __restrict__ vb2, const int* __restrict__ flagp)
{
  __shared__ __align__(16) unsigned short lds[24576];
  f32x4 acc[4][2];
  int mt, nt; xcd_remap(blockIdx.x, 2700, 6, mt, nt);
  const int m0 = mt*128;
  mfma_core128<256>(Ain, WT, m0, nt*128, acc, lds);
  const int f = *flagp;
  const int tid = threadIdx.x, lane = tid&63, wave = tid>>6;
  const int wm = (wave>>2)*64, wn = (wave&3)*32;
  const int fr = lane&15, fq = lane>>4;
  const int seg = nt>>1;
  unsigned short* ob = seg==0? qb : (seg==1? kb : vb2);
  const float* posb = seg==0? posq : posk;
  // ---- write acc(+bias) -> LDS [128][132] bf16 ----
  #pragma unroll
  for (int mi=0;mi<4;++mi){
    #pragma unroll
    for (int r=0;r<4;++r){
      const int row = wm+mi*16+fq*4+r;
      const int grow = m0+row;
      const int bt2 = (grow/28800)*8 + (grow/30)%8;
      #pragma unroll
      for (int ni=0;ni<2;++ni){
        const int lcol = wn+ni*16+fr;
        const int colm = (nt&1)*128 + lcol;
        const float bvv = (seg<2) ? posb[bt2*256+colm] : ldf(bv,colm,f);
        lds[row*132+lcol] = f2bf(acc[mi][ni][r] + bvv);
      }
    }
  }
  __syncthreads();
  // ---- readback wide: 4 threads/row, 4x u16x8 each ----
  const int row = tid>>2;
  unsigned short* dst = ob + (size_t)(m0+row)*256 + (nt&1)*128;
  #pragma unroll
  for (int j=0;j<4;++j){
    const int ci = j*4 + (tid&3);
    *(u16x8*)(dst + ci*8) = *(const u16x8*)(lds + row*132 + ci*8);
  }
}

// ---------------- MFMA attention: one wave per (bt, head) --------------------
__global__ __launch_bounds__(256) void k_attn(const unsigned short* __restrict__ q,
    const unsigned short* __restrict__ k, const unsigned short* __restrict__ v,
    const void* __restrict__ relb, unsigned short* __restrict__ ao,
    const int* __restrict__ flagp)
{
  __shared__ __align__(16) unsigned short vt[4][32*40];   // per-wave V^T [d][m]
  __shared__ __align__(16) unsigned short pa[4][32*40];   // per-wave P [n][m]
  const int f = *flagp;
  const int tid = threadIdx.x, lane = tid&63, wave = tid>>6;
  const int task = blockIdx.x*4 + wave;      // (bt, head)
  const int h = task & 7, bt = task >> 3;
  const int wi = (bt>>3) % 120;
  const int a_ = wi/10, bb_ = wi%10;
  const size_t base = (size_t)bt*7680 + h*32;
  unsigned short* vtw = &vt[wave][0];
  unsigned short* paw = &pa[wave][0];
  // stage V transposed (rows m -> cols), zero-pad m=30,31
  if (lane < 60){
    const int m = lane>>1, hf = lane&1;
    const unsigned short* src = v + base + (size_t)m*256 + hf*16;
    u16x8 r0 = *(const u16x8*)(src);
    u16x8 r1 = *(const u16x8*)(src+8);
    #pragma unroll
    for (int j=0;j<8;++j){ vtw[(hf*16+j)*40+m] = r0[j]; vtw[(hf*16+8+j)*40+m] = r1[j]; }
  }
  vtw[(lane>>1)*40 + 30 + (lane&1)] = 0;
  // QK^T: accS[r] = scores[n=lane&31][m_r], m_r=(r&3)+8*(r>>2)+4*(lane>>5)
  const int n  = lane&31;
  const int hl = lane>>5;
  f32x16 accS = {};
  {
    const unsigned short* ka = k + base + (size_t)n*256 + hl*8;
    const unsigned short* qa = q + base + (size_t)n*256 + hl*8;
    bf16x8 a0 = *(const bf16x8*)(ka);
    bf16x8 b0 = *(const bf16x8*)(qa);
    accS = __builtin_amdgcn_mfma_f32_32x32x16_bf16(a0, b0, accS, 0,0,0);
    bf16x8 a1 = *(const bf16x8*)(ka+16);
    bf16x8 b1 = *(const bf16x8*)(qa+16);
    accS = __builtin_amdgcn_mfma_f32_32x32x16_bf16(a1, b1, accS, 0,0,0);
  }
  // softmax over m (per-lane: 16 regs + partner half via shfl_xor 32)
  const int nc  = (n < 30) ? n : 29;
  const int in_ = nc/6, jn = nc - in_*6;
  const int rn = a_*5+in_, cn = bb_*6+jn;
  const int lnl = (rn<55?0:(rn<58?1:2))*3 + (cn<54?0:(cn<57?1:2));
  #pragma unroll
  for (int r=0;r<16;++r){
    const int m = (r&3) + 8*(r>>2) + 4*hl;
    if (m < 30){
      const int im = m/6, jm = m - im*6;
      const int ridx = (in_-im+4)*11 + (jn-jm+5);
      const float bi = ldf(relb, ridx*8+h, f);
      const int rm = a_*5+im, cm = bb_*6+jm;
      const int lml = (rm<55?0:(rm<58?1:2))*3 + (cm<54?0:(cm<57?1:2));
      accS[r] = accS[r]*SCALE_ + bi + (lnl==lml ? 0.f : -100.f);
    } else accS[r] = -1e30f;
  }
  float mx = accS[0];
  #pragma unroll
  for (int r=1;r<16;++r) mx = fmaxf(mx, accS[r]);
  mx = fmaxf(mx, __shfl_xor(mx, 32, 64));
  float sum = 0.f;
  #pragma unroll
  for (int r=0;r<16;++r){ accS[r] = __expf(accS[r]-mx); sum += accS[r]; }
  sum += __shfl_xor(sum, 32, 64);
  const float inv = 1.f/sum;
  #pragma unroll
  for (int r=0;r<16;++r){
    const int m = (r&3)+8*(r>>2)+4*hl;
    paw[n*40 + m] = f2bf(accS[r]);
  }
  // PV: accO[r] = out[n][d_r]
  f32x16 accO = {};
  #pragma unroll
  for (int ks=0; ks<2; ++ks){
    bf16x8 av  = *(const bf16x8*)(vtw + n*40 + ks*16 + hl*8);
    bf16x8 pv  = *(const bf16x8*)(paw + n*40 + ks*16 + hl*8);
    accO = __builtin_amdgcn_mfma_f32_32x32x16_bf16(av, pv, accO, 0,0,0);
  }
  if (n < 30){
    #pragma unroll
    for (int g4=0; g4<4; ++g4){
      const int d0 = 8*g4 + 4*hl;
      ushort4 o;
      o.x = f2bf(accO[g4*4+0]*inv);
      o.y = f2bf(accO[g4*4+1]*inv);
      o.z = f2bf(accO[g4*4+2]*inv);
      o.w = f2bf(accO[g4*4+3]*inv);
      *(ushort4*)(ao + base + (size_t)n*256 + d0) = o;
    }
  }
}

// ---------------- Wo projection + window reverse + un-shift + residual -------
// x1b: bf16 [ROWS][256] in ws (spatial layout).
__global__ __launch_bounds__(512,5) void k_gemm_wo(const unsigned short* __restrict__ Ain,
    const unsigned short* __restrict__ WT, const void* __restrict__ bias,
    const void* __restrict__ xin, unsigned short* __restrict__ x1b,
    const int* __restrict__ flagp)
{
  __shared__ __align__(16) unsigned short lds[24576];
  f32x4 acc[4][2];
  int mt, nt; xcd_remap(blockIdx.x, 900, 2, mt, nt);
  const int m0 = mt*128, n0 = nt*128;
  mfma_core128<256>(Ain, WT, m0, n0, acc, lds);
  const int f = *flagp;
  const int tid = threadIdx.x, lane = tid&63, wave = tid>>6;
  const int wm = (wave>>2)*64, wn = (wave&3)*32;
  const int fr = lane&15, fq = lane>>4;
  // ---- write acc+bias -> LDS bf16 ----
  #pragma unroll
  for (int mi=0;mi<4;++mi){
    #pragma unroll
    for (int ni=0;ni<2;++ni){
      const int lcol = wn+ni*16+fr;
      const float bvv = ldf(bias, n0+lcol, f);
      #pragma unroll
      for (int r=0;r<4;++r){
        const int row = wm+mi*16+fq*4+r;
        lds[row*132+lcol] = f2bf(acc[mi][ni][r] + bvv);
      }
    }
  }
  __syncthreads();
  // ---- readback: window-reverse row, add residual wide, store bf16 wide ----
  const int row = tid>>2;
  const int rw = m0+row;
  const int nn = rw%30, t = (rw/30)%8, bw = rw/240;
  const int b = bw/120, wi = bw%120;
  const int a = wi/10, bb2 = wi%10, ii = nn/6, jj = nn%6;
  int rr = a*5+ii+SH_; if (rr>=60) rr-=60;
  int cc = bb2*6+jj+SW_; if (cc>=60) cc-=60;
  const size_t srow = ((size_t)((b*8+t)*60 + rr)*60 + cc);
  #pragma unroll
  for (int j=0;j<4;++j){
    const int ci = j*4 + (tid&3);
    const int col = n0 + ci*8;
    u16x8 vv = *(const u16x8*)(lds + row*132 + ci*8);
    float4 xa = ldf4(xin, srow*256+col,   f);
    float4 xbv= ldf4(xin, srow*256+col+4, f);
    u16x8 o;
    o[0]=f2bf(bf2f(vv[0])+xa.x); o[1]=f2bf(bf2f(vv[1])+xa.y);
    o[2]=f2bf(bf2f(vv[2])+xa.z); o[3]=f2bf(bf2f(vv[3])+xa.w);
    o[4]=f2bf(bf2f(vv[4])+xbv.x); o[5]=f2bf(bf2f(vv[5])+xbv.y);
    o[6]=f2bf(bf2f(vv[6])+xbv.z); o[7]=f2bf(bf2f(vv[7])+xbv.w);
    *(u16x8*)(x1b + srow*256 + col) = o;
  }
}

// ---------------- MLP1: xn2 @ W1 + b1 -> exact GELU -> h ---------------------
__global__ __launch_bounds__(512,5) void k_mlp1(const unsigned short* __restrict__ Ain,
    const unsigned short* __restrict__ WT, const void* __restrict__ bias,
    unsigned short* __restrict__ hb, const int row0, const int* __restrict__ flagp)
{
  __shared__ __align__(16) unsigned short lds[24576];
  f32x4 acc[4][2];
  int mt, nt; xcd_remap(blockIdx.x, 1800, 8, mt, nt);
  const int m0 = row0 + mt*128, n0 = nt*128;
  mfma_core128<256>(Ain, WT, m0, n0, acc, lds);
  const int f = *flagp;
  const int tid = threadIdx.x, lane = tid&63, wave = tid>>6;
  const int wm = (wave>>2)*64, wn = (wave&3)*32;
  const int fr = lane&15, fq = lane>>4;
  #pragma unroll
  for (int mi=0;mi<4;++mi){
    #pragma unroll
    for (int ni=0;ni<2;++ni){
      const int lcol = wn+ni*16+fr;
      const float bvv = ldf(bias, n0+lcol, f);
      #pragma unroll
      for (int r=0;r<4;++r){
        const int row = wm+mi*16+fq*4+r;
        const float vv = acc[mi][ni][r] + bvv;
        lds[row*132+lcol] = f2bf(0.5f*vv*(1.f+erff(vv*0.70710678118654752f)));
      }
    }
  }
  __syncthreads();
  const int row = tid>>2;
  unsigned short* dst = hb + (size_t)(mt*128+row)*1024 + n0;
  #pragma unroll
  for (int j=0;j<4;++j){
    const int ci = j*4 + (tid&3);
    *(u16x8*)(dst + ci*8) = *(const u16x8*)(lds + row*132 + ci*8);
  }
}

// ---------------- MLP2: h @ W2 + b2 + x1 -> out ------------------------------
__global__ __launch_bounds__(512,5) void k_mlp2(const unsigned short* __restrict__ hbin,
    const unsigned short* __restrict__ WT, const void* __restrict__ bias,
    const unsigned short* __restrict__ x1b, void* __restrict__ outb,
    const int row0, const int* __restrict__ flagp)
{
  __shared__ __align__(16) unsigned short lds[24576];
  f32x4 acc[4][2];
  int mt, nt; xcd_remap(blockIdx.x, 450, 2, mt, nt);
  const int m0l = mt*128, n0 = nt*128;
  mfma_core128<1024>(hbin, WT, m0l, n0, acc, lds);
  const int f = *flagp;
  const int tid = threadIdx.x, lane = tid&63, wave = tid>>6;
  const int wm = (wave>>2)*64, wn = (wave&3)*32;
  const int fr = lane&15, fq = lane>>4;
  #pragma unroll
  for (int mi=0;mi<4;++mi){
    #pragma unroll
    for (int ni=0;ni<2;++ni){
      const int lcol = wn+ni*16+fr;
      const float bvv = ldf(bias, n0+lcol, f);
      #pragma unroll
      for (int r=0;r<4;++r){
        const int row = wm+mi*16+fq*4+r;
        lds[row*132+lcol] = f2bf(acc[mi][ni][r] + bvv);
      }
    }
  }
  __syncthreads();
  const int row = tid>>2;
  const size_t grow = (size_t)(row0 + m0l + row);
  #pragma unroll
  for (int j=0;j<4;++j){
    const int ci = j*4 + (tid&3);
    const int col = n0 + ci*8;
    u16x8 vv = *(const u16x8*)(lds + row*132 + ci*8);
    u16x8 xv = *(const u16x8*)(x1b + grow*256 + col);
    if (f){
      float4 o0, o1;
      o0.x=bf2f(vv[0])+bf2f(xv[0]); o0.y=bf2f(vv[1])+bf2f(xv[1]);
      o0.z=bf2f(vv[2])+bf2f(xv[2]); o0.w=bf2f(vv[3])+bf2f(xv[3]);
      o1.x=bf2f(vv[4])+bf2f(xv[4]); o1.y=bf2f(vv[5])+bf2f(xv[5]);
      o1.z=bf2f(vv[6])+bf2f(xv[6]); o1.w=bf2f(vv[7])+bf2f(xv[7]);
      *(float4*)((float*)outb + grow*256 + col)     = o0;
      *(float4*)((float*)outb + grow*256 + col + 4) = o1;
    } else {
      u16x8 o;
      #pragma unroll
      for (int e=0;e<8;++e) o[e] = f2bf(bf2f(vv[e])+bf2f(xv[e]));
      *(u16x8*)((unsigned short*)outb + grow*256 + col) = o;
    }
  }
}

extern "C" void kernel_launch(void* const* d_in, const int* in_sizes, int n_in,
                              void* d_out, int out_size, void* d_ws, size_t ws_size,
                              hipStream_t stream)
{
  const void* x   = d_in[0];
  const void* ce  = d_in[1];
  const void* g1  = d_in[2];
  const void* be1 = d_in[3];
  const void* Wq  = d_in[4];
  const void* bq  = d_in[5];
  const void* Wk  = d_in[6];
  const void* bk  = d_in[7];
  const void* Wv  = d_in[8];
  const void* bv  = d_in[9];
  const void* rb  = d_in[10];
  const void* Wo  = d_in[11];
  const void* bo  = d_in[12];
  const void* g2  = d_in[13];
  const void* be2 = d_in[14];
  const void* W1  = d_in[15];
  const void* b1  = d_in[16];
  const void* W2  = d_in[17];
  const void* b2  = d_in[18];

  char* ws = (char*)d_ws;
  const size_t SZ = (size_t)ROWS_*256*2;                 // 29,491,200 B
  unsigned short* kbuf = (unsigned short*)(ws);          // [0, SZ)   later: xn2
  unsigned short* vbuf = (unsigned short*)(ws + SZ);     // [SZ, 2SZ)
  unsigned short* xw   = (unsigned short*)(ws + 2*SZ);   // [2SZ,3SZ) later: ao
  unsigned short* qbuf = (unsigned short*)(ws + 3*SZ);   // [3SZ,4SZ) later: x1b
  unsigned short* aob  = xw;
  unsigned short* xn2  = kbuf;                           // q/k dead after attn
  unsigned short* x1b  = qbuf;                           // bf16 x1
  unsigned short* hb   = vbuf;                           // [SZ,3SZ): v+ao dead in MLP
  float* posq = (float*)(ws + 4*SZ);                     // 16KB
  float* posk = posq + 16*256;                           // 16KB
  int*   flag = (int*)(ws + 4*SZ + 32768);
  unsigned short* wt = (unsigned short*)(ws + 4*SZ + 65536);  // 1.5MB bf16 WT

  unsigned short* wtqkv = wt;            // q|k|v contiguous: WT[768][256]
  unsigned short* wtq = wt;
  unsigned short* wtk = wt + 65536;
  unsigned short* wto = wt + 196608;
  unsigned short* wt1 = wt + 262144;
  unsigned short* wt2 = wt + 524288;

  k_detect<<<1,64,0,stream>>>((const unsigned short*)x, flag);
  k_prepw<<<dim3(1024,6),256,0,stream>>>(Wq,Wk,Wv,Wo,W1,W2, wt, flag);
  k_posqk<<<dim3(16,2),256,0,stream>>>(ce, wtq, wtk, bq, bk, posq, posk, flag);
  k_ln1<<<14400,256,0,stream>>>(x, g1, be1, xw, flag);
  k_gemm_qkv<<<2700,512,0,stream>>>(xw, wtqkv, posq, posk, bv, qbuf, kbuf, vbuf, flag);
  k_attn<<<3840,256,0,stream>>>(qbuf, kbuf, vbuf, rb, aob, flag);
  k_gemm_wo<<<900,512,0,stream>>>(aob, wto, bo, x, x1b, flag);
  k_ln2<<<14400,256,0,stream>>>(x1b, g2, be2, xn2, flag);
  for (int chk=0; chk<2; ++chk){
    const int row0 = chk*28800;
    k_mlp1<<<1800,512,0,stream>>>(xn2, wt1, b1, hb, row0, flag);
    k_mlp2<<<450,512,0,stream>>>(hb, wt2, b2, x1b, d_out, row0, flag);
  }
}